// Round 2
// baseline (8406.361 us; speedup 1.0000x reference)
//
#include <hip/hip_runtime.h>
#include <math.h>

#define N_NODES 50000
#define C_DIM   128
#define E_EDGES 1600000
#define Q_PAIRS 500000
#define H_DIM   256
#define N_CLS   2
#define BN_EPS  1e-5f

// ---------------- degree / norm precompute ----------------
__global__ __launch_bounds__(256) void k_deg_init(float* deg) {
    int i = blockIdx.x * 256 + threadIdx.x;
    if (i < N_NODES) deg[i] = 1.0f;   // +1 self loop
}

__global__ __launch_bounds__(256) void k_deg_acc(const int* __restrict__ dst,
                                                 const float* __restrict__ ew,
                                                 float* deg) {
    int e = blockIdx.x * 256 + threadIdx.x;
    if (e < E_EDGES) unsafeAtomicAdd(&deg[dst[e]], ew[e]);
}

__global__ __launch_bounds__(256) void k_deg_fin(float* deg) {
    int i = blockIdx.x * 256 + threadIdx.x;
    if (i < N_NODES) deg[i] = rsqrtf(deg[i]);   // deg >= 1, safe
}

__global__ __launch_bounds__(256) void k_norm(const int* __restrict__ src,
                                              const int* __restrict__ dst,
                                              const float* __restrict__ ew,
                                              const float* __restrict__ dinv,
                                              float* __restrict__ nrm) {
    int e = blockIdx.x * 256 + threadIdx.x;
    if (e < E_EDGES) nrm[e] = dinv[src[e]] * ew[e] * dinv[dst[e]];
}

// ---------------- GRU weight evolution: w = gru_step(w_init, w_init, ...) ----------------
__global__ __launch_bounds__(128) void k_gru(const float* __restrict__ w_init,
                                             const float* __restrict__ wih,
                                             const float* __restrict__ whh,
                                             const float* __restrict__ bih,
                                             const float* __restrict__ bhh,
                                             float* __restrict__ w_out) {
    __shared__ float xrow[C_DIM];
    int i = blockIdx.x, j = threadIdx.x;
    xrow[j] = w_init[i * C_DIM + j];
    __syncthreads();
    float gi[3], gh[3];
#pragma unroll
    for (int g = 0; g < 3; ++g) {
        const float* wi = wih + (size_t)(g * C_DIM + j) * C_DIM;
        const float* wh = whh + (size_t)(g * C_DIM + j) * C_DIM;
        float ai = 0.f, ah = 0.f;
        for (int k = 0; k < C_DIM; ++k) { ai += xrow[k] * wi[k]; ah += xrow[k] * wh[k]; }
        gi[g] = ai + bih[g * C_DIM + j];
        gh[g] = ah + bhh[g * C_DIM + j];
    }
    float r = 1.f / (1.f + expf(-(gi[0] + gh[0])));
    float z = 1.f / (1.f + expf(-(gi[1] + gh[1])));
    float n = tanhf(gi[2] + r * gh[2]);
    w_out[i * C_DIM + j] = (1.f - z) * n + z * xrow[j];
}

// ---------------- xw = x @ w ; outinit = xw * dinv^2 (self loop) ----------------
template <int RELU_IN>
__global__ __launch_bounds__(256) void k_xw(const float* x,
                                            const float* __restrict__ w,
                                            const float* __restrict__ dinv,
                                            float* __restrict__ xw,
                                            float* outinit) {
    __shared__ float wl[32 * C_DIM];   // w[k0+kk][j]
    __shared__ float xl[32 * C_DIM];   // x[row][k]
    int t = threadIdx.x;
    int r0 = blockIdx.x * 32;
    for (int i = t; i < 32 * C_DIM; i += 256) {
        int r = r0 + (i >> 7);
        float v = (r < N_NODES) ? x[(size_t)r * C_DIM + (i & 127)] : 0.f;
        if (RELU_IN) v = fmaxf(v, 0.f);
        xl[i] = v;
    }
    int tc = t & 31;          // col base (4 cols: tc+32c)
    int tr = (t >> 5) << 2;   // 4 rows: tr..tr+3
    float acc[4][4] = {};
    for (int k0 = 0; k0 < C_DIM; k0 += 32) {
        __syncthreads();
        for (int i = t; i < 32 * C_DIM; i += 256)
            wl[i] = w[(size_t)(k0 + (i >> 7)) * C_DIM + (i & 127)];
        __syncthreads();
        for (int kk = 0; kk < 32; ++kk) {
            float wv[4], xv[4];
#pragma unroll
            for (int c = 0; c < 4; ++c) wv[c] = wl[kk * C_DIM + tc + 32 * c];
#pragma unroll
            for (int rr = 0; rr < 4; ++rr) xv[rr] = xl[(tr + rr) * C_DIM + k0 + kk];
#pragma unroll
            for (int rr = 0; rr < 4; ++rr)
#pragma unroll
                for (int c = 0; c < 4; ++c) acc[rr][c] += xv[rr] * wv[c];
        }
    }
#pragma unroll
    for (int rr = 0; rr < 4; ++rr) {
        int r = r0 + tr + rr;
        if (r < N_NODES) {
            float di = dinv[r];
            float d2 = di * di;
#pragma unroll
            for (int c = 0; c < 4; ++c) {
                size_t o = (size_t)r * C_DIM + tc + 32 * c;
                float v = acc[rr][c];
                xw[o] = v;
                outinit[o] = v * d2;
            }
        }
    }
}

// ---------------- edge scatter: out[dst] += xw[src] * nrm ----------------
__global__ __launch_bounds__(256) void k_scatter(const float* __restrict__ xw,
                                                 const int* __restrict__ src,
                                                 const int* __restrict__ dst,
                                                 const float* __restrict__ nrm,
                                                 float* __restrict__ out) {
    int tid = blockIdx.x * 256 + threadIdx.x;
    int e = tid >> 5;
    int g = (tid & 31) << 2;
    int s = src[e], d = dst[e];
    float nv = nrm[e];
    const float4 v = *reinterpret_cast<const float4*>(xw + (size_t)s * C_DIM + g);
    float* o = out + (size_t)d * C_DIM + g;
    unsafeAtomicAdd(o + 0, v.x * nv);
    unsafeAtomicAdd(o + 1, v.y * nv);
    unsafeAtomicAdd(o + 2, v.z * nv);
    unsafeAtomicAdd(o + 3, v.w * nv);
}

// ---------------- fused query MLP ----------------
// 16 queries/block, 256 threads. Wave tq = t>>6 owns queries {4tq..4tq+3};
// lane tj = t&63 owns cols {tj+64c, c=0..3}. Every (q, j) owned by exactly
// one thread -> in-wave shfl reduce over 64 lanes sums all 256 cols once,
// each wave finishes its own 4 queries (no cross-wave reduction).
__global__ __launch_bounds__(256) void k_mlp(const float* __restrict__ y,
                                             const int* __restrict__ e1,
                                             const int* __restrict__ e2,
                                             const float* __restrict__ w0, const float* __restrict__ b0,
                                             const float* __restrict__ w1, const float* __restrict__ b1,
                                             const float* __restrict__ w2, const float* __restrict__ b2,
                                             const float* __restrict__ g0, const float* __restrict__ bb0,
                                             const float* __restrict__ m0, const float* __restrict__ v0,
                                             const float* __restrict__ g1, const float* __restrict__ bb1,
                                             const float* __restrict__ m1, const float* __restrict__ v1,
                                             float* __restrict__ out) {
    __shared__ float hs[16 * C_DIM];    // 8 KB
    __shared__ float l1s[16 * H_DIM];   // 16 KB
    __shared__ float wt[H_DIM * 33];    // 33 KB, padded (scalar reads conflict-free)
    int t = threadIdx.x;
    int qb = blockIdx.x * 16;
    int tj = t & 63;
    int tq = t >> 6;

    for (int idx = t; idx < 16 * C_DIM; idx += 256) {
        int q = idx >> 7, c = idx & 127;
        int a = e1[qb + q], b = e2[qb + q];
        float xa = fmaxf(y[(size_t)a * C_DIM + c], 0.f);
        float xb = fmaxf(y[(size_t)b * C_DIM + c], 0.f);
        hs[idx] = xa * xb;
    }

    // ---- layer 1: [16 q] x [256 j], K = 128 ----
    float acc[4][4] = {};   // [qq][c]
    for (int k0 = 0; k0 < C_DIM; k0 += 32) {
        __syncthreads();
        for (int i = t; i < H_DIM * 32; i += 256) {
            int j = i >> 5, kk = i & 31;
            wt[j * 33 + kk] = w0[(size_t)j * C_DIM + k0 + kk];
        }
        __syncthreads();
#pragma unroll
        for (int m = 0; m < 8; ++m) {
            float4 hv[4];
#pragma unroll
            for (int qq = 0; qq < 4; ++qq)
                hv[qq] = *reinterpret_cast<const float4*>(&hs[(4 * tq + qq) * C_DIM + k0 + 4 * m]);
#pragma unroll
            for (int u = 0; u < 4; ++u) {
                float wv[4];
#pragma unroll
                for (int c = 0; c < 4; ++c) wv[c] = wt[(tj + 64 * c) * 33 + 4 * m + u];
#pragma unroll
                for (int qq = 0; qq < 4; ++qq) {
                    float hvv = reinterpret_cast<const float*>(&hv[qq])[u];
#pragma unroll
                    for (int c = 0; c < 4; ++c) acc[qq][c] += hvv * wv[c];
                }
            }
        }
    }
    // BN0 + relu -> l1s  (each (q,j) written by exactly one thread)
#pragma unroll
    for (int c = 0; c < 4; ++c) {
        int j = tj + 64 * c;
        float sc = g0[j] * rsqrtf(v0[j] + BN_EPS);
        float sh = (b0[j] - m0[j]) * sc + bb0[j];
#pragma unroll
        for (int qq = 0; qq < 4; ++qq)
            l1s[(4 * tq + qq) * H_DIM + j] = fmaxf(acc[qq][c] * sc + sh, 0.f);
    }

    // ---- layer 2: K = 256 ----
    float acc2[4][4] = {};
    for (int k0 = 0; k0 < H_DIM; k0 += 32) {
        __syncthreads();
        for (int i = t; i < H_DIM * 32; i += 256) {
            int j = i >> 5, kk = i & 31;
            wt[j * 33 + kk] = w1[(size_t)j * H_DIM + k0 + kk];
        }
        __syncthreads();
#pragma unroll
        for (int m = 0; m < 8; ++m) {
            float4 hv[4];
#pragma unroll
            for (int qq = 0; qq < 4; ++qq)
                hv[qq] = *reinterpret_cast<const float4*>(&l1s[(4 * tq + qq) * H_DIM + k0 + 4 * m]);
#pragma unroll
            for (int u = 0; u < 4; ++u) {
                float wv[4];
#pragma unroll
                for (int c = 0; c < 4; ++c) wv[c] = wt[(tj + 64 * c) * 33 + 4 * m + u];
#pragma unroll
                for (int qq = 0; qq < 4; ++qq) {
                    float hvv = reinterpret_cast<const float*>(&hv[qq])[u];
#pragma unroll
                    for (int c = 0; c < 4; ++c) acc2[qq][c] += hvv * wv[c];
                }
            }
        }
    }

    // BN1 + relu + final 256->2 dot (per-thread partial over its 4 cols)
    float p0[4] = {}, p1[4] = {};
#pragma unroll
    for (int c = 0; c < 4; ++c) {
        int j = tj + 64 * c;
        float sc = g1[j] * rsqrtf(v1[j] + BN_EPS);
        float sh = (b1[j] - m1[j]) * sc + bb1[j];
        float wa = w2[j];
        float wb = w2[H_DIM + j];
#pragma unroll
        for (int qq = 0; qq < 4; ++qq) {
            float v = fmaxf(acc2[qq][c] * sc + sh, 0.f);
            p0[qq] += v * wa;
            p1[qq] += v * wb;
        }
    }
    // in-wave reduce over 64 lanes: sums cols 0..255 exactly once
#pragma unroll
    for (int off = 1; off < 64; off <<= 1) {
#pragma unroll
        for (int qq = 0; qq < 4; ++qq) {
            p0[qq] += __shfl_xor(p0[qq], off, 64);
            p1[qq] += __shfl_xor(p1[qq], off, 64);
        }
    }
    if (tj == 0) {
        float c0 = b2[0], c1 = b2[1];
#pragma unroll
        for (int qq = 0; qq < 4; ++qq) {
            float l0 = p0[qq] + c0, l1v = p1[qq] + c1;
            float mx = fmaxf(l0, l1v);
            float lse = mx + logf(expf(l0 - mx) + expf(l1v - mx));
            size_t o = (size_t)(qb + 4 * tq + qq) * N_CLS;
            out[o + 0] = l0 - lse;
            out[o + 1] = l1v - lse;
        }
    }
}

// ---------------- launch ----------------
extern "C" void kernel_launch(void* const* d_in, const int* in_sizes, int n_in,
                              void* d_out, int out_size, void* d_ws, size_t ws_size,
                              hipStream_t stream) {
    const float* X  = (const float*)d_in[0];
    const int*   ei = (const int*)d_in[1];
    const float* ew = (const float*)d_in[2];
    const int*   e1 = (const int*)d_in[3];
    const int*   e2 = (const int*)d_in[4];
    const float* w_init[2] = {(const float*)d_in[5],  (const float*)d_in[10]};
    const float* w_ih[2]   = {(const float*)d_in[6],  (const float*)d_in[11]};
    const float* w_hh[2]   = {(const float*)d_in[7],  (const float*)d_in[12]};
    const float* b_ih[2]   = {(const float*)d_in[8],  (const float*)d_in[13]};
    const float* b_hh[2]   = {(const float*)d_in[9],  (const float*)d_in[14]};
    const float* lw0 = (const float*)d_in[15]; const float* lb0 = (const float*)d_in[16];
    const float* lw1 = (const float*)d_in[17]; const float* lb1 = (const float*)d_in[18];
    const float* lw2 = (const float*)d_in[19]; const float* lb2 = (const float*)d_in[20];
    const float* bg0 = (const float*)d_in[21]; const float* bb0 = (const float*)d_in[22];
    const float* bm0 = (const float*)d_in[23]; const float* bv0 = (const float*)d_in[24];
    const float* bg1 = (const float*)d_in[25]; const float* bb1 = (const float*)d_in[26];
    const float* bm1 = (const float*)d_in[27]; const float* bv1 = (const float*)d_in[28];
    const int* src = ei;
    const int* dst = ei + E_EDGES;

    float* ws   = (float*)d_ws;
    float* bufA = ws;                                  // xw       : N*C
    float* bufB = bufA + (size_t)N_NODES * C_DIM;      // out/x    : N*C
    float* dinv = bufB + (size_t)N_NODES * C_DIM;      // N
    float* w_ev = dinv + N_NODES;                      // C*C
    float* nrm  = w_ev + C_DIM * C_DIM;                // E
    size_t need = ((size_t)2 * N_NODES * C_DIM + N_NODES + C_DIM * C_DIM + E_EDGES) * 4;
    if (ws_size < need) return;  // fail loudly rather than corrupt

    dim3 b256(256);
    k_deg_init<<<(N_NODES + 255) / 256, b256, 0, stream>>>(dinv);
    k_deg_acc<<<(E_EDGES + 255) / 256, b256, 0, stream>>>(dst, ew, dinv);
    k_deg_fin<<<(N_NODES + 255) / 256, b256, 0, stream>>>(dinv);
    k_norm<<<(E_EDGES + 255) / 256, b256, 0, stream>>>(src, dst, ew, dinv, nrm);

    const int xw_grid = (N_NODES + 31) / 32;
    // layer 0
    k_gru<<<C_DIM, 128, 0, stream>>>(w_init[0], w_ih[0], w_hh[0], b_ih[0], b_hh[0], w_ev);
    k_xw<0><<<xw_grid, b256, 0, stream>>>(X, w_ev, dinv, bufA, bufB);
    k_scatter<<<E_EDGES * 32 / 256, b256, 0, stream>>>(bufA, src, dst, nrm, bufB);
    // layer 1 (relu fused into input loads; bufB in/out is row-block safe)
    k_gru<<<C_DIM, 128, 0, stream>>>(w_init[1], w_ih[1], w_hh[1], b_ih[1], b_hh[1], w_ev);
    k_xw<1><<<xw_grid, b256, 0, stream>>>(bufB, w_ev, dinv, bufA, bufB);
    k_scatter<<<E_EDGES * 32 / 256, b256, 0, stream>>>(bufA, src, dst, nrm, bufB);
    // fused MLP (relu fused into gather)
    k_mlp<<<Q_PAIRS / 16, b256, 0, stream>>>(bufB, e1, e2, lw0, lb0, lw1, lb1, lw2, lb2,
                                             bg0, bb0, bm0, bv0, bg1, bb1, bm1, bv1,
                                             (float*)d_out);
}

// Round 3
// 1337.425 us; speedup vs baseline: 6.2855x; 6.2855x over previous
//
#include <hip/hip_runtime.h>
#include <math.h>

#define N_NODES 50000
#define C_DIM   128
#define E_EDGES 1600000
#define Q_PAIRS 500000
#define H_DIM   256
#define N_CLS   2
#define BN_EPS  1e-5f

typedef __attribute__((ext_vector_type(8))) short bf16x8;
typedef __attribute__((ext_vector_type(4))) short s16x4;
typedef __attribute__((ext_vector_type(4))) float f32x4;

__device__ __forceinline__ unsigned short f2bf(float x) {   // RNE f32->bf16 bits
    unsigned u = __float_as_uint(x);
    u += 0x7fffu + ((u >> 16) & 1u);
    return (unsigned short)(u >> 16);
}
__device__ __forceinline__ float bf2f(unsigned short h) {
    return __uint_as_float(((unsigned)h) << 16);
}

// ---------------- small init/degree kernels ----------------
__global__ __launch_bounds__(256) void k_zero_int(int* p, int n) {
    int i = blockIdx.x * 256 + threadIdx.x;
    if (i < n) p[i] = 0;
}
__global__ __launch_bounds__(256) void k_deg_init(float* deg) {
    int i = blockIdx.x * 256 + threadIdx.x;
    if (i < N_NODES) deg[i] = 1.0f;   // +1 self loop
}
__global__ __launch_bounds__(256) void k_deg_acc(const int* __restrict__ dst,
                                                 const float* __restrict__ ew,
                                                 float* deg) {
    int e = blockIdx.x * 256 + threadIdx.x;
    if (e < E_EDGES) unsafeAtomicAdd(&deg[dst[e]], ew[e]);
}
__global__ __launch_bounds__(256) void k_deg_fin(float* deg) {
    int i = blockIdx.x * 256 + threadIdx.x;
    if (i < N_NODES) deg[i] = rsqrtf(deg[i]);
}

// ---------------- CSR build ----------------
__global__ __launch_bounds__(256) void k_hist(const int* __restrict__ dst, int* cnt) {
    int e = blockIdx.x * 256 + threadIdx.x;
    if (e < E_EDGES) atomicAdd(&cnt[dst[e]], 1);
}

__global__ __launch_bounds__(1024) void k_scan(const int* __restrict__ cnt,
                                               int* __restrict__ off,
                                               int* __restrict__ pos) {
    __shared__ int pa[1024], pb[1024];
    int t = threadIdx.x;
    const int CH = (N_NODES + 1023) / 1024;   // 49
    int base = t * CH;
    int s = 0;
    for (int i = 0; i < CH; ++i) { int x = base + i; if (x < N_NODES) s += cnt[x]; }
    pa[t] = s;
    __syncthreads();
    int* sp = pa; int* dp = pb;
    for (int o = 1; o < 1024; o <<= 1) {
        int v = sp[t] + ((t >= o) ? sp[t - o] : 0);
        dp[t] = v;
        __syncthreads();
        int* tmp = sp; sp = dp; dp = tmp;
    }
    int run = (t == 0) ? 0 : sp[t - 1];
    for (int i = 0; i < CH; ++i) {
        int x = base + i;
        if (x < N_NODES) { off[x] = run; pos[x] = run; run += cnt[x]; }
    }
    if (t == 1023) off[N_NODES] = sp[1023];
}

__global__ __launch_bounds__(256) void k_fill(const int* __restrict__ src,
                                              const int* __restrict__ dst,
                                              const float* __restrict__ ew,
                                              const float* __restrict__ dinv,
                                              int* pos,
                                              int* __restrict__ csr_s,
                                              float* __restrict__ csr_w) {
    int e = blockIdx.x * 256 + threadIdx.x;
    if (e >= E_EDGES) return;
    int s = src[e], d = dst[e];
    int slot = atomicAdd(&pos[d], 1);
    csr_s[slot] = s;
    csr_w[slot] = dinv[s] * ew[e] * dinv[d];
}

// ---------------- GRU weight evolution ----------------
__global__ __launch_bounds__(128) void k_gru(const float* __restrict__ w_init,
                                             const float* __restrict__ wih,
                                             const float* __restrict__ whh,
                                             const float* __restrict__ bih,
                                             const float* __restrict__ bhh,
                                             float* __restrict__ w_out) {
    __shared__ float xrow[C_DIM];
    int i = blockIdx.x, j = threadIdx.x;
    xrow[j] = w_init[i * C_DIM + j];
    __syncthreads();
    float gi[3], gh[3];
#pragma unroll
    for (int g = 0; g < 3; ++g) {
        const float* wi = wih + (size_t)(g * C_DIM + j) * C_DIM;
        const float* wh = whh + (size_t)(g * C_DIM + j) * C_DIM;
        float ai = 0.f, ah = 0.f;
        for (int k = 0; k < C_DIM; ++k) { ai += xrow[k] * wi[k]; ah += xrow[k] * wh[k]; }
        gi[g] = ai + bih[g * C_DIM + j];
        gh[g] = ah + bhh[g * C_DIM + j];
    }
    float r = 1.f / (1.f + expf(-(gi[0] + gh[0])));
    float z = 1.f / (1.f + expf(-(gi[1] + gh[1])));
    float n = tanhf(gi[2] + r * gh[2]);
    w_out[i * C_DIM + j] = (1.f - z) * n + z * xrow[j];
}

// ---------------- xw = x @ w ; outinit = xw * dinv^2 ----------------
template <int RELU_IN>
__global__ __launch_bounds__(256) void k_xw(const float* x,
                                            const float* __restrict__ w,
                                            const float* __restrict__ dinv,
                                            float* __restrict__ xw,
                                            float* outinit) {
    __shared__ float wl[32 * C_DIM];
    __shared__ float xl[32 * C_DIM];
    int t = threadIdx.x;
    int r0 = blockIdx.x * 32;
    for (int i = t; i < 32 * C_DIM; i += 256) {
        int r = r0 + (i >> 7);
        float v = (r < N_NODES) ? x[(size_t)r * C_DIM + (i & 127)] : 0.f;
        if (RELU_IN) v = fmaxf(v, 0.f);
        xl[i] = v;
    }
    int tc = t & 31;
    int tr = (t >> 5) << 2;
    float acc[4][4] = {};
    for (int k0 = 0; k0 < C_DIM; k0 += 32) {
        __syncthreads();
        for (int i = t; i < 32 * C_DIM; i += 256)
            wl[i] = w[(size_t)(k0 + (i >> 7)) * C_DIM + (i & 127)];
        __syncthreads();
        for (int kk = 0; kk < 32; ++kk) {
            float wv[4], xv[4];
#pragma unroll
            for (int c = 0; c < 4; ++c) wv[c] = wl[kk * C_DIM + tc + 32 * c];
#pragma unroll
            for (int rr = 0; rr < 4; ++rr) xv[rr] = xl[(tr + rr) * C_DIM + k0 + kk];
#pragma unroll
            for (int rr = 0; rr < 4; ++rr)
#pragma unroll
                for (int c = 0; c < 4; ++c) acc[rr][c] += xv[rr] * wv[c];
        }
    }
#pragma unroll
    for (int rr = 0; rr < 4; ++rr) {
        int r = r0 + tr + rr;
        if (r < N_NODES) {
            float di = dinv[r];
            float d2 = di * di;
#pragma unroll
            for (int c = 0; c < 4; ++c) {
                size_t o = (size_t)r * C_DIM + tc + 32 * c;
                float v = acc[rr][c];
                xw[o] = v;
                outinit[o] = v * d2;
            }
        }
    }
}

// ---------------- CSR gather: out[n] = init[n] + sum_e w_e * xw[src_e] ----------------
// one wave per node, lane owns 2 channels (float2)
__global__ __launch_bounds__(256) void k_gather(const float* __restrict__ xw,
                                                const int* __restrict__ off,
                                                const int* __restrict__ csr_s,
                                                const float* __restrict__ csr_w,
                                                float* __restrict__ io) {
    int n = (blockIdx.x * 256 + threadIdx.x) >> 6;
    if (n >= N_NODES) return;
    int lane = threadIdx.x & 63;
    int c = lane * 2;
    int s0 = off[n], s1 = off[n + 1];
    float2 acc = *(const float2*)(io + (size_t)n * C_DIM + c);
    for (int i = s0; i < s1; ++i) {
        int s = csr_s[i];
        float w = csr_w[i];
        float2 v = *(const float2*)(xw + (size_t)s * C_DIM + c);
        acc.x += w * v.x;
        acc.y += w * v.y;
    }
    *(float2*)(io + (size_t)n * C_DIM + c) = acc;
}

// ---------------- weight prep: BN-folded bf16 hi/lo in MFMA A-fragment layout ----------------
// out idx: [kb][plane(hi=0,lo=1)][kgrp(4)][col(256)][e(8)], k = kb*32+kgrp*8+e
__global__ __launch_bounds__(256) void k_prep_w(const float* __restrict__ w,
                                                const float* __restrict__ g,
                                                const float* __restrict__ v,
                                                int kdim, int total,
                                                unsigned short* __restrict__ outp) {
    int idx = blockIdx.x * 256 + threadIdx.x;
    if (idx >= total) return;
    int e = idx & 7, col = (idx >> 3) & 255, kgrp = (idx >> 11) & 3;
    int plane = (idx >> 13) & 1, kb = idx >> 14;
    int k = kb * 32 + kgrp * 8 + e;
    float sc = g[col] * rsqrtf(v[col] + BN_EPS);
    float x = w[(size_t)col * kdim + k] * sc;
    unsigned short hi = f2bf(x);
    outp[idx] = plane ? f2bf(x - bf2f(hi)) : hi;
}

__global__ __launch_bounds__(512) void k_prep_shift(
    const float* __restrict__ lb0, const float* __restrict__ bg0, const float* __restrict__ bb0,
    const float* __restrict__ bm0, const float* __restrict__ bv0,
    const float* __restrict__ lb1, const float* __restrict__ bg1, const float* __restrict__ bb1,
    const float* __restrict__ bm1, const float* __restrict__ bv1,
    float* __restrict__ shift0, float* __restrict__ shift1) {
    int j = threadIdx.x;
    if (j < 256) {
        float sc = bg0[j] * rsqrtf(bv0[j] + BN_EPS);
        shift0[j] = (lb0[j] - bm0[j]) * sc + bb0[j];
    } else {
        int i = j - 256;
        float sc = bg1[i] * rsqrtf(bv1[i] + BN_EPS);
        shift1[i] = (lb1[i] - bm1[i]) * sc + bb1[i];
    }
}

// ---------------- fused query MLP (bf16 hi/lo MFMA) ----------------
// 32 queries/block, 4 waves: wave = qg*2+ch; qg in {0,1} = 16-query group,
// ch in {0,1} = 128-col half. D = W_tile(A) x H^T(B): D col = query, D row = out-col.
__global__ __launch_bounds__(256) void k_mlp(const float* __restrict__ y,
                                             const int* __restrict__ e1,
                                             const int* __restrict__ e2,
                                             const unsigned short* __restrict__ W0p,
                                             const unsigned short* __restrict__ W1p,
                                             const float* __restrict__ shift0,
                                             const float* __restrict__ shift1,
                                             const float* __restrict__ w2,
                                             const float* __restrict__ b2,
                                             float* __restrict__ out) {
    __shared__ __align__(16) char smem[65536];
    unsigned short* strip = (unsigned short*)smem;          // 32KB: [plane][kgrp][col][8]
    unsigned short* l1b = (unsigned short*)(smem + 32768);  // 32KB: [plane][qrow32][256] swizzled
    float* red = (float*)smem;                              // aliases strip (layer-3 only)

    const int t = threadIdx.x;
    const int lane = t & 63;
    const int wave = t >> 6;
    const int qg = wave >> 1, ch = wave & 1;
    const int l16 = lane & 15, kg = lane >> 4;
    const int qrow = qg * 16 + l16;
    const int qb = blockIdx.x * 32;
    const float* ya = y + (size_t)e1[qb + qrow] * C_DIM;
    const float* yb = y + (size_t)e2[qb + qrow] * C_DIM;
    char* sdst = smem + wave * 8192;

    f32x4 acc1[8];
#pragma unroll
    for (int i = 0; i < 8; ++i) acc1[i] = 0.f;

    // ---- layer 1: K = 128 (4 k-blocks of 32) ----
    for (int kb = 0; kb < 4; ++kb) {
        __syncthreads();   // strip consumed
        const char* gsrc = (const char*)W0p + (size_t)kb * 32768 + wave * 8192 + lane * 16;
#pragma unroll
        for (int r = 0; r < 8; ++r)
            __builtin_amdgcn_global_load_lds(
                (const __attribute__((address_space(1))) void*)(gsrc + r * 1024),
                (__attribute__((address_space(3))) void*)(sdst + r * 1024), 16, 0, 0);
        // B-frag: H[q][k-chunk] from global y (overlaps staging)
        int k0 = kb * 32 + kg * 8;
        f32x4 a0 = *(const f32x4*)(ya + k0);
        f32x4 a1 = *(const f32x4*)(ya + k0 + 4);
        f32x4 b0v = *(const f32x4*)(yb + k0);
        f32x4 b1v = *(const f32x4*)(yb + k0 + 4);
        bf16x8 bh, bl;
#pragma unroll
        for (int e = 0; e < 4; ++e) {
            float h0 = fmaxf(a0[e], 0.f) * fmaxf(b0v[e], 0.f);
            unsigned short hh0 = f2bf(h0);
            bh[e] = (short)hh0; bl[e] = (short)f2bf(h0 - bf2f(hh0));
            float h1 = fmaxf(a1[e], 0.f) * fmaxf(b1v[e], 0.f);
            unsigned short hh1 = f2bf(h1);
            bh[e + 4] = (short)hh1; bl[e + 4] = (short)f2bf(h1 - bf2f(hh1));
        }
        __syncthreads();   // strip ready
#pragma unroll
        for (int jc8 = 0; jc8 < 8; ++jc8) {
            int col = (ch * 8 + jc8) * 16 + l16;
            bf16x8 ahi = *(const bf16x8*)&strip[kg * 2048 + col * 8];
            bf16x8 alo = *(const bf16x8*)&strip[8192 + kg * 2048 + col * 8];
            acc1[jc8] = __builtin_amdgcn_mfma_f32_16x16x32_bf16(ahi, bh, acc1[jc8], 0, 0, 0);
            acc1[jc8] = __builtin_amdgcn_mfma_f32_16x16x32_bf16(alo, bh, acc1[jc8], 0, 0, 0);
            acc1[jc8] = __builtin_amdgcn_mfma_f32_16x16x32_bf16(ahi, bl, acc1[jc8], 0, 0, 0);
        }
    }

    // ---- epilogue 1: BN-shift + relu -> l1b (bf16 hi/lo, XOR-swizzled granules) ----
#pragma unroll
    for (int jc8 = 0; jc8 < 8; ++jc8) {
        int jc = ch * 8 + jc8;
        int j0 = jc * 16 + kg * 4;
        f32x4 sh = *(const f32x4*)(shift0 + j0);
        short hv[4], lv[4];
#pragma unroll
        for (int r = 0; r < 4; ++r) {
            float v = fmaxf(acc1[jc8][r] + sh[r], 0.f);
            unsigned short hh = f2bf(v);
            hv[r] = (short)hh; lv[r] = (short)f2bf(v - bf2f(hh));
        }
        int g = jc * 2 + (kg >> 1);
        int idx = qrow * 256 + ((g ^ (qrow & 7)) * 8) + (kg & 1) * 4;
        s16x4 th; th[0] = hv[0]; th[1] = hv[1]; th[2] = hv[2]; th[3] = hv[3];
        s16x4 tl; tl[0] = lv[0]; tl[1] = lv[1]; tl[2] = lv[2]; tl[3] = lv[3];
        *(s16x4*)&l1b[idx] = th;
        *(s16x4*)&l1b[8192 + idx] = tl;
    }

    // ---- layer 2: K = 256 (8 k-blocks) ----
    f32x4 acc2[8];
#pragma unroll
    for (int i = 0; i < 8; ++i) acc2[i] = 0.f;
    for (int kb = 0; kb < 8; ++kb) {
        __syncthreads();   // strip consumed + (kb==0) l1b fully written
        const char* gsrc = (const char*)W1p + (size_t)kb * 32768 + wave * 8192 + lane * 16;
#pragma unroll
        for (int r = 0; r < 8; ++r)
            __builtin_amdgcn_global_load_lds(
                (const __attribute__((address_space(1))) void*)(gsrc + r * 1024),
                (__attribute__((address_space(3))) void*)(sdst + r * 1024), 16, 0, 0);
        int gidx = qrow * 256 + (((kb * 4 + kg) ^ (qrow & 7)) * 8);
        bf16x8 bh2 = *(const bf16x8*)&l1b[gidx];
        bf16x8 bl2 = *(const bf16x8*)&l1b[8192 + gidx];
        __syncthreads();   // strip ready
#pragma unroll
        for (int jc8 = 0; jc8 < 8; ++jc8) {
            int col = (ch * 8 + jc8) * 16 + l16;
            bf16x8 ahi = *(const bf16x8*)&strip[kg * 2048 + col * 8];
            bf16x8 alo = *(const bf16x8*)&strip[8192 + kg * 2048 + col * 8];
            acc2[jc8] = __builtin_amdgcn_mfma_f32_16x16x32_bf16(ahi, bh2, acc2[jc8], 0, 0, 0);
            acc2[jc8] = __builtin_amdgcn_mfma_f32_16x16x32_bf16(alo, bh2, acc2[jc8], 0, 0, 0);
            acc2[jc8] = __builtin_amdgcn_mfma_f32_16x16x32_bf16(ahi, bl2, acc2[jc8], 0, 0, 0);
        }
    }

    // ---- layer 3: BN-shift + relu + 256->2 + log_softmax ----
    float p0 = 0.f, p1 = 0.f;
#pragma unroll
    for (int jc8 = 0; jc8 < 8; ++jc8) {
        int j0 = (ch * 8 + jc8) * 16 + kg * 4;
        f32x4 sh = *(const f32x4*)(shift1 + j0);
        f32x4 wa = *(const f32x4*)(w2 + j0);
        f32x4 wb = *(const f32x4*)(w2 + H_DIM + j0);
#pragma unroll
        for (int r = 0; r < 4; ++r) {
            float v = fmaxf(acc2[jc8][r] + sh[r], 0.f);
            p0 += v * wa[r];
            p1 += v * wb[r];
        }
    }
    p0 += __shfl_xor(p0, 16, 64); p0 += __shfl_xor(p0, 32, 64);
    p1 += __shfl_xor(p1, 16, 64); p1 += __shfl_xor(p1, 32, 64);
    __syncthreads();   // strip reads done; reuse as red
    if (lane < 16) {
        red[(wave * 16 + lane) * 2 + 0] = p0;
        red[(wave * 16 + lane) * 2 + 1] = p1;
    }
    __syncthreads();
    if (ch == 0 && lane < 16) {
        float l0 = red[(wave * 16 + lane) * 2 + 0] + red[((wave + 1) * 16 + lane) * 2 + 0] + b2[0];
        float l1v = red[(wave * 16 + lane) * 2 + 1] + red[((wave + 1) * 16 + lane) * 2 + 1] + b2[1];
        float mx = fmaxf(l0, l1v);
        float lse = mx + logf(expf(l0 - mx) + expf(l1v - mx));
        float2 o; o.x = l0 - lse; o.y = l1v - lse;
        *(float2*)(out + (size_t)(qb + qrow) * N_CLS) = o;
    }
}

// ---------------- launch ----------------
extern "C" void kernel_launch(void* const* d_in, const int* in_sizes, int n_in,
                              void* d_out, int out_size, void* d_ws, size_t ws_size,
                              hipStream_t stream) {
    const float* X  = (const float*)d_in[0];
    const int*   ei = (const int*)d_in[1];
    const float* ew = (const float*)d_in[2];
    const int*   e1 = (const int*)d_in[3];
    const int*   e2 = (const int*)d_in[4];
    const float* w_init[2] = {(const float*)d_in[5],  (const float*)d_in[10]};
    const float* w_ih[2]   = {(const float*)d_in[6],  (const float*)d_in[11]};
    const float* w_hh[2]   = {(const float*)d_in[7],  (const float*)d_in[12]};
    const float* b_ih[2]   = {(const float*)d_in[8],  (const float*)d_in[13]};
    const float* b_hh[2]   = {(const float*)d_in[9],  (const float*)d_in[14]};
    const float* lw0 = (const float*)d_in[15]; const float* lb0 = (const float*)d_in[16];
    const float* lw1 = (const float*)d_in[17]; const float* lb1 = (const float*)d_in[18];
    const float* lw2 = (const float*)d_in[19]; const float* lb2 = (const float*)d_in[20];
    const float* bg0 = (const float*)d_in[21]; const float* bb0 = (const float*)d_in[22];
    const float* bm0 = (const float*)d_in[23]; const float* bv0 = (const float*)d_in[24];
    const float* bg1 = (const float*)d_in[25]; const float* bb1 = (const float*)d_in[26];
    const float* bm1 = (const float*)d_in[27]; const float* bv1 = (const float*)d_in[28];
    const int* src = ei;
    const int* dst = ei + E_EDGES;

    char* ws = (char*)d_ws;
    size_t o = 0;
    auto alloc = [&](size_t bytes) { char* p = ws + o; o += (bytes + 63) & ~(size_t)63; return p; };
    float* bufA   = (float*)alloc((size_t)N_NODES * C_DIM * 4);
    float* bufB   = (float*)alloc((size_t)N_NODES * C_DIM * 4);
    float* dinv   = (float*)alloc(N_NODES * 4);
    float* w_ev   = (float*)alloc(C_DIM * C_DIM * 4);
    float* csr_w  = (float*)alloc((size_t)E_EDGES * 4);
    float* shift0 = (float*)alloc(H_DIM * 4);
    float* shift1 = (float*)alloc(H_DIM * 4);
    int*   cnt    = (int*)alloc(N_NODES * 4);
    int*   pos    = (int*)alloc(N_NODES * 4);
    int*   off    = (int*)alloc((N_NODES + 1) * 4);
    int*   csr_s  = (int*)alloc((size_t)E_EDGES * 4);
    unsigned short* W0p = (unsigned short*)alloc(4 * 2 * 4 * 256 * 8 * 2);   // 128KB
    unsigned short* W1p = (unsigned short*)alloc(8 * 2 * 4 * 256 * 8 * 2);   // 256KB
    if (o > ws_size) return;   // fail loudly

    dim3 b256(256);
    const int gN = (N_NODES + 255) / 256;
    const int gE = (E_EDGES + 255) / 256;

    // degrees + CSR
    k_zero_int<<<gN, b256, 0, stream>>>(cnt, N_NODES);
    k_deg_init<<<gN, b256, 0, stream>>>(dinv);
    k_deg_acc<<<gE, b256, 0, stream>>>(dst, ew, dinv);
    k_deg_fin<<<gN, b256, 0, stream>>>(dinv);
    k_hist<<<gE, b256, 0, stream>>>(dst, cnt);
    k_scan<<<1, 1024, 0, stream>>>(cnt, off, pos);
    k_fill<<<gE, b256, 0, stream>>>(src, dst, ew, dinv, pos, csr_s, csr_w);

    // MLP weight prep (BN folded, bf16 hi/lo, MFMA fragment layout)
    k_prep_w<<<(4 * 2 * 4 * 256 * 8) / 256, b256, 0, stream>>>(lw0, bg0, bv0, C_DIM, 4 * 2 * 4 * 256 * 8, W0p);
    k_prep_w<<<(8 * 2 * 4 * 256 * 8) / 256, b256, 0, stream>>>(lw1, bg1, bv1, H_DIM, 8 * 2 * 4 * 256 * 8, W1p);
    k_prep_shift<<<1, 512, 0, stream>>>(lb0, bg0, bb0, bm0, bv0, lb1, bg1, bb1, bm1, bv1, shift0, shift1);

    const int xw_grid = (N_NODES + 31) / 32;
    const int gg = (N_NODES * 64) / 256;
    // layer 0
    k_gru<<<C_DIM, 128, 0, stream>>>(w_init[0], w_ih[0], w_hh[0], b_ih[0], b_hh[0], w_ev);
    k_xw<0><<<xw_grid, b256, 0, stream>>>(X, w_ev, dinv, bufA, bufB);
    k_gather<<<gg, b256, 0, stream>>>(bufA, off, csr_s, csr_w, bufB);
    // layer 1
    k_gru<<<C_DIM, 128, 0, stream>>>(w_init[1], w_ih[1], w_hh[1], b_ih[1], b_hh[1], w_ev);
    k_xw<1><<<xw_grid, b256, 0, stream>>>(bufB, w_ev, dinv, bufA, bufB);
    k_gather<<<gg, b256, 0, stream>>>(bufA, off, csr_s, csr_w, bufB);
    // fused MFMA MLP
    k_mlp<<<Q_PAIRS / 32, b256, 0, stream>>>(bufB, e1, e2, W0p, W1p, shift0, shift1,
                                             lw2, lb2, (float*)d_out);
}

// Round 4
// 1174.690 us; speedup vs baseline: 7.1562x; 1.1385x over previous
//
#include <hip/hip_runtime.h>
#include <math.h>

#define N_NODES 50000
#define C_DIM   128
#define E_EDGES 1600000
#define Q_PAIRS 500000
#define H_DIM   256
#define N_CLS   2
#define BN_EPS  1e-5f

typedef __attribute__((ext_vector_type(8))) short bf16x8;
typedef __attribute__((ext_vector_type(4))) short s16x4;
typedef __attribute__((ext_vector_type(4))) float f32x4;

__device__ __forceinline__ unsigned short f2bf(float x) {   // RNE f32->bf16 bits
    unsigned u = __float_as_uint(x);
    u += 0x7fffu + ((u >> 16) & 1u);
    return (unsigned short)(u >> 16);
}
__device__ __forceinline__ float bf2f(unsigned short h) {
    return __uint_as_float(((unsigned)h) << 16);
}

// ---------------- init + degree/hist (fused per-edge passes) ----------------
__global__ __launch_bounds__(256) void k_init(float* deg, int* cnt) {
    int i = blockIdx.x * 256 + threadIdx.x;
    if (i < N_NODES) { deg[i] = 1.0f; cnt[i] = 0; }   // deg: +1 self loop
}
__global__ __launch_bounds__(256) void k_deg_hist(const int* __restrict__ dst,
                                                  const float* __restrict__ ew,
                                                  float* deg, int* cnt) {
    int e = blockIdx.x * 256 + threadIdx.x;
    if (e < E_EDGES) {
        int d = dst[e];
        unsafeAtomicAdd(&deg[d], ew[e]);
        atomicAdd(&cnt[d], 1);
    }
}
__global__ __launch_bounds__(256) void k_deg_fin(float* deg) {
    int i = blockIdx.x * 256 + threadIdx.x;
    if (i < N_NODES) deg[i] = rsqrtf(deg[i]);
}

// ---------------- CSR build ----------------
__global__ __launch_bounds__(1024) void k_scan(const int* __restrict__ cnt,
                                               int* __restrict__ off,
                                               int* __restrict__ pos) {
    __shared__ int pa[1024], pb[1024];
    int t = threadIdx.x;
    const int CH = (N_NODES + 1023) / 1024;   // 49
    int base = t * CH;
    int s = 0;
    for (int i = 0; i < CH; ++i) { int x = base + i; if (x < N_NODES) s += cnt[x]; }
    pa[t] = s;
    __syncthreads();
    int* sp = pa; int* dp = pb;
    for (int o = 1; o < 1024; o <<= 1) {
        int v = sp[t] + ((t >= o) ? sp[t - o] : 0);
        dp[t] = v;
        __syncthreads();
        int* tmp = sp; sp = dp; dp = tmp;
    }
    int run = (t == 0) ? 0 : sp[t - 1];
    for (int i = 0; i < CH; ++i) {
        int x = base + i;
        if (x < N_NODES) { off[x] = run; pos[x] = run; run += cnt[x]; }
    }
    if (t == 1023) off[N_NODES] = sp[1023];
}

__global__ __launch_bounds__(256) void k_fill(const int* __restrict__ src,
                                              const int* __restrict__ dst,
                                              const float* __restrict__ ew,
                                              const float* __restrict__ dinv,
                                              int* pos,
                                              int* __restrict__ csr_s,
                                              float* __restrict__ csr_w) {
    int e = blockIdx.x * 256 + threadIdx.x;
    if (e >= E_EDGES) return;
    int s = src[e], d = dst[e];
    int slot = atomicAdd(&pos[d], 1);
    csr_s[slot] = s;
    csr_w[slot] = dinv[s] * ew[e] * dinv[d];
}

// ---------------- GRU weight evolution ----------------
__global__ __launch_bounds__(128) void k_gru(const float* __restrict__ w_init,
                                             const float* __restrict__ wih,
                                             const float* __restrict__ whh,
                                             const float* __restrict__ bih,
                                             const float* __restrict__ bhh,
                                             float* __restrict__ w_out) {
    __shared__ float xrow[C_DIM];
    int i = blockIdx.x, j = threadIdx.x;
    xrow[j] = w_init[i * C_DIM + j];
    __syncthreads();
    float gi[3], gh[3];
#pragma unroll
    for (int g = 0; g < 3; ++g) {
        const float* wi = wih + (size_t)(g * C_DIM + j) * C_DIM;
        const float* wh = whh + (size_t)(g * C_DIM + j) * C_DIM;
        float ai = 0.f, ah = 0.f;
        for (int k = 0; k < C_DIM; ++k) { ai += xrow[k] * wi[k]; ah += xrow[k] * wh[k]; }
        gi[g] = ai + bih[g * C_DIM + j];
        gh[g] = ah + bhh[g * C_DIM + j];
    }
    float r = 1.f / (1.f + expf(-(gi[0] + gh[0])));
    float z = 1.f / (1.f + expf(-(gi[1] + gh[1])));
    float n = tanhf(gi[2] + r * gh[2]);
    w_out[i * C_DIM + j] = (1.f - z) * n + z * xrow[j];
}

// ---------------- xw = x @ w ; outinit = xw * dinv^2 ----------------
template <int RELU_IN>
__global__ __launch_bounds__(256) void k_xw(const float* x,
                                            const float* __restrict__ w,
                                            const float* __restrict__ dinv,
                                            float* __restrict__ xw,
                                            float* outinit) {
    __shared__ float wl[32 * C_DIM];
    __shared__ float xl[32 * C_DIM];
    int t = threadIdx.x;
    int r0 = blockIdx.x * 32;
    for (int i = t; i < 32 * C_DIM; i += 256) {
        int r = r0 + (i >> 7);
        float v = (r < N_NODES) ? x[(size_t)r * C_DIM + (i & 127)] : 0.f;
        if (RELU_IN) v = fmaxf(v, 0.f);
        xl[i] = v;
    }
    int tc = t & 31;
    int tr = (t >> 5) << 2;
    float acc[4][4] = {};
    for (int k0 = 0; k0 < C_DIM; k0 += 32) {
        __syncthreads();
        for (int i = t; i < 32 * C_DIM; i += 256)
            wl[i] = w[(size_t)(k0 + (i >> 7)) * C_DIM + (i & 127)];
        __syncthreads();
        for (int kk = 0; kk < 32; ++kk) {
            float wv[4], xv[4];
#pragma unroll
            for (int c = 0; c < 4; ++c) wv[c] = wl[kk * C_DIM + tc + 32 * c];
#pragma unroll
            for (int rr = 0; rr < 4; ++rr) xv[rr] = xl[(tr + rr) * C_DIM + k0 + kk];
#pragma unroll
            for (int rr = 0; rr < 4; ++rr)
#pragma unroll
                for (int c = 0; c < 4; ++c) acc[rr][c] += xv[rr] * wv[c];
        }
    }
#pragma unroll
    for (int rr = 0; rr < 4; ++rr) {
        int r = r0 + tr + rr;
        if (r < N_NODES) {
            float di = dinv[r];
            float d2 = di * di;
#pragma unroll
            for (int c = 0; c < 4; ++c) {
                size_t o = (size_t)r * C_DIM + tc + 32 * c;
                float v = acc[rr][c];
                xw[o] = v;
                outinit[o] = v * d2;
            }
        }
    }
}

// ---------------- CSR gather: io[n] += sum_e w_e * xw[src_e] ----------------
// 2 nodes per wave: 32 lanes x float4 per node; edge loop unrolled x4 (MLP)
__global__ __launch_bounds__(256) void k_gather(const float* __restrict__ xw,
                                                const int* __restrict__ off,
                                                const int* __restrict__ csr_s,
                                                const float* __restrict__ csr_w,
                                                float* __restrict__ io) {
    int tid = blockIdx.x * 256 + threadIdx.x;
    int n = tid >> 5;
    if (n >= N_NODES) return;
    int c = (tid & 31) << 2;
    int i = off[n], e = off[n + 1];
    float* p = io + (size_t)n * C_DIM + c;
    float4 acc = *(const float4*)p;
    for (; i + 4 <= e; i += 4) {
        int s0 = csr_s[i], s1 = csr_s[i + 1], s2 = csr_s[i + 2], s3 = csr_s[i + 3];
        float w0 = csr_w[i], w1 = csr_w[i + 1], w2 = csr_w[i + 2], w3 = csr_w[i + 3];
        float4 v0 = *(const float4*)(xw + (size_t)s0 * C_DIM + c);
        float4 v1 = *(const float4*)(xw + (size_t)s1 * C_DIM + c);
        float4 v2 = *(const float4*)(xw + (size_t)s2 * C_DIM + c);
        float4 v3 = *(const float4*)(xw + (size_t)s3 * C_DIM + c);
        acc.x += w0 * v0.x + w1 * v1.x + w2 * v2.x + w3 * v3.x;
        acc.y += w0 * v0.y + w1 * v1.y + w2 * v2.y + w3 * v3.y;
        acc.z += w0 * v0.z + w1 * v1.z + w2 * v2.z + w3 * v3.z;
        acc.w += w0 * v0.w + w1 * v1.w + w2 * v2.w + w3 * v3.w;
    }
    for (; i < e; ++i) {
        int s = csr_s[i];
        float w = csr_w[i];
        float4 v = *(const float4*)(xw + (size_t)s * C_DIM + c);
        acc.x += w * v.x; acc.y += w * v.y; acc.z += w * v.z; acc.w += w * v.w;
    }
    *(float4*)p = acc;
}

// ---------------- weight prep: BN-folded bf16 hi/lo in MFMA A-fragment layout ----------------
// out idx: [kb][plane(hi=0,lo=1)][kgrp(4)][col(256)][e(8)], k = kb*32+kgrp*8+e
__global__ __launch_bounds__(256) void k_prep_w(const float* __restrict__ w,
                                                const float* __restrict__ g,
                                                const float* __restrict__ v,
                                                int kdim, int total,
                                                unsigned short* __restrict__ outp) {
    int idx = blockIdx.x * 256 + threadIdx.x;
    if (idx >= total) return;
    int e = idx & 7, col = (idx >> 3) & 255, kgrp = (idx >> 11) & 3;
    int plane = (idx >> 13) & 1, kb = idx >> 14;
    int k = kb * 32 + kgrp * 8 + e;
    float sc = g[col] * rsqrtf(v[col] + BN_EPS);
    float x = w[(size_t)col * kdim + k] * sc;
    unsigned short hi = f2bf(x);
    outp[idx] = plane ? f2bf(x - bf2f(hi)) : hi;
}

__global__ __launch_bounds__(512) void k_prep_shift(
    const float* __restrict__ lb0, const float* __restrict__ bg0, const float* __restrict__ bb0,
    const float* __restrict__ bm0, const float* __restrict__ bv0,
    const float* __restrict__ lb1, const float* __restrict__ bg1, const float* __restrict__ bb1,
    const float* __restrict__ bm1, const float* __restrict__ bv1,
    float* __restrict__ shift0, float* __restrict__ shift1) {
    int j = threadIdx.x;
    if (j < 256) {
        float sc = bg0[j] * rsqrtf(bv0[j] + BN_EPS);
        shift0[j] = (lb0[j] - bm0[j]) * sc + bb0[j];
    } else {
        int i = j - 256;
        float sc = bg1[i] * rsqrtf(bv1[i] + BN_EPS);
        shift1[i] = (lb1[i] - bm1[i]) * sc + bb1[i];
    }
}

// ---------------- fused query MLP (bf16 hi/lo MFMA) ----------------
// 64 queries/block, 512 threads, 8 waves: wave = qg*2+ch, qg in 0..3 (16-q
// group), ch in 0..1 (128-col half). Split-plane weight staging: 16 KB strip.
// LDS = 16 KB strip + 64 KB l1b = 80 KB -> 2 blocks/CU (16 waves, 50% occ).
__global__ __launch_bounds__(512, 4) void k_mlp(const float* __restrict__ y,
                                             const int* __restrict__ e1,
                                             const int* __restrict__ e2,
                                             const unsigned short* __restrict__ W0p,
                                             const unsigned short* __restrict__ W1p,
                                             const float* __restrict__ shift0,
                                             const float* __restrict__ shift1,
                                             const float* __restrict__ w2,
                                             const float* __restrict__ b2,
                                             float* __restrict__ out) {
    __shared__ __align__(16) char smem[81920];
    unsigned short* strip = (unsigned short*)smem;          // 16KB: [kgrp][col][8] (one plane)
    unsigned short* l1b = (unsigned short*)(smem + 16384);  // 64KB: [plane][qrow64][256] swizzled
    float* red = (float*)smem;                              // aliases strip (layer-3 only)

    const int t = threadIdx.x;
    const int lane = t & 63;
    const int wave = t >> 6;
    const int qg = wave >> 1, ch = wave & 1;
    const int l16 = lane & 15, kg = lane >> 4;
    const int qrow = qg * 16 + l16;                          // 0..63
    const int qb = blockIdx.x * 64;
    int qi = qb + qrow; if (qi >= Q_PAIRS) qi = Q_PAIRS - 1; // tail clamp
    const float* ya = y + (size_t)e1[qi] * C_DIM;
    const float* yb = y + (size_t)e2[qi] * C_DIM;
    char* sdst = smem + wave * 2048;                         // linear stage dest

    f32x4 acc1[8];
#pragma unroll
    for (int i = 0; i < 8; ++i) acc1[i] = 0.f;

    // ---- layer 1: K = 128 (4 k-blocks of 32), split-plane staging ----
    for (int kb = 0; kb < 4; ++kb) {
        __syncthreads();   // prev strip consumed
        {   // stage hi plane (16 KB)
            const char* gsrc = (const char*)W0p + (size_t)(kb * 2) * 16384 + wave * 2048 + lane * 16;
            __builtin_amdgcn_global_load_lds((const __attribute__((address_space(1))) void*)gsrc,
                                             (__attribute__((address_space(3))) void*)sdst, 16, 0, 0);
            __builtin_amdgcn_global_load_lds((const __attribute__((address_space(1))) void*)(gsrc + 1024),
                                             (__attribute__((address_space(3))) void*)(sdst + 1024), 16, 0, 0);
        }
        // B-frag: H[q][k-chunk] from global y (overlaps staging)
        int k0 = kb * 32 + kg * 8;
        f32x4 a0 = *(const f32x4*)(ya + k0);
        f32x4 a1 = *(const f32x4*)(ya + k0 + 4);
        f32x4 b0v = *(const f32x4*)(yb + k0);
        f32x4 b1v = *(const f32x4*)(yb + k0 + 4);
        bf16x8 bh, bl;
#pragma unroll
        for (int e = 0; e < 4; ++e) {
            float h0 = fmaxf(a0[e], 0.f) * fmaxf(b0v[e], 0.f);
            unsigned short hh0 = f2bf(h0);
            bh[e] = (short)hh0; bl[e] = (short)f2bf(h0 - bf2f(hh0));
            float h1 = fmaxf(a1[e], 0.f) * fmaxf(b1v[e], 0.f);
            unsigned short hh1 = f2bf(h1);
            bh[e + 4] = (short)hh1; bl[e + 4] = (short)f2bf(h1 - bf2f(hh1));
        }
        __syncthreads();   // hi strip ready
#pragma unroll
        for (int jc8 = 0; jc8 < 8; ++jc8) {
            int col = (ch * 8 + jc8) * 16 + l16;
            bf16x8 ahi = *(const bf16x8*)&strip[kg * 2048 + col * 8];
            acc1[jc8] = __builtin_amdgcn_mfma_f32_16x16x32_bf16(ahi, bh, acc1[jc8], 0, 0, 0);
            acc1[jc8] = __builtin_amdgcn_mfma_f32_16x16x32_bf16(ahi, bl, acc1[jc8], 0, 0, 0);
        }
        __syncthreads();   // hi strip consumed
        {   // stage lo plane
            const char* gsrc = (const char*)W0p + (size_t)(kb * 2 + 1) * 16384 + wave * 2048 + lane * 16;
            __builtin_amdgcn_global_load_lds((const __attribute__((address_space(1))) void*)gsrc,
                                             (__attribute__((address_space(3))) void*)sdst, 16, 0, 0);
            __builtin_amdgcn_global_load_lds((const __attribute__((address_space(1))) void*)(gsrc + 1024),
                                             (__attribute__((address_space(3))) void*)(sdst + 1024), 16, 0, 0);
        }
        __syncthreads();   // lo strip ready
#pragma unroll
        for (int jc8 = 0; jc8 < 8; ++jc8) {
            int col = (ch * 8 + jc8) * 16 + l16;
            bf16x8 alo = *(const bf16x8*)&strip[kg * 2048 + col * 8];
            acc1[jc8] = __builtin_amdgcn_mfma_f32_16x16x32_bf16(alo, bh, acc1[jc8], 0, 0, 0);
        }
    }

    // ---- epilogue 1: BN-shift + relu -> l1b (bf16 hi/lo, XOR-swizzled granules) ----
#pragma unroll
    for (int jc8 = 0; jc8 < 8; ++jc8) {
        int jc = ch * 8 + jc8;
        int j0 = jc * 16 + kg * 4;
        f32x4 sh = *(const f32x4*)(shift0 + j0);
        short hv[4], lv[4];
#pragma unroll
        for (int r = 0; r < 4; ++r) {
            float v = fmaxf(acc1[jc8][r] + sh[r], 0.f);
            unsigned short hh = f2bf(v);
            hv[r] = (short)hh; lv[r] = (short)f2bf(v - bf2f(hh));
        }
        int g = jc * 2 + (kg >> 1);
        int idx = qrow * 256 + ((g ^ (qrow & 7)) * 8) + (kg & 1) * 4;
        s16x4 th; th[0] = hv[0]; th[1] = hv[1]; th[2] = hv[2]; th[3] = hv[3];
        s16x4 tl; tl[0] = lv[0]; tl[1] = lv[1]; tl[2] = lv[2]; tl[3] = lv[3];
        *(s16x4*)&l1b[idx] = th;
        *(s16x4*)&l1b[16384 + idx] = tl;
    }

    // ---- layer 2: K = 256 (8 k-blocks), split-plane staging ----
    f32x4 acc2[8];
#pragma unroll
    for (int i = 0; i < 8; ++i) acc2[i] = 0.f;
    for (int kb = 0; kb < 8; ++kb) {
        __syncthreads();   // prev strip consumed + (kb==0) l1b fully written
        {   // stage hi plane
            const char* gsrc = (const char*)W1p + (size_t)(kb * 2) * 16384 + wave * 2048 + lane * 16;
            __builtin_amdgcn_global_load_lds((const __attribute__((address_space(1))) void*)gsrc,
                                             (__attribute__((address_space(3))) void*)sdst, 16, 0, 0);
            __builtin_amdgcn_global_load_lds((const __attribute__((address_space(1))) void*)(gsrc + 1024),
                                             (__attribute__((address_space(3))) void*)(sdst + 1024), 16, 0, 0);
        }
        int gidx = qrow * 256 + (((kb * 4 + kg) ^ (qrow & 7)) * 8);
        bf16x8 bh2 = *(const bf16x8*)&l1b[gidx];
        bf16x8 bl2 = *(const bf16x8*)&l1b[16384 + gidx];
        __syncthreads();   // hi strip ready
#pragma unroll
        for (int jc8 = 0; jc8 < 8; ++jc8) {
            int col = (ch * 8 + jc8) * 16 + l16;
            bf16x8 ahi = *(const bf16x8*)&strip[kg * 2048 + col * 8];
            acc2[jc8] = __builtin_amdgcn_mfma_f32_16x16x32_bf16(ahi, bh2, acc2[jc8], 0, 0, 0);
            acc2[jc8] = __builtin_amdgcn_mfma_f32_16x16x32_bf16(ahi, bl2, acc2[jc8], 0, 0, 0);
        }
        __syncthreads();   // hi strip consumed
        {   // stage lo plane
            const char* gsrc = (const char*)W1p + (size_t)(kb * 2 + 1) * 16384 + wave * 2048 + lane * 16;
            __builtin_amdgcn_global_load_lds((const __attribute__((address_space(1))) void*)gsrc,
                                             (__attribute__((address_space(3))) void*)sdst, 16, 0, 0);
            __builtin_amdgcn_global_load_lds((const __attribute__((address_space(1))) void*)(gsrc + 1024),
                                             (__attribute__((address_space(3))) void*)(sdst + 1024), 16, 0, 0);
        }
        __syncthreads();   // lo strip ready
#pragma unroll
        for (int jc8 = 0; jc8 < 8; ++jc8) {
            int col = (ch * 8 + jc8) * 16 + l16;
            bf16x8 alo = *(const bf16x8*)&strip[kg * 2048 + col * 8];
            acc2[jc8] = __builtin_amdgcn_mfma_f32_16x16x32_bf16(alo, bh2, acc2[jc8], 0, 0, 0);
        }
    }

    // ---- layer 3: BN-shift + relu + 256->2 + log_softmax ----
    float p0 = 0.f, p1 = 0.f;
#pragma unroll
    for (int jc8 = 0; jc8 < 8; ++jc8) {
        int j0 = (ch * 8 + jc8) * 16 + kg * 4;
        f32x4 sh = *(const f32x4*)(shift1 + j0);
        f32x4 wa = *(const f32x4*)(w2 + j0);
        f32x4 wb = *(const f32x4*)(w2 + H_DIM + j0);
#pragma unroll
        for (int r = 0; r < 4; ++r) {
            float v = fmaxf(acc2[jc8][r] + sh[r], 0.f);
            p0 += v * wa[r];
            p1 += v * wb[r];
        }
    }
    p0 += __shfl_xor(p0, 16, 64); p0 += __shfl_xor(p0, 32, 64);
    p1 += __shfl_xor(p1, 16, 64); p1 += __shfl_xor(p1, 32, 64);
    __syncthreads();   // strip reads done; reuse as red
    if (lane < 16) {
        red[(wave * 16 + lane) * 2 + 0] = p0;
        red[(wave * 16 + lane) * 2 + 1] = p1;
    }
    __syncthreads();
    if (ch == 0 && lane < 16) {
        int q = qb + qg * 16 + lane;
        if (q < Q_PAIRS) {
            float l0 = red[(wave * 16 + lane) * 2 + 0] + red[((wave + 1) * 16 + lane) * 2 + 0] + b2[0];
            float l1v = red[(wave * 16 + lane) * 2 + 1] + red[((wave + 1) * 16 + lane) * 2 + 1] + b2[1];
            float mx = fmaxf(l0, l1v);
            float lse = mx + logf(expf(l0 - mx) + expf(l1v - mx));
            float2 o; o.x = l0 - lse; o.y = l1v - lse;
            *(float2*)(out + (size_t)q * N_CLS) = o;
        }
    }
}

// ---------------- launch ----------------
extern "C" void kernel_launch(void* const* d_in, const int* in_sizes, int n_in,
                              void* d_out, int out_size, void* d_ws, size_t ws_size,
                              hipStream_t stream) {
    const float* X  = (const float*)d_in[0];
    const int*   ei = (const int*)d_in[1];
    const float* ew = (const float*)d_in[2];
    const int*   e1 = (const int*)d_in[3];
    const int*   e2 = (const int*)d_in[4];
    const float* w_init[2] = {(const float*)d_in[5],  (const float*)d_in[10]};
    const float* w_ih[2]   = {(const float*)d_in[6],  (const float*)d_in[11]};
    const float* w_hh[2]   = {(const float*)d_in[7],  (const float*)d_in[12]};
    const float* b_ih[2]   = {(const float*)d_in[8],  (const float*)d_in[13]};
    const float* b_hh[2]   = {(const float*)d_in[9],  (const float*)d_in[14]};
    const float* lw0 = (const float*)d_in[15]; const float* lb0 = (const float*)d_in[16];
    const float* lw1 = (const float*)d_in[17]; const float* lb1 = (const float*)d_in[18];
    const float* lw2 = (const float*)d_in[19]; const float* lb2 = (const float*)d_in[20];
    const float* bg0 = (const float*)d_in[21]; const float* bb0 = (const float*)d_in[22];
    const float* bm0 = (const float*)d_in[23]; const float* bv0 = (const float*)d_in[24];
    const float* bg1 = (const float*)d_in[25]; const float* bb1 = (const float*)d_in[26];
    const float* bm1 = (const float*)d_in[27]; const float* bv1 = (const float*)d_in[28];
    const int* src = ei;
    const int* dst = ei + E_EDGES;

    char* ws = (char*)d_ws;
    size_t o = 0;
    auto alloc = [&](size_t bytes) { char* p = ws + o; o += (bytes + 63) & ~(size_t)63; return p; };
    float* bufA   = (float*)alloc((size_t)N_NODES * C_DIM * 4);
    float* bufB   = (float*)alloc((size_t)N_NODES * C_DIM * 4);
    float* dinv   = (float*)alloc(N_NODES * 4);
    float* w_ev   = (float*)alloc(C_DIM * C_DIM * 4);
    float* csr_w  = (float*)alloc((size_t)E_EDGES * 4);
    float* shift0 = (float*)alloc(H_DIM * 4);
    float* shift1 = (float*)alloc(H_DIM * 4);
    int*   cnt    = (int*)alloc(N_NODES * 4);
    int*   pos    = (int*)alloc(N_NODES * 4);
    int*   off    = (int*)alloc((N_NODES + 1) * 4);
    int*   csr_s  = (int*)alloc((size_t)E_EDGES * 4);
    unsigned short* W0p = (unsigned short*)alloc(4 * 2 * 4 * 256 * 8 * 2);   // 128KB
    unsigned short* W1p = (unsigned short*)alloc(8 * 2 * 4 * 256 * 8 * 2);   // 256KB
    if (o > ws_size) return;   // fail loudly

    dim3 b256(256);
    const int gN = (N_NODES + 255) / 256;
    const int gE = (E_EDGES + 255) / 256;

    // degrees + CSR
    k_init<<<gN, b256, 0, stream>>>(dinv, cnt);
    k_deg_hist<<<gE, b256, 0, stream>>>(dst, ew, dinv, cnt);
    k_deg_fin<<<gN, b256, 0, stream>>>(dinv);
    k_scan<<<1, 1024, 0, stream>>>(cnt, off, pos);
    k_fill<<<gE, b256, 0, stream>>>(src, dst, ew, dinv, pos, csr_s, csr_w);

    // MLP weight prep (BN folded, bf16 hi/lo, MFMA fragment layout)
    k_prep_w<<<(4 * 2 * 4 * 256 * 8) / 256, b256, 0, stream>>>(lw0, bg0, bv0, C_DIM, 4 * 2 * 4 * 256 * 8, W0p);
    k_prep_w<<<(8 * 2 * 4 * 256 * 8) / 256, b256, 0, stream>>>(lw1, bg1, bv1, H_DIM, 8 * 2 * 4 * 256 * 8, W1p);
    k_prep_shift<<<1, 512, 0, stream>>>(lb0, bg0, bb0, bm0, bv0, lb1, bg1, bb1, bm1, bv1, shift0, shift1);

    const int xw_grid = (N_NODES + 31) / 32;
    const int gg = (N_NODES * 32 + 255) / 256;
    // layer 0
    k_gru<<<C_DIM, 128, 0, stream>>>(w_init[0], w_ih[0], w_hh[0], b_ih[0], b_hh[0], w_ev);
    k_xw<0><<<xw_grid, b256, 0, stream>>>(X, w_ev, dinv, bufA, bufB);
    k_gather<<<gg, b256, 0, stream>>>(bufA, off, csr_s, csr_w, bufB);
    // layer 1
    k_gru<<<C_DIM, 128, 0, stream>>>(w_init[1], w_ih[1], w_hh[1], b_ih[1], b_hh[1], w_ev);
    k_xw<1><<<xw_grid, b256, 0, stream>>>(bufB, w_ev, dinv, bufA, bufB);
    k_gather<<<gg, b256, 0, stream>>>(bufA, off, csr_s, csr_w, bufB);
    // fused MFMA MLP (64 queries/block)
    k_mlp<<<(Q_PAIRS + 63) / 64, dim3(512), 0, stream>>>(bufB, e1, e2, W0p, W1p, shift0, shift1,
                                                         lw2, lb2, (float*)d_out);
}

// Round 5
// 1048.807 us; speedup vs baseline: 8.0152x; 1.1200x over previous
//
#include <hip/hip_runtime.h>
#include <math.h>

#define N_NODES 50000
#define C_DIM   128
#define E_EDGES 1600000
#define Q_PAIRS 500000
#define H_DIM   256
#define N_CLS   2
#define BN_EPS  1e-5f

typedef __attribute__((ext_vector_type(8))) short bf16x8;
typedef __attribute__((ext_vector_type(4))) short s16x4;
typedef __attribute__((ext_vector_type(4))) float f32x4;

__device__ __forceinline__ unsigned short f2bf(float x) {   // RNE f32->bf16 bits
    unsigned u = __float_as_uint(x);
    u += 0x7fffu + ((u >> 16) & 1u);
    return (unsigned short)(u >> 16);
}
__device__ __forceinline__ float bf2f(unsigned short h) {
    return __uint_as_float(((unsigned)h) << 16);
}

// ---------------- init + degree/hist (fused per-edge passes) ----------------
__global__ __launch_bounds__(256) void k_init(float* deg, int* cnt) {
    int i = blockIdx.x * 256 + threadIdx.x;
    if (i < N_NODES) { deg[i] = 1.0f; cnt[i] = 0; }   // deg: +1 self loop
}
__global__ __launch_bounds__(256) void k_deg_hist(const int* __restrict__ dst,
                                                  const float* __restrict__ ew,
                                                  float* deg, int* cnt) {
    int e = blockIdx.x * 256 + threadIdx.x;
    if (e < E_EDGES) {
        int d = dst[e];
        unsafeAtomicAdd(&deg[d], ew[e]);
        atomicAdd(&cnt[d], 1);
    }
}
__global__ __launch_bounds__(256) void k_deg_fin(float* deg) {
    int i = blockIdx.x * 256 + threadIdx.x;
    if (i < N_NODES) deg[i] = rsqrtf(deg[i]);
}

// ---------------- CSR build ----------------
__global__ __launch_bounds__(1024) void k_scan(const int* __restrict__ cnt,
                                               int* __restrict__ off,
                                               int* __restrict__ pos) {
    __shared__ int pa[1024], pb[1024];
    int t = threadIdx.x;
    const int CH = (N_NODES + 1023) / 1024;   // 49
    int base = t * CH;
    int s = 0;
    for (int i = 0; i < CH; ++i) { int x = base + i; if (x < N_NODES) s += cnt[x]; }
    pa[t] = s;
    __syncthreads();
    int* sp = pa; int* dp = pb;
    for (int o = 1; o < 1024; o <<= 1) {
        int v = sp[t] + ((t >= o) ? sp[t - o] : 0);
        dp[t] = v;
        __syncthreads();
        int* tmp = sp; sp = dp; dp = tmp;
    }
    int run = (t == 0) ? 0 : sp[t - 1];
    for (int i = 0; i < CH; ++i) {
        int x = base + i;
        if (x < N_NODES) { off[x] = run; pos[x] = run; run += cnt[x]; }
    }
    if (t == 1023) off[N_NODES] = sp[1023];
}

// packed CSR entry: .x = src node, .y = float weight bits
__global__ __launch_bounds__(256) void k_fill(const int* __restrict__ src,
                                              const int* __restrict__ dst,
                                              const float* __restrict__ ew,
                                              const float* __restrict__ dinv,
                                              int* pos,
                                              int2* __restrict__ csr) {
    int e = blockIdx.x * 256 + threadIdx.x;
    if (e >= E_EDGES) return;
    int s = src[e], d = dst[e];
    int slot = atomicAdd(&pos[d], 1);
    int2 p;
    p.x = s;
    p.y = __float_as_int(dinv[s] * ew[e] * dinv[d]);
    csr[slot] = p;
}

// ---------------- GRU weight evolution ----------------
__global__ __launch_bounds__(128) void k_gru(const float* __restrict__ w_init,
                                             const float* __restrict__ wih,
                                             const float* __restrict__ whh,
                                             const float* __restrict__ bih,
                                             const float* __restrict__ bhh,
                                             float* __restrict__ w_out) {
    __shared__ float xrow[C_DIM];
    int i = blockIdx.x, j = threadIdx.x;
    xrow[j] = w_init[i * C_DIM + j];
    __syncthreads();
    float gi[3], gh[3];
#pragma unroll
    for (int g = 0; g < 3; ++g) {
        const float* wi = wih + (size_t)(g * C_DIM + j) * C_DIM;
        const float* wh = whh + (size_t)(g * C_DIM + j) * C_DIM;
        float ai = 0.f, ah = 0.f;
        for (int k = 0; k < C_DIM; ++k) { ai += xrow[k] * wi[k]; ah += xrow[k] * wh[k]; }
        gi[g] = ai + bih[g * C_DIM + j];
        gh[g] = ah + bhh[g * C_DIM + j];
    }
    float r = 1.f / (1.f + expf(-(gi[0] + gh[0])));
    float z = 1.f / (1.f + expf(-(gi[1] + gh[1])));
    float n = tanhf(gi[2] + r * gh[2]);
    w_out[i * C_DIM + j] = (1.f - z) * n + z * xrow[j];
}

// ---------------- xw = x @ w ; outinit = xw * dinv^2 ----------------
template <int RELU_IN>
__global__ __launch_bounds__(256) void k_xw(const float* x,
                                            const float* __restrict__ w,
                                            const float* __restrict__ dinv,
                                            float* __restrict__ xw,
                                            float* outinit) {
    __shared__ float wl[32 * C_DIM];
    __shared__ float xl[32 * C_DIM];
    int t = threadIdx.x;
    int r0 = blockIdx.x * 32;
    for (int i = t; i < 32 * C_DIM; i += 256) {
        int r = r0 + (i >> 7);
        float v = (r < N_NODES) ? x[(size_t)r * C_DIM + (i & 127)] : 0.f;
        if (RELU_IN) v = fmaxf(v, 0.f);
        xl[i] = v;
    }
    int tc = t & 31;
    int tr = (t >> 5) << 2;
    float acc[4][4] = {};
    for (int k0 = 0; k0 < C_DIM; k0 += 32) {
        __syncthreads();
        for (int i = t; i < 32 * C_DIM; i += 256)
            wl[i] = w[(size_t)(k0 + (i >> 7)) * C_DIM + (i & 127)];
        __syncthreads();
        for (int kk = 0; kk < 32; ++kk) {
            float wv[4], xv[4];
#pragma unroll
            for (int c = 0; c < 4; ++c) wv[c] = wl[kk * C_DIM + tc + 32 * c];
#pragma unroll
            for (int rr = 0; rr < 4; ++rr) xv[rr] = xl[(tr + rr) * C_DIM + k0 + kk];
#pragma unroll
            for (int rr = 0; rr < 4; ++rr)
#pragma unroll
                for (int c = 0; c < 4; ++c) acc[rr][c] += xv[rr] * wv[c];
        }
    }
#pragma unroll
    for (int rr = 0; rr < 4; ++rr) {
        int r = r0 + tr + rr;
        if (r < N_NODES) {
            float di = dinv[r];
            float d2 = di * di;
#pragma unroll
            for (int c = 0; c < 4; ++c) {
                size_t o = (size_t)r * C_DIM + tc + 32 * c;
                float v = acc[rr][c];
                xw[o] = v;
                outinit[o] = v * d2;
            }
        }
    }
}

// ---------------- CSR gather: io[n] += sum_e w_e * xw[src_e] ----------------
// 2 nodes per wave: 32 lanes x float4 per node; edge loop unrolled x4 (MLP)
__global__ __launch_bounds__(256) void k_gather(const float* __restrict__ xw,
                                                const int* __restrict__ off,
                                                const int2* __restrict__ csr,
                                                float* __restrict__ io) {
    int tid = blockIdx.x * 256 + threadIdx.x;
    int n = tid >> 5;
    if (n >= N_NODES) return;
    int c = (tid & 31) << 2;
    int i = off[n], e = off[n + 1];
    float* p = io + (size_t)n * C_DIM + c;
    float4 acc = *(const float4*)p;
    for (; i + 4 <= e; i += 4) {
        int2 p0 = csr[i], p1 = csr[i + 1], p2 = csr[i + 2], p3 = csr[i + 3];
        float4 v0 = *(const float4*)(xw + (size_t)p0.x * C_DIM + c);
        float4 v1 = *(const float4*)(xw + (size_t)p1.x * C_DIM + c);
        float4 v2 = *(const float4*)(xw + (size_t)p2.x * C_DIM + c);
        float4 v3 = *(const float4*)(xw + (size_t)p3.x * C_DIM + c);
        float w0 = __int_as_float(p0.y), w1 = __int_as_float(p1.y);
        float w2 = __int_as_float(p2.y), w3 = __int_as_float(p3.y);
        acc.x += w0 * v0.x + w1 * v1.x + w2 * v2.x + w3 * v3.x;
        acc.y += w0 * v0.y + w1 * v1.y + w2 * v2.y + w3 * v3.y;
        acc.z += w0 * v0.z + w1 * v1.z + w2 * v2.z + w3 * v3.z;
        acc.w += w0 * v0.w + w1 * v1.w + w2 * v2.w + w3 * v3.w;
    }
    for (; i < e; ++i) {
        int2 pe = csr[i];
        float w = __int_as_float(pe.y);
        float4 v = *(const float4*)(xw + (size_t)pe.x * C_DIM + c);
        acc.x += w * v.x; acc.y += w * v.y; acc.z += w * v.z; acc.w += w * v.w;
    }
    *(float4*)p = acc;
}

// ---------------- weight prep: BN-folded bf16 hi/lo in MFMA A-fragment layout ----------------
// out idx: [kb][plane(hi=0,lo=1)][kgrp(4)][col(256)][e(8)], k = kb*32+kgrp*8+e
__global__ __launch_bounds__(256) void k_prep_w(const float* __restrict__ w,
                                                const float* __restrict__ g,
                                                const float* __restrict__ v,
                                                int kdim, int total,
                                                unsigned short* __restrict__ outp) {
    int idx = blockIdx.x * 256 + threadIdx.x;
    if (idx >= total) return;
    int e = idx & 7, col = (idx >> 3) & 255, kgrp = (idx >> 11) & 3;
    int plane = (idx >> 13) & 1, kb = idx >> 14;
    int k = kb * 32 + kgrp * 8 + e;
    float sc = g[col] * rsqrtf(v[col] + BN_EPS);
    float x = w[(size_t)col * kdim + k] * sc;
    unsigned short hi = f2bf(x);
    outp[idx] = plane ? f2bf(x - bf2f(hi)) : hi;
}

__global__ __launch_bounds__(512) void k_prep_shift(
    const float* __restrict__ lb0, const float* __restrict__ bg0, const float* __restrict__ bb0,
    const float* __restrict__ bm0, const float* __restrict__ bv0,
    const float* __restrict__ lb1, const float* __restrict__ bg1, const float* __restrict__ bb1,
    const float* __restrict__ bm1, const float* __restrict__ bv1,
    float* __restrict__ shift0, float* __restrict__ shift1) {
    int j = threadIdx.x;
    if (j < 256) {
        float sc = bg0[j] * rsqrtf(bv0[j] + BN_EPS);
        shift0[j] = (lb0[j] - bm0[j]) * sc + bb0[j];
    } else {
        int i = j - 256;
        float sc = bg1[i] * rsqrtf(bv1[i] + BN_EPS);
        shift1[i] = (lb1[i] - bm1[i]) * sc + bb1[i];
    }
}

// ---------------- fused query MLP (bf16 hi/lo MFMA, dbuf strip pipeline) ----------------
// 64 queries/block, 512 threads, 8 waves: wave = qg*2+ch.
// LDS 64 KB -> 2 blocks/CU:
//   [0,16K)+[16K,32K): weight strip double-buffer (one bf16 plane = 16 KB)
//   [32K,64K): l1 activations HI plane, persistent ([64 rows][256] swizzled)
//   [0,32K):   l1 activations LO plane, transient (aliases strips; picked up
//              into 32 VGPRs/lane before layer-2 staging reuses the region)
// Per strip: STAGE(next -> buf^1); ds_read+MFMA(cur); barrier.  (T3-minimum)
__global__ __launch_bounds__(512, 4) void k_mlp(const float* __restrict__ y,
                                             const int* __restrict__ e1,
                                             const int* __restrict__ e2,
                                             const unsigned short* __restrict__ W0p,
                                             const unsigned short* __restrict__ W1p,
                                             const float* __restrict__ shift0,
                                             const float* __restrict__ shift1,
                                             const float* __restrict__ w2,
                                             const float* __restrict__ b2,
                                             float* __restrict__ out) {
    __shared__ __align__(16) char smem[65536];
    unsigned short* l1hi = (unsigned short*)(smem + 32768);
    unsigned short* l1lo = (unsigned short*)smem;
    float* red = (float*)smem;   // layer-3 only (strip region dead)

    const int t = threadIdx.x;
    const int lane = t & 63;
    const int wave = t >> 6;
    const int qg = wave >> 1, ch = wave & 1;
    const int l16 = lane & 15, kg = lane >> 4;
    const int qrow = qg * 16 + l16;                          // 0..63
    const int qb = blockIdx.x * 64;
    int qi = qb + qrow; if (qi >= Q_PAIRS) qi = Q_PAIRS - 1; // tail clamp
    const float* ya = y + (size_t)e1[qi] * C_DIM;
    const float* yb = y + (size_t)e2[qi] * C_DIM;

    auto STAGE = [&](const unsigned short* W, int sidx, int b) {
        const char* gsrc = (const char*)W + ((size_t)sidx << 14) + wave * 2048 + lane * 16;
        char* d = smem + (b << 14) + wave * 2048;
        __builtin_amdgcn_global_load_lds((const __attribute__((address_space(1))) void*)gsrc,
                                         (__attribute__((address_space(3))) void*)d, 16, 0, 0);
        __builtin_amdgcn_global_load_lds((const __attribute__((address_space(1))) void*)(gsrc + 1024),
                                         (__attribute__((address_space(3))) void*)(d + 1024), 16, 0, 0);
    };

    // ---- prologue: stage strip 0; build all h-fragments (hi/lo) in regs ----
    STAGE(W0p, 0, 0);
    bf16x8 bh[4], bl[4];
#pragma unroll
    for (int kb = 0; kb < 4; ++kb) {
        int k0 = kb * 32 + kg * 8;
        f32x4 a0 = *(const f32x4*)(ya + k0);
        f32x4 a1 = *(const f32x4*)(ya + k0 + 4);
        f32x4 b0v = *(const f32x4*)(yb + k0);
        f32x4 b1v = *(const f32x4*)(yb + k0 + 4);
#pragma unroll
        for (int e = 0; e < 4; ++e) {
            float h0 = fmaxf(a0[e], 0.f) * fmaxf(b0v[e], 0.f);
            unsigned short hh0 = f2bf(h0);
            bh[kb][e] = (short)hh0; bl[kb][e] = (short)f2bf(h0 - bf2f(hh0));
            float h1 = fmaxf(a1[e], 0.f) * fmaxf(b1v[e], 0.f);
            unsigned short hh1 = f2bf(h1);
            bh[kb][e + 4] = (short)hh1; bl[kb][e + 4] = (short)f2bf(h1 - bf2f(hh1));
        }
    }
    f32x4 acc1[8];
#pragma unroll
    for (int i = 0; i < 8; ++i) acc1[i] = 0.f;
    __syncthreads();   // strip 0 resident

    // ---- layer 1: 8 strips (kb 0..3 x {hi,lo}), pipelined ----
    int cur = 0;
#pragma unroll
    for (int s = 0; s < 8; ++s) {
        if (s < 7) STAGE(W0p, s + 1, cur ^ 1);
        const unsigned short* strip = (const unsigned short*)(smem + (cur << 14));
        const int kb = s >> 1;
#pragma unroll
        for (int jc8 = 0; jc8 < 8; ++jc8) {
            int col = (ch * 8 + jc8) * 16 + l16;
            bf16x8 a = *(const bf16x8*)&strip[kg * 2048 + col * 8];
            acc1[jc8] = __builtin_amdgcn_mfma_f32_16x16x32_bf16(a, bh[kb], acc1[jc8], 0, 0, 0);
            if ((s & 1) == 0)
                acc1[jc8] = __builtin_amdgcn_mfma_f32_16x16x32_bf16(a, bl[kb], acc1[jc8], 0, 0, 0);
        }
        __syncthreads();
        cur ^= 1;
    }

    // ---- epilogue 1: BN-shift + relu -> hi to l1hi, lo to l1lo (strip region dead) ----
#pragma unroll
    for (int jc8 = 0; jc8 < 8; ++jc8) {
        int jc = ch * 8 + jc8;
        int j0 = jc * 16 + kg * 4;
        f32x4 sh = *(const f32x4*)(shift0 + j0);
        short hv[4], lv[4];
#pragma unroll
        for (int r = 0; r < 4; ++r) {
            float v = fmaxf(acc1[jc8][r] + sh[r], 0.f);
            unsigned short hh = f2bf(v);
            hv[r] = (short)hh; lv[r] = (short)f2bf(v - bf2f(hh));
        }
        int g = jc * 2 + (kg >> 1);
        int idx = qrow * 256 + ((g ^ (qrow & 7)) * 8) + (kg & 1) * 4;
        s16x4 th; th[0] = hv[0]; th[1] = hv[1]; th[2] = hv[2]; th[3] = hv[3];
        s16x4 tl; tl[0] = lv[0]; tl[1] = lv[1]; tl[2] = lv[2]; tl[3] = lv[3];
        *(s16x4*)&l1hi[idx] = th;
        *(s16x4*)&l1lo[idx] = tl;
    }
    __syncthreads();   // all l1 planes written

    // ---- pickup: each lane loads its 8 lo B-frags (own qrow) into regs ----
    bf16x8 bl2[8];
#pragma unroll
    for (int kb = 0; kb < 8; ++kb) {
        int gidx = qrow * 256 + (((kb * 4 + kg) ^ (qrow & 7)) * 8);
        bl2[kb] = *(const bf16x8*)&l1lo[gidx];
    }
    __syncthreads();   // lo region free for layer-2 strips

    // ---- layer 2: 16 strips (kb 0..7 x {hi,lo}), pipelined ----
    f32x4 acc2[8];
#pragma unroll
    for (int i = 0; i < 8; ++i) acc2[i] = 0.f;
    STAGE(W1p, 0, 0);
    __syncthreads();   // strip 0 resident
    cur = 0;
#pragma unroll
    for (int s = 0; s < 16; ++s) {
        if (s < 15) STAGE(W1p, s + 1, cur ^ 1);
        const unsigned short* strip = (const unsigned short*)(smem + (cur << 14));
        const int kb = s >> 1;
        int gidx = qrow * 256 + (((kb * 4 + kg) ^ (qrow & 7)) * 8);
        bf16x8 bh2 = *(const bf16x8*)&l1hi[gidx];
#pragma unroll
        for (int jc8 = 0; jc8 < 8; ++jc8) {
            int col = (ch * 8 + jc8) * 16 + l16;
            bf16x8 a = *(const bf16x8*)&strip[kg * 2048 + col * 8];
            acc2[jc8] = __builtin_amdgcn_mfma_f32_16x16x32_bf16(a, bh2, acc2[jc8], 0, 0, 0);
            if ((s & 1) == 0)
                acc2[jc8] = __builtin_amdgcn_mfma_f32_16x16x32_bf16(a, bl2[kb], acc2[jc8], 0, 0, 0);
        }
        __syncthreads();
        cur ^= 1;
    }

    // ---- layer 3: BN-shift + relu + 256->2 + log_softmax ----
    float p0 = 0.f, p1 = 0.f;
#pragma unroll
    for (int jc8 = 0; jc8 < 8; ++jc8) {
        int j0 = (ch * 8 + jc8) * 16 + kg * 4;
        f32x4 sh = *(const f32x4*)(shift1 + j0);
        f32x4 wa = *(const f32x4*)(w2 + j0);
        f32x4 wb = *(const f32x4*)(w2 + H_DIM + j0);
#pragma unroll
        for (int r = 0; r < 4; ++r) {
            float v = fmaxf(acc2[jc8][r] + sh[r], 0.f);
            p0 += v * wa[r];
            p1 += v * wb[r];
        }
    }
    p0 += __shfl_xor(p0, 16, 64); p0 += __shfl_xor(p0, 32, 64);
    p1 += __shfl_xor(p1, 16, 64); p1 += __shfl_xor(p1, 32, 64);
    // strip region dead (last barrier was after strip 15); reuse as red
    if (lane < 16) {
        red[(wave * 16 + lane) * 2 + 0] = p0;
        red[(wave * 16 + lane) * 2 + 1] = p1;
    }
    __syncthreads();
    if (ch == 0 && lane < 16) {
        int q = qb + qg * 16 + lane;
        if (q < Q_PAIRS) {
            float l0 = red[(wave * 16 + lane) * 2 + 0] + red[((wave + 1) * 16 + lane) * 2 + 0] + b2[0];
            float l1v = red[(wave * 16 + lane) * 2 + 1] + red[((wave + 1) * 16 + lane) * 2 + 1] + b2[1];
            float mx = fmaxf(l0, l1v);
            float lse = mx + logf(expf(l0 - mx) + expf(l1v - mx));
            float2 o; o.x = l0 - lse; o.y = l1v - lse;
            *(float2*)(out + (size_t)q * N_CLS) = o;
        }
    }
}

// ---------------- launch ----------------
extern "C" void kernel_launch(void* const* d_in, const int* in_sizes, int n_in,
                              void* d_out, int out_size, void* d_ws, size_t ws_size,
                              hipStream_t stream) {
    const float* X  = (const float*)d_in[0];
    const int*   ei = (const int*)d_in[1];
    const float* ew = (const float*)d_in[2];
    const int*   e1 = (const int*)d_in[3];
    const int*   e2 = (const int*)d_in[4];
    const float* w_init[2] = {(const float*)d_in[5],  (const float*)d_in[10]};
    const float* w_ih[2]   = {(const float*)d_in[6],  (const float*)d_in[11]};
    const float* w_hh[2]   = {(const float*)d_in[7],  (const float*)d_in[12]};
    const float* b_ih[2]   = {(const float*)d_in[8],  (const float*)d_in[13]};
    const float* b_hh[2]   = {(const float*)d_in[9],  (const float*)d_in[14]};
    const float* lw0 = (const float*)d_in[15]; const float* lb0 = (const float*)d_in[16];
    const float* lw1 = (const float*)d_in[17]; const float* lb1 = (const float*)d_in[18];
    const float* lw2 = (const float*)d_in[19]; const float* lb2 = (const float*)d_in[20];
    const float* bg0 = (const float*)d_in[21]; const float* bb0 = (const float*)d_in[22];
    const float* bm0 = (const float*)d_in[23]; const float* bv0 = (const float*)d_in[24];
    const float* bg1 = (const float*)d_in[25]; const float* bb1 = (const float*)d_in[26];
    const float* bm1 = (const float*)d_in[27]; const float* bv1 = (const float*)d_in[28];
    const int* src = ei;
    const int* dst = ei + E_EDGES;

    char* ws = (char*)d_ws;
    size_t o = 0;
    auto alloc = [&](size_t bytes) { char* p = ws + o; o += (bytes + 63) & ~(size_t)63; return p; };
    float* bufA   = (float*)alloc((size_t)N_NODES * C_DIM * 4);
    float* bufB   = (float*)alloc((size_t)N_NODES * C_DIM * 4);
    float* dinv   = (float*)alloc(N_NODES * 4);
    float* w_ev   = (float*)alloc(C_DIM * C_DIM * 4);
    float* shift0 = (float*)alloc(H_DIM * 4);
    float* shift1 = (float*)alloc(H_DIM * 4);
    int*   cnt    = (int*)alloc(N_NODES * 4);
    int*   pos    = (int*)alloc(N_NODES * 4);
    int*   off    = (int*)alloc((N_NODES + 1) * 4);
    int2*  csr    = (int2*)alloc((size_t)E_EDGES * 8);
    unsigned short* W0p = (unsigned short*)alloc(4 * 2 * 4 * 256 * 8 * 2);   // 128KB
    unsigned short* W1p = (unsigned short*)alloc(8 * 2 * 4 * 256 * 8 * 2);   // 256KB
    if (o > ws_size) return;   // fail loudly

    dim3 b256(256);
    const int gN = (N_NODES + 255) / 256;
    const int gE = (E_EDGES + 255) / 256;

    // degrees + CSR
    k_init<<<gN, b256, 0, stream>>>(dinv, cnt);
    k_deg_hist<<<gE, b256, 0, stream>>>(dst, ew, dinv, cnt);
    k_deg_fin<<<gN, b256, 0, stream>>>(dinv);
    k_scan<<<1, 1024, 0, stream>>>(cnt, off, pos);
    k_fill<<<gE, b256, 0, stream>>>(src, dst, ew, dinv, pos, csr);

    // MLP weight prep (BN folded, bf16 hi/lo, MFMA fragment layout)
    k_prep_w<<<(4 * 2 * 4 * 256 * 8) / 256, b256, 0, stream>>>(lw0, bg0, bv0, C_DIM, 4 * 2 * 4 * 256 * 8, W0p);
    k_prep_w<<<(8 * 2 * 4 * 256 * 8) / 256, b256, 0, stream>>>(lw1, bg1, bv1, H_DIM, 8 * 2 * 4 * 256 * 8, W1p);
    k_prep_shift<<<1, 512, 0, stream>>>(lb0, bg0, bb0, bm0, bv0, lb1, bg1, bb1, bm1, bv1, shift0, shift1);

    const int xw_grid = (N_NODES + 31) / 32;
    const int gg = (N_NODES * 32 + 255) / 256;
    // layer 0
    k_gru<<<C_DIM, 128, 0, stream>>>(w_init[0], w_ih[0], w_hh[0], b_ih[0], b_hh[0], w_ev);
    k_xw<0><<<xw_grid, b256, 0, stream>>>(X, w_ev, dinv, bufA, bufB);
    k_gather<<<gg, b256, 0, stream>>>(bufA, off, csr, bufB);
    // layer 1
    k_gru<<<C_DIM, 128, 0, stream>>>(w_init[1], w_ih[1], w_hh[1], b_ih[1], b_hh[1], w_ev);
    k_xw<1><<<xw_grid, b256, 0, stream>>>(bufB, w_ev, dinv, bufA, bufB);
    k_gather<<<gg, b256, 0, stream>>>(bufA, off, csr, bufB);
    // fused MFMA MLP (64 queries/block, dbuf strip pipeline)
    k_mlp<<<(Q_PAIRS + 63) / 64, dim3(512), 0, stream>>>(bufB, e1, e2, W0p, W1p, shift0, shift1,
                                                         lw2, lb2, (float*)d_out);
}

// Round 6
// 905.794 us; speedup vs baseline: 9.2807x; 1.1579x over previous
//
#include <hip/hip_runtime.h>
#include <math.h>

#define N_NODES 50000
#define C_DIM   128
#define E_EDGES 1600000
#define Q_PAIRS 500000
#define H_DIM   256
#define N_CLS   2
#define BN_EPS  1e-5f

typedef __attribute__((ext_vector_type(8))) short bf16x8;
typedef __attribute__((ext_vector_type(4))) short s16x4;
typedef __attribute__((ext_vector_type(4))) float f32x4;

#define VMCNT0 asm volatile("s_waitcnt vmcnt(0)" ::: "memory")
#define VMCNT1 asm volatile("s_waitcnt vmcnt(1)" ::: "memory")
#define VMCNT2 asm volatile("s_waitcnt vmcnt(2)" ::: "memory")
#define SBAR do { __builtin_amdgcn_sched_barrier(0); __builtin_amdgcn_s_barrier(); \
                  __builtin_amdgcn_sched_barrier(0); } while (0)

__device__ __forceinline__ unsigned short f2bf(float x) {   // RNE f32->bf16 bits
    unsigned u = __float_as_uint(x);
    u += 0x7fffu + ((u >> 16) & 1u);
    return (unsigned short)(u >> 16);
}
__device__ __forceinline__ float bf2f(unsigned short h) {
    return __uint_as_float(((unsigned)h) << 16);
}

// ---------------- init + degree/hist ----------------
__global__ __launch_bounds__(256) void k_init(float* deg, int* cnt) {
    int i = blockIdx.x * 256 + threadIdx.x;
    if (i < N_NODES) { deg[i] = 1.0f; cnt[i] = 0; }
}
__global__ __launch_bounds__(256) void k_deg_hist(const int* __restrict__ dst,
                                                  const float* __restrict__ ew,
                                                  float* deg, int* cnt) {
    int e = blockIdx.x * 256 + threadIdx.x;
    if (e < E_EDGES) {
        int d = dst[e];
        unsafeAtomicAdd(&deg[d], ew[e]);
        atomicAdd(&cnt[d], 1);
    }
}
__global__ __launch_bounds__(256) void k_deg_fin(float* deg) {
    int i = blockIdx.x * 256 + threadIdx.x;
    if (i < N_NODES) deg[i] = rsqrtf(deg[i]);
}

// ---------------- multi-block scan (3 kernels) ----------------
__global__ __launch_bounds__(1024) void k_scan1(const int* __restrict__ cnt,
                                                int* __restrict__ locincl,
                                                int* __restrict__ bsum) {
    __shared__ int pa[1024], pb[1024];
    int t = threadIdx.x;
    int x = blockIdx.x * 1024 + t;
    int v = (x < N_NODES) ? cnt[x] : 0;
    pa[t] = v;
    __syncthreads();
    int* sp = pa; int* dp = pb;
    for (int o = 1; o < 1024; o <<= 1) {
        int u = sp[t] + ((t >= o) ? sp[t - o] : 0);
        dp[t] = u;
        __syncthreads();
        int* tmp = sp; sp = dp; dp = tmp;
    }
    if (x < N_NODES) locincl[x] = sp[t];
    if (t == 1023) bsum[blockIdx.x] = sp[1023];
}
__global__ __launch_bounds__(64) void k_scan2(const int* __restrict__ bsum,
                                              int* __restrict__ boff) {
    int t = threadIdx.x;
    int v = (t < 49) ? bsum[t] : 0;
    int own = v;
    for (int o = 1; o < 64; o <<= 1) {
        int u = __shfl_up(v, o, 64);
        if (t >= o) v += u;
    }
    if (t < 49) boff[t] = v - own;   // exclusive
}
__global__ __launch_bounds__(1024) void k_scan3(const int* __restrict__ cnt,
                                                int* __restrict__ pos,
                                                const int* __restrict__ boff,
                                                int* __restrict__ off) {
    int x = blockIdx.x * 1024 + threadIdx.x;
    if (x >= N_NODES) return;
    int incl = pos[x];
    int c = cnt[x];
    int o = boff[blockIdx.x] + incl - c;
    off[x] = o;
    pos[x] = o;
    if (x == N_NODES - 1) off[N_NODES] = o + c;
}

// packed CSR entry: .x = src node, .y = float weight bits
__global__ __launch_bounds__(256) void k_fill(const int* __restrict__ src,
                                              const int* __restrict__ dst,
                                              const float* __restrict__ ew,
                                              const float* __restrict__ dinv,
                                              int* pos,
                                              int2* __restrict__ csr) {
    int e = blockIdx.x * 256 + threadIdx.x;
    if (e >= E_EDGES) return;
    int s = src[e], d = dst[e];
    int slot = atomicAdd(&pos[d], 1);
    int2 p;
    p.x = s;
    p.y = __float_as_int(dinv[s] * ew[e] * dinv[d]);
    csr[slot] = p;
}

// ---------------- GRU weight evolution (both layers in one launch) ----------------
__global__ __launch_bounds__(128) void k_gru2(
    const float* __restrict__ wi0, const float* __restrict__ wih0, const float* __restrict__ whh0,
    const float* __restrict__ bih0, const float* __restrict__ bhh0, float* __restrict__ we0,
    const float* __restrict__ wi1, const float* __restrict__ wih1, const float* __restrict__ whh1,
    const float* __restrict__ bih1, const float* __restrict__ bhh1, float* __restrict__ we1) {
    __shared__ float xrow[C_DIM];
    int layer = blockIdx.x >> 7;
    int i = blockIdx.x & 127, j = threadIdx.x;
    const float* w_init = layer ? wi1 : wi0;
    const float* wih = layer ? wih1 : wih0;
    const float* whh = layer ? whh1 : whh0;
    const float* bih = layer ? bih1 : bih0;
    const float* bhh = layer ? bhh1 : bhh0;
    float* w_out = layer ? we1 : we0;
    xrow[j] = w_init[i * C_DIM + j];
    __syncthreads();
    float gi[3], gh[3];
#pragma unroll
    for (int g = 0; g < 3; ++g) {
        const float* wi = wih + (size_t)(g * C_DIM + j) * C_DIM;
        const float* wh = whh + (size_t)(g * C_DIM + j) * C_DIM;
        float ai = 0.f, ah = 0.f;
        for (int k = 0; k < C_DIM; ++k) { ai += xrow[k] * wi[k]; ah += xrow[k] * wh[k]; }
        gi[g] = ai + bih[g * C_DIM + j];
        gh[g] = ah + bhh[g * C_DIM + j];
    }
    float r = 1.f / (1.f + expf(-(gi[0] + gh[0])));
    float z = 1.f / (1.f + expf(-(gi[1] + gh[1])));
    float n = tanhf(gi[2] + r * gh[2]);
    w_out[i * C_DIM + j] = (1.f - z) * n + z * xrow[j];
}

// ---------------- CSR aggregation on raw features: agg[n] = dinv_n^2 x[n] + sum w_e x[src] ----------------
__global__ __launch_bounds__(256) void k_agg(const float* __restrict__ x,
                                             const float* __restrict__ dinv,
                                             const int* __restrict__ off,
                                             const int2* __restrict__ csr,
                                             float* __restrict__ agg) {
    int tid = blockIdx.x * 256 + threadIdx.x;
    int n = tid >> 5;
    int c = (tid & 31) << 2;
    float dv = dinv[n];
    float d2 = dv * dv;
    const float4 xn = *(const float4*)(x + (size_t)n * C_DIM + c);
    float4 acc;
    acc.x = d2 * xn.x; acc.y = d2 * xn.y; acc.z = d2 * xn.z; acc.w = d2 * xn.w;
    int i = off[n], e = off[n + 1];
    for (; i + 4 <= e; i += 4) {
        int2 p0 = csr[i], p1 = csr[i + 1], p2 = csr[i + 2], p3 = csr[i + 3];
        float4 v0 = *(const float4*)(x + (size_t)p0.x * C_DIM + c);
        float4 v1 = *(const float4*)(x + (size_t)p1.x * C_DIM + c);
        float4 v2 = *(const float4*)(x + (size_t)p2.x * C_DIM + c);
        float4 v3 = *(const float4*)(x + (size_t)p3.x * C_DIM + c);
        float w0 = __int_as_float(p0.y), w1 = __int_as_float(p1.y);
        float w2 = __int_as_float(p2.y), w3 = __int_as_float(p3.y);
        acc.x += w0 * v0.x + w1 * v1.x + w2 * v2.x + w3 * v3.x;
        acc.y += w0 * v0.y + w1 * v1.y + w2 * v2.y + w3 * v3.y;
        acc.z += w0 * v0.z + w1 * v1.z + w2 * v2.z + w3 * v3.z;
        acc.w += w0 * v0.w + w1 * v1.w + w2 * v2.w + w3 * v3.w;
    }
    for (; i < e; ++i) {
        int2 pe = csr[i];
        float w = __int_as_float(pe.y);
        float4 v = *(const float4*)(x + (size_t)pe.x * C_DIM + c);
        acc.x += w * v.x; acc.y += w * v.y; acc.z += w * v.z; acc.w += w * v.w;
    }
    *(float4*)(agg + (size_t)n * C_DIM + c) = acc;
}

// ---------------- weight prep ----------------
// MLP weights: [kb][plane][col(256)][kg(4)][e(8)]; strip read is 1KB-contiguous per 64-lane b128.
__global__ __launch_bounds__(256) void k_prep_w(const float* __restrict__ w,
                                                const float* __restrict__ g,
                                                const float* __restrict__ v,
                                                int kdim, int total,
                                                unsigned short* __restrict__ outp) {
    int idx = blockIdx.x * 256 + threadIdx.x;
    if (idx >= total) return;
    int e = idx & 7, kg = (idx >> 3) & 3, col = (idx >> 5) & 255;
    int plane = (idx >> 13) & 1, kb = idx >> 14;
    int k = kb * 32 + kg * 8 + e;
    float sc = g[col] * rsqrtf(v[col] + BN_EPS);
    float x = w[(size_t)col * kdim + k] * sc;
    unsigned short hi = f2bf(x);
    outp[idx] = plane ? f2bf(x - bf2f(hi)) : hi;
}
// conv weights (both layers): [layer][kb(4)][plane][col(128)][kg(4)][e(8)], value = w_ev[k][col]
__global__ __launch_bounds__(256) void k_prep_conv(const float* __restrict__ we0,
                                                   const float* __restrict__ we1,
                                                   unsigned short* __restrict__ Wc0,
                                                   unsigned short* __restrict__ Wc1) {
    int idx = blockIdx.x * 256 + threadIdx.x;   // 65536 total
    int e = idx & 7, kg = (idx >> 3) & 3, col = (idx >> 5) & 127;
    int plane = (idx >> 12) & 1, kb = (idx >> 13) & 3, layer = idx >> 15;
    int k = kb * 32 + kg * 8 + e;
    const float* we = layer ? we1 : we0;
    float x = we[(size_t)k * C_DIM + col];
    unsigned short hi = f2bf(x);
    unsigned short o = plane ? f2bf(x - bf2f(hi)) : hi;
    (layer ? Wc1 : Wc0)[idx & 32767] = o;
}

__global__ __launch_bounds__(512) void k_prep_shift(
    const float* __restrict__ lb0, const float* __restrict__ bg0, const float* __restrict__ bb0,
    const float* __restrict__ bm0, const float* __restrict__ bv0,
    const float* __restrict__ lb1, const float* __restrict__ bg1, const float* __restrict__ bb1,
    const float* __restrict__ bm1, const float* __restrict__ bv1,
    float* __restrict__ shift0, float* __restrict__ shift1) {
    int j = threadIdx.x;
    if (j < 256) {
        float sc = bg0[j] * rsqrtf(bv0[j] + BN_EPS);
        shift0[j] = (lb0[j] - bm0[j]) * sc + bb0[j];
    } else {
        int i = j - 256;
        float sc = bg1[i] * rsqrtf(bv1[i] + BN_EPS);
        shift1[i] = (lb1[i] - bm1[i]) * sc + bb1[i];
    }
}

// ---------------- conv GEMM: y = relu(agg @ W) via bf16 hi/lo MFMA ----------------
// 64 rows/block, 512 thr, 8 waves (4 row-groups x 2 col-halves of 64). K=128.
// 8 strips of 8KB, 3-buffer depth-2 pipeline, counted vmcnt, drain-free barriers.
__global__ __launch_bounds__(512) void k_gemm(const float* __restrict__ agg,
                                              const unsigned short* __restrict__ Wc,
                                              float* __restrict__ y) {
    __shared__ __align__(16) char smem[3 * 8192];
    const int t = threadIdx.x, lane = t & 63, wave = t >> 6;
    const int qg = wave >> 1, ch = wave & 1;
    const int l16 = lane & 15, kg = lane >> 4;
    const int qrow = qg * 16 + l16;
    const int node = blockIdx.x * 64 + qrow;
    const int nodec = node < N_NODES ? node : N_NODES - 1;

    auto STG = [&](int sidx, int b) {
        const char* g = (const char*)Wc + sidx * 8192 + wave * 1024 + lane * 16;
        char* d = smem + b * 8192 + wave * 1024;
        __builtin_amdgcn_global_load_lds((const __attribute__((address_space(1))) void*)g,
                                         (__attribute__((address_space(3))) void*)d, 16, 0, 0);
    };
    STG(0, 0); STG(1, 1);

    bf16x8 bh[4], bl[4];
    const float* ar = agg + (size_t)nodec * C_DIM;
#pragma unroll
    for (int kb = 0; kb < 4; ++kb) {
        int k0 = kb * 32 + kg * 8;
        f32x4 a0 = *(const f32x4*)(ar + k0);
        f32x4 a1 = *(const f32x4*)(ar + k0 + 4);
#pragma unroll
        for (int e = 0; e < 4; ++e) {
            unsigned short h0 = f2bf(a0[e]);
            bh[kb][e] = (short)h0; bl[kb][e] = (short)f2bf(a0[e] - bf2f(h0));
            unsigned short h1 = f2bf(a1[e]);
            bh[kb][e + 4] = (short)h1; bl[kb][e + 4] = (short)f2bf(a1[e] - bf2f(h1));
        }
    }
    f32x4 acc[4];
#pragma unroll
    for (int i = 0; i < 4; ++i) acc[i] = 0.f;

#pragma unroll
    for (int s = 0; s < 8; ++s) {
        if (s < 7) { VMCNT1; } else { VMCNT0; }
        SBAR;
        if (s + 2 < 8) STG(s + 2, (s + 2) % 3);
        const unsigned short* strip = (const unsigned short*)(smem + (s % 3) * 8192);
        const int kb = s >> 1;
        __builtin_amdgcn_s_setprio(1);
#pragma unroll
        for (int jc8 = 0; jc8 < 4; ++jc8) {
            int col = (ch * 4 + jc8) * 16 + l16;
            bf16x8 a = *(const bf16x8*)&strip[col * 32 + kg * 8];
            acc[jc8] = __builtin_amdgcn_mfma_f32_16x16x32_bf16(a, bh[kb], acc[jc8], 0, 0, 0);
            if ((s & 1) == 0)
                acc[jc8] = __builtin_amdgcn_mfma_f32_16x16x32_bf16(a, bl[kb], acc[jc8], 0, 0, 0);
        }
        __builtin_amdgcn_s_setprio(0);
    }

    if (node < N_NODES) {
#pragma unroll
        for (int jc8 = 0; jc8 < 4; ++jc8) {
            int j0 = (ch * 4 + jc8) * 16 + kg * 4;
            float4 v;
            v.x = fmaxf(acc[jc8][0], 0.f); v.y = fmaxf(acc[jc8][1], 0.f);
            v.z = fmaxf(acc[jc8][2], 0.f); v.w = fmaxf(acc[jc8][3], 0.f);
            *(float4*)(y + (size_t)node * C_DIM + j0) = v;
        }
    }
}

// ---------------- fused query MLP (bf16 hi/lo MFMA, depth-2 strip pipeline) ----------------
// 64 q/block, 512 thr, 8 waves. LDS 80KB -> 2 blocks/CU:
//   [0,48K): 3 x 16KB strip buffers (depth-2 pipeline)
//   [48K,80K): l1hi persistent; l1lo transient at [0,32K) between layers.
__global__ __launch_bounds__(512, 4) void k_mlp(const float* __restrict__ y,
                                             const int* __restrict__ e1,
                                             const int* __restrict__ e2,
                                             const unsigned short* __restrict__ W0p,
                                             const unsigned short* __restrict__ W1p,
                                             const float* __restrict__ shift0,
                                             const float* __restrict__ shift1,
                                             const float* __restrict__ w2,
                                             const float* __restrict__ b2,
                                             float* __restrict__ out) {
    __shared__ __align__(16) char smem[81920];
    unsigned short* l1hi = (unsigned short*)(smem + 49152);
    unsigned short* l1lo = (unsigned short*)smem;
    float* red = (float*)smem;

    const int t = threadIdx.x;
    const int lane = t & 63;
    const int wave = t >> 6;
    const int qg = wave >> 1, ch = wave & 1;
    const int l16 = lane & 15, kg = lane >> 4;
    const int qrow = qg * 16 + l16;
    const int qb = blockIdx.x * 64;
    int qi = qb + qrow; if (qi >= Q_PAIRS) qi = Q_PAIRS - 1;
    const float* ya = y + (size_t)e1[qi] * C_DIM;
    const float* yb = y + (size_t)e2[qi] * C_DIM;

    auto STG = [&](const unsigned short* W, int sidx, int b) {
        const char* g = (const char*)W + ((size_t)sidx << 14) + wave * 2048 + lane * 16;
        char* d = smem + b * 16384 + wave * 2048;
        __builtin_amdgcn_global_load_lds((const __attribute__((address_space(1))) void*)g,
                                         (__attribute__((address_space(3))) void*)d, 16, 0, 0);
        __builtin_amdgcn_global_load_lds((const __attribute__((address_space(1))) void*)(g + 1024),
                                         (__attribute__((address_space(3))) void*)(d + 1024), 16, 0, 0);
    };

    // prologue: stage strips 0,1; build h fragments (y is already relu'd)
    STG(W0p, 0, 0); STG(W0p, 1, 1);
    bf16x8 bh[4], bl[4];
#pragma unroll
    for (int kb = 0; kb < 4; ++kb) {
        int k0 = kb * 32 + kg * 8;
        f32x4 a0 = *(const f32x4*)(ya + k0);
        f32x4 a1 = *(const f32x4*)(ya + k0 + 4);
        f32x4 b0v = *(const f32x4*)(yb + k0);
        f32x4 b1v = *(const f32x4*)(yb + k0 + 4);
#pragma unroll
        for (int e = 0; e < 4; ++e) {
            float h0 = a0[e] * b0v[e];
            unsigned short hh0 = f2bf(h0);
            bh[kb][e] = (short)hh0; bl[kb][e] = (short)f2bf(h0 - bf2f(hh0));
            float h1 = a1[e] * b1v[e];
            unsigned short hh1 = f2bf(h1);
            bh[kb][e + 4] = (short)hh1; bl[kb][e + 4] = (short)f2bf(h1 - bf2f(hh1));
        }
    }
    f32x4 acc1[8];
#pragma unroll
    for (int i = 0; i < 8; ++i) acc1[i] = 0.f;

    // ---- layer 1: 8 strips, depth-2 pipeline ----
#pragma unroll
    for (int s = 0; s < 8; ++s) {
        if (s < 7) { VMCNT2; } else { VMCNT0; }
        SBAR;
        if (s + 2 < 8) STG(W0p, s + 2, (s + 2) % 3);
        const unsigned short* strip = (const unsigned short*)(smem + (s % 3) * 16384);
        const int kb = s >> 1;
        __builtin_amdgcn_s_setprio(1);
#pragma unroll
        for (int jc8 = 0; jc8 < 8; ++jc8) {
            int col = (ch * 8 + jc8) * 16 + l16;
            bf16x8 a = *(const bf16x8*)&strip[col * 32 + kg * 8];
            acc1[jc8] = __builtin_amdgcn_mfma_f32_16x16x32_bf16(a, bh[kb], acc1[jc8], 0, 0, 0);
            if ((s & 1) == 0)
                acc1[jc8] = __builtin_amdgcn_mfma_f32_16x16x32_bf16(a, bl[kb], acc1[jc8], 0, 0, 0);
        }
        __builtin_amdgcn_s_setprio(0);
    }
    __syncthreads();   // all strip reads done; strip region dead

    // ---- epilogue 1: BN-shift + relu -> l1hi / l1lo (swizzled granules) ----
#pragma unroll
    for (int jc8 = 0; jc8 < 8; ++jc8) {
        int jc = ch * 8 + jc8;
        int j0 = jc * 16 + kg * 4;
        f32x4 sh = *(const f32x4*)(shift0 + j0);
        short hv[4], lv[4];
#pragma unroll
        for (int r = 0; r < 4; ++r) {
            float v = fmaxf(acc1[jc8][r] + sh[r], 0.f);
            unsigned short hh = f2bf(v);
            hv[r] = (short)hh; lv[r] = (short)f2bf(v - bf2f(hh));
        }
        int g = jc * 2 + (kg >> 1);
        int idx = qrow * 256 + ((g ^ (qrow & 7)) * 8) + (kg & 1) * 4;
        s16x4 th; th[0] = hv[0]; th[1] = hv[1]; th[2] = hv[2]; th[3] = hv[3];
        s16x4 tl; tl[0] = lv[0]; tl[1] = lv[1]; tl[2] = lv[2]; tl[3] = lv[3];
        *(s16x4*)&l1hi[idx] = th;
        *(s16x4*)&l1lo[idx] = tl;
    }
    __syncthreads();

    // ---- pickup lo-plane B-frags into regs; free [0,32K) for layer-2 strips ----
    bf16x8 bl2[8];
#pragma unroll
    for (int kb = 0; kb < 8; ++kb) {
        int gidx = qrow * 256 + (((kb * 4 + kg) ^ (qrow & 7)) * 8);
        bl2[kb] = *(const bf16x8*)&l1lo[gidx];
    }
    __syncthreads();

    // ---- layer 2: 16 strips, depth-2 pipeline ----
    f32x4 acc2[8];
#pragma unroll
    for (int i = 0; i < 8; ++i) acc2[i] = 0.f;
    STG(W1p, 0, 0); STG(W1p, 1, 1);
#pragma unroll
    for (int s = 0; s < 16; ++s) {
        if (s < 15) { VMCNT2; } else { VMCNT0; }
        SBAR;
        if (s + 2 < 16) STG(W1p, s + 2, (s + 2) % 3);
        const unsigned short* strip = (const unsigned short*)(smem + (s % 3) * 16384);
        const int kb = s >> 1;
        int gidx = qrow * 256 + (((kb * 4 + kg) ^ (qrow & 7)) * 8);
        bf16x8 bh2 = *(const bf16x8*)&l1hi[gidx];
        __builtin_amdgcn_s_setprio(1);
#pragma unroll
        for (int jc8 = 0; jc8 < 8; ++jc8) {
            int col = (ch * 8 + jc8) * 16 + l16;
            bf16x8 a = *(const bf16x8*)&strip[col * 32 + kg * 8];
            acc2[jc8] = __builtin_amdgcn_mfma_f32_16x16x32_bf16(a, bh2, acc2[jc8], 0, 0, 0);
            if ((s & 1) == 0)
                acc2[jc8] = __builtin_amdgcn_mfma_f32_16x16x32_bf16(a, bl2[kb], acc2[jc8], 0, 0, 0);
        }
        __builtin_amdgcn_s_setprio(0);
    }

    // ---- layer 3: BN-shift + relu + 256->2 + log_softmax ----
    float p0 = 0.f, p1 = 0.f;
#pragma unroll
    for (int jc8 = 0; jc8 < 8; ++jc8) {
        int j0 = (ch * 8 + jc8) * 16 + kg * 4;
        f32x4 sh = *(const f32x4*)(shift1 + j0);
        f32x4 wa = *(const f32x4*)(w2 + j0);
        f32x4 wb = *(const f32x4*)(w2 + H_DIM + j0);
#pragma unroll
        for (int r = 0; r < 4; ++r) {
            float v = fmaxf(acc2[jc8][r] + sh[r], 0.f);
            p0 += v * wa[r];
            p1 += v * wb[r];
        }
    }
    p0 += __shfl_xor(p0, 16, 64); p0 += __shfl_xor(p0, 32, 64);
    p1 += __shfl_xor(p1, 16, 64); p1 += __shfl_xor(p1, 32, 64);
    __syncthreads();   // strip reads done; reuse as red
    if (lane < 16) {
        red[(wave * 16 + lane) * 2 + 0] = p0;
        red[(wave * 16 + lane) * 2 + 1] = p1;
    }
    __syncthreads();
    if (ch == 0 && lane < 16) {
        int q = qb + qg * 16 + lane;
        if (q < Q_PAIRS) {
            float l0 = red[(wave * 16 + lane) * 2 + 0] + red[((wave + 1) * 16 + lane) * 2 + 0] + b2[0];
            float l1v = red[(wave * 16 + lane) * 2 + 1] + red[((wave + 1) * 16 + lane) * 2 + 1] + b2[1];
            float mx = fmaxf(l0, l1v);
            float lse = mx + logf(expf(l0 - mx) + expf(l1v - mx));
            float2 o; o.x = l0 - lse; o.y = l1v - lse;
            *(float2*)(out + (size_t)q * N_CLS) = o;
        }
    }
}

// ---------------- launch ----------------
extern "C" void kernel_launch(void* const* d_in, const int* in_sizes, int n_in,
                              void* d_out, int out_size, void* d_ws, size_t ws_size,
                              hipStream_t stream) {
    const float* X  = (const float*)d_in[0];
    const int*   ei = (const int*)d_in[1];
    const float* ew = (const float*)d_in[2];
    const int*   e1 = (const int*)d_in[3];
    const int*   e2 = (const int*)d_in[4];
    const float* w_init[2] = {(const float*)d_in[5],  (const float*)d_in[10]};
    const float* w_ih[2]   = {(const float*)d_in[6],  (const float*)d_in[11]};
    const float* w_hh[2]   = {(const float*)d_in[7],  (const float*)d_in[12]};
    const float* b_ih[2]   = {(const float*)d_in[8],  (const float*)d_in[13]};
    const float* b_hh[2]   = {(const float*)d_in[9],  (const float*)d_in[14]};
    const float* lw0 = (const float*)d_in[15]; const float* lb0 = (const float*)d_in[16];
    const float* lw1 = (const float*)d_in[17]; const float* lb1 = (const float*)d_in[18];
    const float* lw2 = (const float*)d_in[19]; const float* lb2 = (const float*)d_in[20];
    const float* bg0 = (const float*)d_in[21]; const float* bb0 = (const float*)d_in[22];
    const float* bm0 = (const float*)d_in[23]; const float* bv0 = (const float*)d_in[24];
    const float* bg1 = (const float*)d_in[25]; const float* bb1 = (const float*)d_in[26];
    const float* bm1 = (const float*)d_in[27]; const float* bv1 = (const float*)d_in[28];
    const int* src = ei;
    const int* dst = ei + E_EDGES;

    char* ws = (char*)d_ws;
    size_t o = 0;
    auto alloc = [&](size_t bytes) { char* p = ws + o; o += (bytes + 63) & ~(size_t)63; return p; };
    float* bufA   = (float*)alloc((size_t)N_NODES * C_DIM * 4);   // agg
    float* bufB   = (float*)alloc((size_t)N_NODES * C_DIM * 4);   // y
    float* dinv   = (float*)alloc(N_NODES * 4);
    float* we0    = (float*)alloc(C_DIM * C_DIM * 4);
    float* we1    = (float*)alloc(C_DIM * C_DIM * 4);
    float* shift0 = (float*)alloc(H_DIM * 4);
    float* shift1 = (float*)alloc(H_DIM * 4);
    int*   cnt    = (int*)alloc(N_NODES * 4);
    int*   pos    = (int*)alloc(N_NODES * 4);
    int*   off    = (int*)alloc((N_NODES + 1) * 4);
    int*   bsum   = (int*)alloc(64 * 4);
    int*   boff   = (int*)alloc(64 * 4);
    int2*  csr    = (int2*)alloc((size_t)E_EDGES * 8);
    unsigned short* W0p = (unsigned short*)alloc(65536 * 2);    // 128KB
    unsigned short* W1p = (unsigned short*)alloc(131072 * 2);   // 256KB
    unsigned short* Wc0 = (unsigned short*)alloc(32768 * 2);    // 64KB
    unsigned short* Wc1 = (unsigned short*)alloc(32768 * 2);    // 64KB
    if (o > ws_size) return;

    dim3 b256(256);
    const int gN = (N_NODES + 255) / 256;
    const int gE = (E_EDGES + 255) / 256;

    // degrees + CSR
    k_init<<<gN, b256, 0, stream>>>(dinv, cnt);
    k_deg_hist<<<gE, b256, 0, stream>>>(dst, ew, dinv, cnt);
    k_deg_fin<<<gN, b256, 0, stream>>>(dinv);
    k_scan1<<<49, dim3(1024), 0, stream>>>(cnt, pos, bsum);
    k_scan2<<<1, dim3(64), 0, stream>>>(bsum, boff);
    k_scan3<<<49, dim3(1024), 0, stream>>>(cnt, pos, boff, off);
    k_fill<<<gE, b256, 0, stream>>>(src, dst, ew, dinv, pos, csr);

    // GRU (both layers) + weight preps
    k_gru2<<<256, dim3(128), 0, stream>>>(w_init[0], w_ih[0], w_hh[0], b_ih[0], b_hh[0], we0,
                                          w_init[1], w_ih[1], w_hh[1], b_ih[1], b_hh[1], we1);
    k_prep_conv<<<256, b256, 0, stream>>>(we0, we1, Wc0, Wc1);
    k_prep_w<<<256, b256, 0, stream>>>(lw0, bg0, bv0, C_DIM, 65536, W0p);
    k_prep_w<<<512, b256, 0, stream>>>(lw1, bg1, bv1, H_DIM, 131072, W1p);
    k_prep_shift<<<1, dim3(512), 0, stream>>>(lb0, bg0, bb0, bm0, bv0, lb1, bg1, bb1, bm1, bv1, shift0, shift1);

    const int ga = (N_NODES * 32) / 256;          // 6250
    const int gg = (N_NODES + 63) / 64;           // 782
    // layer 0: aggregate-then-multiply (A(XW) == (AX)W)
    k_agg<<<ga, b256, 0, stream>>>(X, dinv, off, csr, bufA);
    k_gemm<<<gg, dim3(512), 0, stream>>>(bufA, Wc0, bufB);
    // layer 1
    k_agg<<<ga, b256, 0, stream>>>(bufB, dinv, off, csr, bufA);
    k_gemm<<<gg, dim3(512), 0, stream>>>(bufA, Wc1, bufB);
    // fused MFMA MLP
    k_mlp<<<(Q_PAIRS + 63) / 64, dim3(512), 0, stream>>>(bufB, e1, e2, W0p, W1p, shift0, shift1,
                                                         lw2, lb2, (float*)d_out);
}

// Round 7
// 879.809 us; speedup vs baseline: 9.5548x; 1.0295x over previous
//
#include <hip/hip_runtime.h>
#include <math.h>

#define N_NODES 50000
#define C_DIM   128
#define E_EDGES 1600000
#define Q_PAIRS 500000
#define H_DIM   256
#define N_CLS   2
#define BN_EPS  1e-5f

typedef __attribute__((ext_vector_type(8))) short bf16x8;
typedef __attribute__((ext_vector_type(4))) short s16x4;
typedef __attribute__((ext_vector_type(4))) float f32x4;

#define VMCNT0 asm volatile("s_waitcnt vmcnt(0)" ::: "memory")
#define VMCNT1 asm volatile("s_waitcnt vmcnt(1)" ::: "memory")
#define VMCNT2 asm volatile("s_waitcnt vmcnt(2)" ::: "memory")
#define SBAR do { __builtin_amdgcn_s_barrier(); \
                  __builtin_amdgcn_sched_barrier(0); } while (0)

__device__ __forceinline__ unsigned short f2bf(float x) {   // RNE f32->bf16 bits
    unsigned u = __float_as_uint(x);
    u += 0x7fffu + ((u >> 16) & 1u);
    return (unsigned short)(u >> 16);
}
__device__ __forceinline__ float bf2f(unsigned short h) {
    return __uint_as_float(((unsigned)h) << 16);
}

// ---------------- init + degree/hist ----------------
__global__ __launch_bounds__(256) void k_init(float* deg, int* cnt) {
    int i = blockIdx.x * 256 + threadIdx.x;
    if (i < N_NODES) { deg[i] = 1.0f; cnt[i] = 0; }
}
__global__ __launch_bounds__(256) void k_deg_hist(const int* __restrict__ dst,
                                                  const float* __restrict__ ew,
                                                  float* deg, int* cnt) {
    int e = blockIdx.x * 256 + threadIdx.x;
    if (e < E_EDGES) {
        int d = dst[e];
        unsafeAtomicAdd(&deg[d], ew[e]);
        atomicAdd(&cnt[d], 1);
    }
}
__global__ __launch_bounds__(256) void k_deg_fin(float* deg) {
    int i = blockIdx.x * 256 + threadIdx.x;
    if (i < N_NODES) deg[i] = rsqrtf(deg[i]);
}

// ---------------- multi-block scan (3 kernels) ----------------
__global__ __launch_bounds__(1024) void k_scan1(const int* __restrict__ cnt,
                                                int* __restrict__ locincl,
                                                int* __restrict__ bsum) {
    __shared__ int pa[1024], pb[1024];
    int t = threadIdx.x;
    int x = blockIdx.x * 1024 + t;
    int v = (x < N_NODES) ? cnt[x] : 0;
    pa[t] = v;
    __syncthreads();
    int* sp = pa; int* dp = pb;
    for (int o = 1; o < 1024; o <<= 1) {
        int u = sp[t] + ((t >= o) ? sp[t - o] : 0);
        dp[t] = u;
        __syncthreads();
        int* tmp = sp; sp = dp; dp = tmp;
    }
    if (x < N_NODES) locincl[x] = sp[t];
    if (t == 1023) bsum[blockIdx.x] = sp[1023];
}
__global__ __launch_bounds__(64) void k_scan2(const int* __restrict__ bsum,
                                              int* __restrict__ boff) {
    int t = threadIdx.x;
    int v = (t < 49) ? bsum[t] : 0;
    int own = v;
    for (int o = 1; o < 64; o <<= 1) {
        int u = __shfl_up(v, o, 64);
        if (t >= o) v += u;
    }
    if (t < 49) boff[t] = v - own;   // exclusive
}
__global__ __launch_bounds__(1024) void k_scan3(const int* __restrict__ cnt,
                                                int* __restrict__ pos,
                                                const int* __restrict__ boff,
                                                int* __restrict__ off) {
    int x = blockIdx.x * 1024 + threadIdx.x;
    if (x >= N_NODES) return;
    int incl = pos[x];
    int c = cnt[x];
    int o = boff[blockIdx.x] + incl - c;
    off[x] = o;
    pos[x] = o;
    if (x == N_NODES - 1) off[N_NODES] = o + c;
}

// packed CSR entry: .x = src node, .y = float weight bits
__global__ __launch_bounds__(256) void k_fill(const int* __restrict__ src,
                                              const int* __restrict__ dst,
                                              const float* __restrict__ ew,
                                              const float* __restrict__ dinv,
                                              int* pos,
                                              int2* __restrict__ csr) {
    int e = blockIdx.x * 256 + threadIdx.x;
    if (e >= E_EDGES) return;
    int s = src[e], d = dst[e];
    int slot = atomicAdd(&pos[d], 1);
    int2 p;
    p.x = s;
    p.y = __float_as_int(dinv[s] * ew[e] * dinv[d]);
    csr[slot] = p;
}

// ---------------- GRU weight evolution (both layers in one launch) ----------------
__global__ __launch_bounds__(128) void k_gru2(
    const float* __restrict__ wi0, const float* __restrict__ wih0, const float* __restrict__ whh0,
    const float* __restrict__ bih0, const float* __restrict__ bhh0, float* __restrict__ we0,
    const float* __restrict__ wi1, const float* __restrict__ wih1, const float* __restrict__ whh1,
    const float* __restrict__ bih1, const float* __restrict__ bhh1, float* __restrict__ we1) {
    __shared__ float xrow[C_DIM];
    int layer = blockIdx.x >> 7;
    int i = blockIdx.x & 127, j = threadIdx.x;
    const float* w_init = layer ? wi1 : wi0;
    const float* wih = layer ? wih1 : wih0;
    const float* whh = layer ? whh1 : whh0;
    const float* bih = layer ? bih1 : bih0;
    const float* bhh = layer ? bhh1 : bhh0;
    float* w_out = layer ? we1 : we0;
    xrow[j] = w_init[i * C_DIM + j];
    __syncthreads();
    float gi[3], gh[3];
#pragma unroll
    for (int g = 0; g < 3; ++g) {
        const float* wi = wih + (size_t)(g * C_DIM + j) * C_DIM;
        const float* wh = whh + (size_t)(g * C_DIM + j) * C_DIM;
        float ai = 0.f, ah = 0.f;
        for (int k = 0; k < C_DIM; ++k) { ai += xrow[k] * wi[k]; ah += xrow[k] * wh[k]; }
        gi[g] = ai + bih[g * C_DIM + j];
        gh[g] = ah + bhh[g * C_DIM + j];
    }
    float r = 1.f / (1.f + expf(-(gi[0] + gh[0])));
    float z = 1.f / (1.f + expf(-(gi[1] + gh[1])));
    float n = tanhf(gi[2] + r * gh[2]);
    w_out[i * C_DIM + j] = (1.f - z) * n + z * xrow[j];
}

// ---------------- CSR aggregation: agg[n] = dinv_n^2 x[n] + sum w_e x[src] ----------------
__global__ __launch_bounds__(256) void k_agg(const float* __restrict__ x,
                                             const float* __restrict__ dinv,
                                             const int* __restrict__ off,
                                             const int2* __restrict__ csr,
                                             float* __restrict__ agg) {
    int tid = blockIdx.x * 256 + threadIdx.x;
    int n = tid >> 5;
    int c = (tid & 31) << 2;
    float dv = dinv[n];
    float d2 = dv * dv;
    const float4 xn = *(const float4*)(x + (size_t)n * C_DIM + c);
    float4 acc;
    acc.x = d2 * xn.x; acc.y = d2 * xn.y; acc.z = d2 * xn.z; acc.w = d2 * xn.w;
    int i = off[n], e = off[n + 1];
    for (; i + 8 <= e; i += 8) {
        int2 q0 = csr[i], q1 = csr[i + 1], q2 = csr[i + 2], q3 = csr[i + 3];
        int2 q4 = csr[i + 4], q5 = csr[i + 5], q6 = csr[i + 6], q7 = csr[i + 7];
        float4 v0 = *(const float4*)(x + (size_t)q0.x * C_DIM + c);
        float4 v1 = *(const float4*)(x + (size_t)q1.x * C_DIM + c);
        float4 v2 = *(const float4*)(x + (size_t)q2.x * C_DIM + c);
        float4 v3 = *(const float4*)(x + (size_t)q3.x * C_DIM + c);
        float4 v4 = *(const float4*)(x + (size_t)q4.x * C_DIM + c);
        float4 v5 = *(const float4*)(x + (size_t)q5.x * C_DIM + c);
        float4 v6 = *(const float4*)(x + (size_t)q6.x * C_DIM + c);
        float4 v7 = *(const float4*)(x + (size_t)q7.x * C_DIM + c);
        float w0 = __int_as_float(q0.y), w1 = __int_as_float(q1.y);
        float w2 = __int_as_float(q2.y), w3 = __int_as_float(q3.y);
        float w4 = __int_as_float(q4.y), w5 = __int_as_float(q5.y);
        float w6 = __int_as_float(q6.y), w7 = __int_as_float(q7.y);
        acc.x += w0 * v0.x + w1 * v1.x + w2 * v2.x + w3 * v3.x
               + w4 * v4.x + w5 * v5.x + w6 * v6.x + w7 * v7.x;
        acc.y += w0 * v0.y + w1 * v1.y + w2 * v2.y + w3 * v3.y
               + w4 * v4.y + w5 * v5.y + w6 * v6.y + w7 * v7.y;
        acc.z += w0 * v0.z + w1 * v1.z + w2 * v2.z + w3 * v3.z
               + w4 * v4.z + w5 * v5.z + w6 * v6.z + w7 * v7.z;
        acc.w += w0 * v0.w + w1 * v1.w + w2 * v2.w + w3 * v3.w
               + w4 * v4.w + w5 * v5.w + w6 * v6.w + w7 * v7.w;
    }
    for (; i < e; ++i) {
        int2 pe = csr[i];
        float w = __int_as_float(pe.y);
        float4 v = *(const float4*)(x + (size_t)pe.x * C_DIM + c);
        acc.x += w * v.x; acc.y += w * v.y; acc.z += w * v.z; acc.w += w * v.w;
    }
    *(float4*)(agg + (size_t)n * C_DIM + c) = acc;
}

// ---------------- weight prep ----------------
// MLP weights: [kb][plane][kg(4)][col(256)][e(8)] (16B stride per lane -> 2-way banks)
__global__ __launch_bounds__(256) void k_prep_w(const float* __restrict__ w,
                                                const float* __restrict__ g,
                                                const float* __restrict__ v,
                                                int kdim, int total,
                                                unsigned short* __restrict__ outp) {
    int idx = blockIdx.x * 256 + threadIdx.x;
    if (idx >= total) return;
    int e = idx & 7, col = (idx >> 3) & 255, kg = (idx >> 11) & 3;
    int plane = (idx >> 13) & 1, kb = idx >> 14;
    int k = kb * 32 + kg * 8 + e;
    float sc = g[col] * rsqrtf(v[col] + BN_EPS);
    float x = w[(size_t)col * kdim + k] * sc;
    unsigned short hi = f2bf(x);
    outp[idx] = plane ? f2bf(x - bf2f(hi)) : hi;
}
// conv weights (both layers): [layer][kb(4)][plane][kg(4)][col(128)][e(8)], value = w_ev[k][col]
__global__ __launch_bounds__(256) void k_prep_conv(const float* __restrict__ we0,
                                                   const float* __restrict__ we1,
                                                   unsigned short* __restrict__ Wc0,
                                                   unsigned short* __restrict__ Wc1) {
    int idx = blockIdx.x * 256 + threadIdx.x;   // 65536 total
    int e = idx & 7, col = (idx >> 3) & 127, kg = (idx >> 10) & 3;
    int plane = (idx >> 12) & 1, kb = (idx >> 13) & 3, layer = idx >> 15;
    int k = kb * 32 + kg * 8 + e;
    const float* we = layer ? we1 : we0;
    float x = we[(size_t)k * C_DIM + col];
    unsigned short hi = f2bf(x);
    unsigned short o = plane ? f2bf(x - bf2f(hi)) : hi;
    (layer ? Wc1 : Wc0)[idx & 32767] = o;
}

__global__ __launch_bounds__(512) void k_prep_shift(
    const float* __restrict__ lb0, const float* __restrict__ bg0, const float* __restrict__ bb0,
    const float* __restrict__ bm0, const float* __restrict__ bv0,
    const float* __restrict__ lb1, const float* __restrict__ bg1, const float* __restrict__ bb1,
    const float* __restrict__ bm1, const float* __restrict__ bv1,
    float* __restrict__ shift0, float* __restrict__ shift1) {
    int j = threadIdx.x;
    if (j < 256) {
        float sc = bg0[j] * rsqrtf(bv0[j] + BN_EPS);
        shift0[j] = (lb0[j] - bm0[j]) * sc + bb0[j];
    } else {
        int i = j - 256;
        float sc = bg1[i] * rsqrtf(bv1[i] + BN_EPS);
        shift1[i] = (lb1[i] - bm1[i]) * sc + bb1[i];
    }
}

// ---------------- conv GEMM: y = relu(agg @ W) via bf16 hi/lo MFMA ----------------
__global__ __launch_bounds__(512) void k_gemm(const float* __restrict__ agg,
                                              const unsigned short* __restrict__ Wc,
                                              float* __restrict__ y) {
    __shared__ __align__(16) char smem[3 * 8192];
    const int t = threadIdx.x, lane = t & 63, wave = t >> 6;
    const int qg = wave >> 1, ch = wave & 1;
    const int l16 = lane & 15, kg = lane >> 4;
    const int qrow = qg * 16 + l16;
    const int node = blockIdx.x * 64 + qrow;
    const int nodec = node < N_NODES ? node : N_NODES - 1;

    auto STG = [&](int sidx, int b) {
        const char* g = (const char*)Wc + sidx * 8192 + wave * 1024 + lane * 16;
        char* d = smem + b * 8192 + wave * 1024;
        __builtin_amdgcn_global_load_lds((const __attribute__((address_space(1))) void*)g,
                                         (__attribute__((address_space(3))) void*)d, 16, 0, 0);
    };
    STG(0, 0); STG(1, 1);

    bf16x8 bh[4], bl[4];
    const float* ar = agg + (size_t)nodec * C_DIM;
#pragma unroll
    for (int kb = 0; kb < 4; ++kb) {
        int k0 = kb * 32 + kg * 8;
        f32x4 a0 = *(const f32x4*)(ar + k0);
        f32x4 a1 = *(const f32x4*)(ar + k0 + 4);
#pragma unroll
        for (int e = 0; e < 4; ++e) {
            unsigned short h0 = f2bf(a0[e]);
            bh[kb][e] = (short)h0; bl[kb][e] = (short)f2bf(a0[e] - bf2f(h0));
            unsigned short h1 = f2bf(a1[e]);
            bh[kb][e + 4] = (short)h1; bl[kb][e + 4] = (short)f2bf(a1[e] - bf2f(h1));
        }
    }
    f32x4 acc[4];
#pragma unroll
    for (int i = 0; i < 4; ++i) acc[i] = 0.f;

#pragma unroll
    for (int s = 0; s < 8; ++s) {
        if (s < 7) { VMCNT1; } else { VMCNT0; }
        SBAR;
        if (s + 2 < 8) STG(s + 2, (s + 2) % 3);
        const unsigned short* strip = (const unsigned short*)(smem + (s % 3) * 8192);
        const int kb = s >> 1;
        __builtin_amdgcn_s_setprio(1);
#pragma unroll
        for (int jc8 = 0; jc8 < 4; ++jc8) {
            int col = (ch * 4 + jc8) * 16 + l16;
            bf16x8 a = *(const bf16x8*)&strip[kg * 1024 + col * 8];
            acc[jc8] = __builtin_amdgcn_mfma_f32_16x16x32_bf16(a, bh[kb], acc[jc8], 0, 0, 0);
            if ((s & 1) == 0)
                acc[jc8] = __builtin_amdgcn_mfma_f32_16x16x32_bf16(a, bl[kb], acc[jc8], 0, 0, 0);
        }
        __builtin_amdgcn_s_setprio(0);
    }

    if (node < N_NODES) {
#pragma unroll
        for (int jc8 = 0; jc8 < 4; ++jc8) {
            int j0 = (ch * 4 + jc8) * 16 + kg * 4;
            float4 v;
            v.x = fmaxf(acc[jc8][0], 0.f); v.y = fmaxf(acc[jc8][1], 0.f);
            v.z = fmaxf(acc[jc8][2], 0.f); v.w = fmaxf(acc[jc8][3], 0.f);
            *(float4*)(y + (size_t)node * C_DIM + j0) = v;
        }
    }
}

// ---------------- fused query MLP (bf16 hi/lo MFMA, depth-2 strip pipeline) ----------------
// 64 q/block, 512 thr, 8 waves. LDS 80KB -> 2 blocks/CU:
//   [0,48K): 3 x 16KB strip buffers (depth-2 pipeline)
//   [48K,80K): l1hi persistent; l1lo transient at [0,32K) between layers.
__global__ __launch_bounds__(512, 4) void k_mlp(const float* __restrict__ y,
                                             const int* __restrict__ e1,
                                             const int* __restrict__ e2,
                                             const unsigned short* __restrict__ W0p,
                                             const unsigned short* __restrict__ W1p,
                                             const float* __restrict__ shift0,
                                             const float* __restrict__ shift1,
                                             const float* __restrict__ w2,
                                             const float* __restrict__ b2,
                                             float* __restrict__ out) {
    __shared__ __align__(16) char smem[81920];
    unsigned short* l1hi = (unsigned short*)(smem + 49152);
    unsigned short* l1lo = (unsigned short*)smem;
    float* red = (float*)smem;

    const int t = threadIdx.x;
    const int lane = t & 63;
    const int wave = t >> 6;
    const int qg = wave >> 1, ch = wave & 1;
    const int l16 = lane & 15, kg = lane >> 4;
    const int qrow = qg * 16 + l16;
    const int qb = blockIdx.x * 64;
    int qi = qb + qrow; if (qi >= Q_PAIRS) qi = Q_PAIRS - 1;
    const float* ya = y + (size_t)e1[qi] * C_DIM;
    const float* yb = y + (size_t)e2[qi] * C_DIM;

    auto STG = [&](const unsigned short* W, int sidx, int b) {
        const char* g = (const char*)W + ((size_t)sidx << 14) + wave * 2048 + lane * 16;
        char* d = smem + b * 16384 + wave * 2048;
        __builtin_amdgcn_global_load_lds((const __attribute__((address_space(1))) void*)g,
                                         (__attribute__((address_space(3))) void*)d, 16, 0, 0);
        __builtin_amdgcn_global_load_lds((const __attribute__((address_space(1))) void*)(g + 1024),
                                         (__attribute__((address_space(3))) void*)(d + 1024), 16, 0, 0);
    };

    // prologue: stage strips 0,1; build h fragments (y is already relu'd)
    STG(W0p, 0, 0); STG(W0p, 1, 1);
    bf16x8 bh[4], bl[4];
#pragma unroll
    for (int kb = 0; kb < 4; ++kb) {
        int k0 = kb * 32 + kg * 8;
        f32x4 a0 = *(const f32x4*)(ya + k0);
        f32x4 a1 = *(const f32x4*)(ya + k0 + 4);
        f32x4 b0v = *(const f32x4*)(yb + k0);
        f32x4 b1v = *(const f32x4*)(yb + k0 + 4);
#pragma unroll
        for (int e = 0; e < 4; ++e) {
            float h0 = a0[e] * b0v[e];
            unsigned short hh0 = f2bf(h0);
            bh[kb][e] = (short)hh0; bl[kb][e] = (short)f2bf(h0 - bf2f(hh0));
            float h1 = a1[e] * b1v[e];
            unsigned short hh1 = f2bf(h1);
            bh[kb][e + 4] = (short)hh1; bl[kb][e + 4] = (short)f2bf(h1 - bf2f(hh1));
        }
    }
    f32x4 acc1[8];
#pragma unroll
    for (int i = 0; i < 8; ++i) acc1[i] = 0.f;

    // ---- layer 1: 8 strips, depth-2 pipeline ----
#pragma unroll
    for (int s = 0; s < 8; ++s) {
        if (s < 7) { VMCNT2; } else { VMCNT0; }
        SBAR;
        if (s + 2 < 8) STG(W0p, s + 2, (s + 2) % 3);
        const unsigned short* strip = (const unsigned short*)(smem + (s % 3) * 16384);
        const int kb = s >> 1;
        __builtin_amdgcn_s_setprio(1);
#pragma unroll
        for (int jc8 = 0; jc8 < 8; ++jc8) {
            int col = (ch * 8 + jc8) * 16 + l16;
            bf16x8 a = *(const bf16x8*)&strip[kg * 2048 + col * 8];
            acc1[jc8] = __builtin_amdgcn_mfma_f32_16x16x32_bf16(a, bh[kb], acc1[jc8], 0, 0, 0);
            if ((s & 1) == 0)
                acc1[jc8] = __builtin_amdgcn_mfma_f32_16x16x32_bf16(a, bl[kb], acc1[jc8], 0, 0, 0);
        }
        __builtin_amdgcn_s_setprio(0);
    }
    __syncthreads();   // all strip reads done; strip region dead

    // ---- epilogue 1: BN-shift + relu -> l1hi / l1lo (swizzled granules) ----
#pragma unroll
    for (int jc8 = 0; jc8 < 8; ++jc8) {
        int jc = ch * 8 + jc8;
        int j0 = jc * 16 + kg * 4;
        f32x4 sh = *(const f32x4*)(shift0 + j0);
        short hv[4], lv[4];
#pragma unroll
        for (int r = 0; r < 4; ++r) {
            float v = fmaxf(acc1[jc8][r] + sh[r], 0.f);
            unsigned short hh = f2bf(v);
            hv[r] = (short)hh; lv[r] = (short)f2bf(v - bf2f(hh));
        }
        int g = jc * 2 + (kg >> 1);
        int idx = qrow * 256 + ((g ^ (qrow & 7)) * 8) + (kg & 1) * 4;
        s16x4 th; th[0] = hv[0]; th[1] = hv[1]; th[2] = hv[2]; th[3] = hv[3];
        s16x4 tl; tl[0] = lv[0]; tl[1] = lv[1]; tl[2] = lv[2]; tl[3] = lv[3];
        *(s16x4*)&l1hi[idx] = th;
        *(s16x4*)&l1lo[idx] = tl;
    }
    __syncthreads();

    // ---- pickup lo-plane B-frags into regs; free [0,32K) for layer-2 strips ----
    bf16x8 bl2[8];
#pragma unroll
    for (int kb = 0; kb < 8; ++kb) {
        int gidx = qrow * 256 + (((kb * 4 + kg) ^ (qrow & 7)) * 8);
        bl2[kb] = *(const bf16x8*)&l1lo[gidx];
    }
    __syncthreads();

    // ---- layer 2: 16 strips, depth-2 pipeline ----
    f32x4 acc2[8];
#pragma unroll
    for (int i = 0; i < 8; ++i) acc2[i] = 0.f;
    STG(W1p, 0, 0); STG(W1p, 1, 1);
#pragma unroll
    for (int s = 0; s < 16; ++s) {
        if (s < 15) { VMCNT2; } else { VMCNT0; }
        SBAR;
        if (s + 2 < 16) STG(W1p, s + 2, (s + 2) % 3);
        const unsigned short* strip = (const unsigned short*)(smem + (s % 3) * 16384);
        const int kb = s >> 1;
        int gidx = qrow * 256 + (((kb * 4 + kg) ^ (qrow & 7)) * 8);
        bf16x8 bh2 = *(const bf16x8*)&l1hi[gidx];
        __builtin_amdgcn_s_setprio(1);
#pragma unroll
        for (int jc8 = 0; jc8 < 8; ++jc8) {
            int col = (ch * 8 + jc8) * 16 + l16;
            bf16x8 a = *(const bf16x8*)&strip[kg * 2048 + col * 8];
            acc2[jc8] = __builtin_amdgcn_mfma_f32_16x16x32_bf16(a, bh2, acc2[jc8], 0, 0, 0);
            if ((s & 1) == 0)
                acc2[jc8] = __builtin_amdgcn_mfma_f32_16x16x32_bf16(a, bl2[kb], acc2[jc8], 0, 0, 0);
        }
        __builtin_amdgcn_s_setprio(0);
    }

    // ---- layer 3: BN-shift + relu + 256->2 + log_softmax ----
    float p0 = 0.f, p1 = 0.f;
#pragma unroll
    for (int jc8 = 0; jc8 < 8; ++jc8) {
        int j0 = (ch * 8 + jc8) * 16 + kg * 4;
        f32x4 sh = *(const f32x4*)(shift1 + j0);
        f32x4 wa = *(const f32x4*)(w2 + j0);
        f32x4 wb = *(const f32x4*)(w2 + H_DIM + j0);
#pragma unroll
        for (int r = 0; r < 4; ++r) {
            float v = fmaxf(acc2[jc8][r] + sh[r], 0.f);
            p0 += v * wa[r];
            p1 += v * wb[r];
        }
    }
    p0 += __shfl_xor(p0, 16, 64); p0 += __shfl_xor(p0, 32, 64);
    p1 += __shfl_xor(p1, 16, 64); p1 += __shfl_xor(p1, 32, 64);
    __syncthreads();   // strip reads done; reuse as red
    if (lane < 16) {
        red[(wave * 16 + lane) * 2 + 0] = p0;
        red[(wave * 16 + lane) * 2 + 1] = p1;
    }
    __syncthreads();
    if (ch == 0 && lane < 16) {
        int q = qb + qg * 16 + lane;
        if (q < Q_PAIRS) {
            float l0 = red[(wave * 16 + lane) * 2 + 0] + red[((wave + 1) * 16 + lane) * 2 + 0] + b2[0];
            float l1v = red[(wave * 16 + lane) * 2 + 1] + red[((wave + 1) * 16 + lane) * 2 + 1] + b2[1];
            float mx = fmaxf(l0, l1v);
            float lse = mx + logf(expf(l0 - mx) + expf(l1v - mx));
            float2 o; o.x = l0 - lse; o.y = l1v - lse;
            *(float2*)(out + (size_t)q * N_CLS) = o;
        }
    }
}

// ---------------- launch ----------------
extern "C" void kernel_launch(void* const* d_in, const int* in_sizes, int n_in,
                              void* d_out, int out_size, void* d_ws, size_t ws_size,
                              hipStream_t stream) {
    const float* X  = (const float*)d_in[0];
    const int*   ei = (const int*)d_in[1];
    const float* ew = (const float*)d_in[2];
    const int*   e1 = (const int*)d_in[3];
    const int*   e2 = (const int*)d_in[4];
    const float* w_init[2] = {(const float*)d_in[5],  (const float*)d_in[10]};
    const float* w_ih[2]   = {(const float*)d_in[6],  (const float*)d_in[11]};
    const float* w_hh[2]   = {(const float*)d_in[7],  (const float*)d_in[12]};
    const float* b_ih[2]   = {(const float*)d_in[8],  (const float*)d_in[13]};
    const float* b_hh[2]   = {(const float*)d_in[9],  (const float*)d_in[14]};
    const float* lw0 = (const float*)d_in[15]; const float* lb0 = (const float*)d_in[16];
    const float* lw1 = (const float*)d_in[17]; const float* lb1 = (const float*)d_in[18];
    const float* lw2 = (const float*)d_in[19]; const float* lb2 = (const float*)d_in[20];
    const float* bg0 = (const float*)d_in[21]; const float* bb0 = (const float*)d_in[22];
    const float* bm0 = (const float*)d_in[23]; const float* bv0 = (const float*)d_in[24];
    const float* bg1 = (const float*)d_in[25]; const float* bb1 = (const float*)d_in[26];
    const float* bm1 = (const float*)d_in[27]; const float* bv1 = (const float*)d_in[28];
    const int* src = ei;
    const int* dst = ei + E_EDGES;

    char* ws = (char*)d_ws;
    size_t o = 0;
    auto alloc = [&](size_t bytes) { char* p = ws + o; o += (bytes + 63) & ~(size_t)63; return p; };
    float* bufA   = (float*)alloc((size_t)N_NODES * C_DIM * 4);   // agg
    float* bufB   = (float*)alloc((size_t)N_NODES * C_DIM * 4);   // y
    float* dinv   = (float*)alloc(N_NODES * 4);
    float* we0    = (float*)alloc(C_DIM * C_DIM * 4);
    float* we1    = (float*)alloc(C_DIM * C_DIM * 4);
    float* shift0 = (float*)alloc(H_DIM * 4);
    float* shift1 = (float*)alloc(H_DIM * 4);
    int*   cnt    = (int*)alloc(N_NODES * 4);
    int*   pos    = (int*)alloc(N_NODES * 4);
    int*   off    = (int*)alloc((N_NODES + 1) * 4);
    int*   bsum   = (int*)alloc(64 * 4);
    int*   boff   = (int*)alloc(64 * 4);
    int2*  csr    = (int2*)alloc((size_t)E_EDGES * 8);
    unsigned short* W0p = (unsigned short*)alloc(65536 * 2);    // 128KB
    unsigned short* W1p = (unsigned short*)alloc(131072 * 2);   // 256KB
    unsigned short* Wc0 = (unsigned short*)alloc(32768 * 2);    // 64KB
    unsigned short* Wc1 = (unsigned short*)alloc(32768 * 2);    // 64KB
    if (o > ws_size) return;

    dim3 b256(256);
    const int gN = (N_NODES + 255) / 256;
    const int gE = (E_EDGES + 255) / 256;

    // degrees + CSR
    k_init<<<gN, b256, 0, stream>>>(dinv, cnt);
    k_deg_hist<<<gE, b256, 0, stream>>>(dst, ew, dinv, cnt);
    k_deg_fin<<<gN, b256, 0, stream>>>(dinv);
    k_scan1<<<49, dim3(1024), 0, stream>>>(cnt, pos, bsum);
    k_scan2<<<1, dim3(64), 0, stream>>>(bsum, boff);
    k_scan3<<<49, dim3(1024), 0, stream>>>(cnt, pos, boff, off);
    k_fill<<<gE, b256, 0, stream>>>(src, dst, ew, dinv, pos, csr);

    // GRU (both layers) + weight preps
    k_gru2<<<256, dim3(128), 0, stream>>>(w_init[0], w_ih[0], w_hh[0], b_ih[0], b_hh[0], we0,
                                          w_init[1], w_ih[1], w_hh[1], b_ih[1], b_hh[1], we1);
    k_prep_conv<<<256, b256, 0, stream>>>(we0, we1, Wc0, Wc1);
    k_prep_w<<<256, b256, 0, stream>>>(lw0, bg0, bv0, C_DIM, 65536, W0p);
    k_prep_w<<<512, b256, 0, stream>>>(lw1, bg1, bv1, H_DIM, 131072, W1p);
    k_prep_shift<<<1, dim3(512), 0, stream>>>(lb0, bg0, bb0, bm0, bv0, lb1, bg1, bb1, bm1, bv1, shift0, shift1);

    const int ga = (N_NODES * 32) / 256;          // 6250
    const int gg = (N_NODES + 63) / 64;           // 782
    // layer 0: aggregate-then-multiply (A(XW) == (AX)W)
    k_agg<<<ga, b256, 0, stream>>>(X, dinv, off, csr, bufA);
    k_gemm<<<gg, dim3(512), 0, stream>>>(bufA, Wc0, bufB);
    // layer 1
    k_agg<<<ga, b256, 0, stream>>>(bufB, dinv, off, csr, bufA);
    k_gemm<<<gg, dim3(512), 0, stream>>>(bufA, Wc1, bufB);
    // fused MFMA MLP
    k_mlp<<<(Q_PAIRS + 63) / 64, dim3(512), 0, stream>>>(bufB, e1, e2, W0p, W1p, shift0, shift1,
                                                         lw2, lb2, (float*)d_out);
}

// Round 8
// 746.056 us; speedup vs baseline: 11.2677x; 1.1793x over previous
//
#include <hip/hip_runtime.h>
#include <math.h>

#define N_NODES 50000
#define C_DIM   128
#define E_EDGES 1600000
#define Q_PAIRS 500000
#define H_DIM   256
#define N_CLS   2
#define BN_EPS  1e-5f

typedef __attribute__((ext_vector_type(8))) short bf16x8;
typedef __attribute__((ext_vector_type(4))) short s16x4;
typedef __attribute__((ext_vector_type(4))) float f32x4;

#define VMCNT0 asm volatile("s_waitcnt vmcnt(0)" ::: "memory")
#define VMCNT1 asm volatile("s_waitcnt vmcnt(1)" ::: "memory")
#define VMCNT2 asm volatile("s_waitcnt vmcnt(2)" ::: "memory")
#define SBAR do { __builtin_amdgcn_s_barrier(); \
                  __builtin_amdgcn_sched_barrier(0); } while (0)

__device__ __forceinline__ unsigned short f2bf(float x) {   // RNE f32->bf16 bits
    unsigned u = __float_as_uint(x);
    u += 0x7fffu + ((u >> 16) & 1u);
    return (unsigned short)(u >> 16);
}
__device__ __forceinline__ float bf2f(unsigned short h) {
    return __uint_as_float(((unsigned)h) << 16);
}

// ---------------- init + degree/hist ----------------
__global__ __launch_bounds__(256) void k_init(float* deg, int* cnt) {
    int i = blockIdx.x * 256 + threadIdx.x;
    if (i < N_NODES) { deg[i] = 1.0f; cnt[i] = 0; }
}
__global__ __launch_bounds__(256) void k_deg_hist(const int* __restrict__ dst,
                                                  const float* __restrict__ ew,
                                                  float* deg, int* cnt) {
    int e = blockIdx.x * 256 + threadIdx.x;
    if (e < E_EDGES) {
        int d = dst[e];
        unsafeAtomicAdd(&deg[d], ew[e]);
        atomicAdd(&cnt[d], 1);
    }
}
__global__ __launch_bounds__(256) void k_deg_fin(float* deg) {
    int i = blockIdx.x * 256 + threadIdx.x;
    if (i < N_NODES) deg[i] = rsqrtf(deg[i]);
}

// ---------------- multi-block scan (3 kernels) ----------------
__global__ __launch_bounds__(1024) void k_scan1(const int* __restrict__ cnt,
                                                int* __restrict__ locincl,
                                                int* __restrict__ bsum) {
    __shared__ int pa[1024], pb[1024];
    int t = threadIdx.x;
    int x = blockIdx.x * 1024 + t;
    int v = (x < N_NODES) ? cnt[x] : 0;
    pa[t] = v;
    __syncthreads();
    int* sp = pa; int* dp = pb;
    for (int o = 1; o < 1024; o <<= 1) {
        int u = sp[t] + ((t >= o) ? sp[t - o] : 0);
        dp[t] = u;
        __syncthreads();
        int* tmp = sp; sp = dp; dp = tmp;
    }
    if (x < N_NODES) locincl[x] = sp[t];
    if (t == 1023) bsum[blockIdx.x] = sp[1023];
}
__global__ __launch_bounds__(64) void k_scan2(const int* __restrict__ bsum,
                                              int* __restrict__ boff) {
    int t = threadIdx.x;
    int v = (t < 49) ? bsum[t] : 0;
    int own = v;
    for (int o = 1; o < 64; o <<= 1) {
        int u = __shfl_up(v, o, 64);
        if (t >= o) v += u;
    }
    if (t < 49) boff[t] = v - own;   // exclusive
}
__global__ __launch_bounds__(1024) void k_scan3(const int* __restrict__ cnt,
                                                int* __restrict__ pos,
                                                const int* __restrict__ boff,
                                                int* __restrict__ off) {
    int x = blockIdx.x * 1024 + threadIdx.x;
    if (x >= N_NODES) return;
    int incl = pos[x];
    int c = cnt[x];
    int o = boff[blockIdx.x] + incl - c;
    off[x] = o;
    pos[x] = o;
    if (x == N_NODES - 1) off[N_NODES] = o + c;
}

// packed CSR entry: .x = src node, .y = float weight bits
__global__ __launch_bounds__(256) void k_fill(const int* __restrict__ src,
                                              const int* __restrict__ dst,
                                              const float* __restrict__ ew,
                                              const float* __restrict__ dinv,
                                              int* pos,
                                              int2* __restrict__ csr) {
    int e = blockIdx.x * 256 + threadIdx.x;
    if (e >= E_EDGES) return;
    int s = src[e], d = dst[e];
    int slot = atomicAdd(&pos[d], 1);
    int2 p;
    p.x = s;
    p.y = __float_as_int(dinv[s] * ew[e] * dinv[d]);
    csr[slot] = p;
}

// ---------------- GRU weight evolution (both layers in one launch) ----------------
__global__ __launch_bounds__(128) void k_gru2(
    const float* __restrict__ wi0, const float* __restrict__ wih0, const float* __restrict__ whh0,
    const float* __restrict__ bih0, const float* __restrict__ bhh0, float* __restrict__ we0,
    const float* __restrict__ wi1, const float* __restrict__ wih1, const float* __restrict__ whh1,
    const float* __restrict__ bih1, const float* __restrict__ bhh1, float* __restrict__ we1) {
    __shared__ float xrow[C_DIM];
    int layer = blockIdx.x >> 7;
    int i = blockIdx.x & 127, j = threadIdx.x;
    const float* w_init = layer ? wi1 : wi0;
    const float* wih = layer ? wih1 : wih0;
    const float* whh = layer ? whh1 : whh0;
    const float* bih = layer ? bih1 : bih0;
    const float* bhh = layer ? bhh1 : bhh0;
    float* w_out = layer ? we1 : we0;
    xrow[j] = w_init[i * C_DIM + j];
    __syncthreads();
    float gi[3], gh[3];
#pragma unroll
    for (int g = 0; g < 3; ++g) {
        const float* wi = wih + (size_t)(g * C_DIM + j) * C_DIM;
        const float* wh = whh + (size_t)(g * C_DIM + j) * C_DIM;
        float ai = 0.f, ah = 0.f;
        for (int k = 0; k < C_DIM; ++k) { ai += xrow[k] * wi[k]; ah += xrow[k] * wh[k]; }
        gi[g] = ai + bih[g * C_DIM + j];
        gh[g] = ah + bhh[g * C_DIM + j];
    }
    float r = 1.f / (1.f + expf(-(gi[0] + gh[0])));
    float z = 1.f / (1.f + expf(-(gi[1] + gh[1])));
    float n = tanhf(gi[2] + r * gh[2]);
    w_out[i * C_DIM + j] = (1.f - z) * n + z * xrow[j];
}

// ---------------- CSR aggregation: agg[n] = dinv_n^2 x[n] + sum w_e x[src] ----------------
__global__ __launch_bounds__(256) void k_agg(const float* __restrict__ x,
                                             const float* __restrict__ dinv,
                                             const int* __restrict__ off,
                                             const int2* __restrict__ csr,
                                             float* __restrict__ agg) {
    int tid = blockIdx.x * 256 + threadIdx.x;
    int n = tid >> 5;
    int c = (tid & 31) << 2;
    float dv = dinv[n];
    float d2 = dv * dv;
    const float4 xn = *(const float4*)(x + (size_t)n * C_DIM + c);
    float4 acc;
    acc.x = d2 * xn.x; acc.y = d2 * xn.y; acc.z = d2 * xn.z; acc.w = d2 * xn.w;
    int i = off[n], e = off[n + 1];
    for (; i + 8 <= e; i += 8) {
        int2 q0 = csr[i], q1 = csr[i + 1], q2 = csr[i + 2], q3 = csr[i + 3];
        int2 q4 = csr[i + 4], q5 = csr[i + 5], q6 = csr[i + 6], q7 = csr[i + 7];
        float4 v0 = *(const float4*)(x + (size_t)q0.x * C_DIM + c);
        float4 v1 = *(const float4*)(x + (size_t)q1.x * C_DIM + c);
        float4 v2 = *(const float4*)(x + (size_t)q2.x * C_DIM + c);
        float4 v3 = *(const float4*)(x + (size_t)q3.x * C_DIM + c);
        float4 v4 = *(const float4*)(x + (size_t)q4.x * C_DIM + c);
        float4 v5 = *(const float4*)(x + (size_t)q5.x * C_DIM + c);
        float4 v6 = *(const float4*)(x + (size_t)q6.x * C_DIM + c);
        float4 v7 = *(const float4*)(x + (size_t)q7.x * C_DIM + c);
        float w0 = __int_as_float(q0.y), w1 = __int_as_float(q1.y);
        float w2 = __int_as_float(q2.y), w3 = __int_as_float(q3.y);
        float w4 = __int_as_float(q4.y), w5 = __int_as_float(q5.y);
        float w6 = __int_as_float(q6.y), w7 = __int_as_float(q7.y);
        acc.x += w0 * v0.x + w1 * v1.x + w2 * v2.x + w3 * v3.x
               + w4 * v4.x + w5 * v5.x + w6 * v6.x + w7 * v7.x;
        acc.y += w0 * v0.y + w1 * v1.y + w2 * v2.y + w3 * v3.y
               + w4 * v4.y + w5 * v5.y + w6 * v6.y + w7 * v7.y;
        acc.z += w0 * v0.z + w1 * v1.z + w2 * v2.z + w3 * v3.z
               + w4 * v4.z + w5 * v5.z + w6 * v6.z + w7 * v7.z;
        acc.w += w0 * v0.w + w1 * v1.w + w2 * v2.w + w3 * v3.w
               + w4 * v4.w + w5 * v5.w + w6 * v6.w + w7 * v7.w;
    }
    for (; i < e; ++i) {
        int2 pe = csr[i];
        float w = __int_as_float(pe.y);
        float4 v = *(const float4*)(x + (size_t)pe.x * C_DIM + c);
        acc.x += w * v.x; acc.y += w * v.y; acc.z += w * v.z; acc.w += w * v.w;
    }
    *(float4*)(agg + (size_t)n * C_DIM + c) = acc;
}

// ---------------- weight prep ----------------
// MLP weights: [kb][plane][kg(4)][col(256)][e(8)] (16B stride per lane -> minimal banks)
__global__ __launch_bounds__(256) void k_prep_w(const float* __restrict__ w,
                                                const float* __restrict__ g,
                                                const float* __restrict__ v,
                                                int kdim, int total,
                                                unsigned short* __restrict__ outp) {
    int idx = blockIdx.x * 256 + threadIdx.x;
    if (idx >= total) return;
    int e = idx & 7, col = (idx >> 3) & 255, kg = (idx >> 11) & 3;
    int plane = (idx >> 13) & 1, kb = idx >> 14;
    int k = kb * 32 + kg * 8 + e;
    float sc = g[col] * rsqrtf(v[col] + BN_EPS);
    float x = w[(size_t)col * kdim + k] * sc;
    unsigned short hi = f2bf(x);
    outp[idx] = plane ? f2bf(x - bf2f(hi)) : hi;
}
// conv weights (both layers): [layer][kb(4)][plane][kg(4)][col(128)][e(8)], value = w_ev[k][col]
__global__ __launch_bounds__(256) void k_prep_conv(const float* __restrict__ we0,
                                                   const float* __restrict__ we1,
                                                   unsigned short* __restrict__ Wc0,
                                                   unsigned short* __restrict__ Wc1) {
    int idx = blockIdx.x * 256 + threadIdx.x;   // 65536 total
    int e = idx & 7, col = (idx >> 3) & 127, kg = (idx >> 10) & 3;
    int plane = (idx >> 12) & 1, kb = (idx >> 13) & 3, layer = idx >> 15;
    int k = kb * 32 + kg * 8 + e;
    const float* we = layer ? we1 : we0;
    float x = we[(size_t)k * C_DIM + col];
    unsigned short hi = f2bf(x);
    unsigned short o = plane ? f2bf(x - bf2f(hi)) : hi;
    (layer ? Wc1 : Wc0)[idx & 32767] = o;
}

__global__ __launch_bounds__(512) void k_prep_shift(
    const float* __restrict__ lb0, const float* __restrict__ bg0, const float* __restrict__ bb0,
    const float* __restrict__ bm0, const float* __restrict__ bv0,
    const float* __restrict__ lb1, const float* __restrict__ bg1, const float* __restrict__ bb1,
    const float* __restrict__ bm1, const float* __restrict__ bv1,
    float* __restrict__ shift0, float* __restrict__ shift1) {
    int j = threadIdx.x;
    if (j < 256) {
        float sc = bg0[j] * rsqrtf(bv0[j] + BN_EPS);
        shift0[j] = (lb0[j] - bm0[j]) * sc + bb0[j];
    } else {
        int i = j - 256;
        float sc = bg1[i] * rsqrtf(bv1[i] + BN_EPS);
        shift1[i] = (lb1[i] - bm1[i]) * sc + bb1[i];
    }
}

// ---------------- conv GEMM: y = relu(agg @ W) via bf16 hi/lo MFMA ----------------
__global__ __launch_bounds__(512) void k_gemm(const float* __restrict__ agg,
                                              const unsigned short* __restrict__ Wc,
                                              float* __restrict__ y) {
    __shared__ __align__(16) char smem[3 * 8192];
    const int t = threadIdx.x, lane = t & 63, wave = t >> 6;
    const int qg = wave >> 1, ch = wave & 1;
    const int l16 = lane & 15, kg = lane >> 4;
    const int qrow = qg * 16 + l16;
    const int node = blockIdx.x * 64 + qrow;
    const int nodec = node < N_NODES ? node : N_NODES - 1;

    auto STG = [&](int sidx, int b) {
        const char* g = (const char*)Wc + sidx * 8192 + wave * 1024 + lane * 16;
        char* d = smem + b * 8192 + wave * 1024;
        __builtin_amdgcn_global_load_lds((const __attribute__((address_space(1))) void*)g,
                                         (__attribute__((address_space(3))) void*)d, 16, 0, 0);
    };
    STG(0, 0); STG(1, 1);

    bf16x8 bh[4], bl[4];
    const float* ar = agg + (size_t)nodec * C_DIM;
#pragma unroll
    for (int kb = 0; kb < 4; ++kb) {
        int k0 = kb * 32 + kg * 8;
        f32x4 a0 = *(const f32x4*)(ar + k0);
        f32x4 a1 = *(const f32x4*)(ar + k0 + 4);
#pragma unroll
        for (int e = 0; e < 4; ++e) {
            unsigned short h0 = f2bf(a0[e]);
            bh[kb][e] = (short)h0; bl[kb][e] = (short)f2bf(a0[e] - bf2f(h0));
            unsigned short h1 = f2bf(a1[e]);
            bh[kb][e + 4] = (short)h1; bl[kb][e + 4] = (short)f2bf(a1[e] - bf2f(h1));
        }
    }
    f32x4 acc[4];
#pragma unroll
    for (int i = 0; i < 4; ++i) acc[i] = 0.f;

#pragma unroll
    for (int s = 0; s < 8; ++s) {
        if (s < 7) { VMCNT1; } else { VMCNT0; }
        SBAR;
        if (s + 2 < 8) STG(s + 2, (s + 2) % 3);
        const unsigned short* strip = (const unsigned short*)(smem + (s % 3) * 8192);
        const int kb = s >> 1;
        __builtin_amdgcn_s_setprio(1);
#pragma unroll
        for (int jc8 = 0; jc8 < 4; ++jc8) {
            int col = (ch * 4 + jc8) * 16 + l16;
            bf16x8 a = *(const bf16x8*)&strip[kg * 1024 + col * 8];
            acc[jc8] = __builtin_amdgcn_mfma_f32_16x16x32_bf16(a, bh[kb], acc[jc8], 0, 0, 0);
            if ((s & 1) == 0)
                acc[jc8] = __builtin_amdgcn_mfma_f32_16x16x32_bf16(a, bl[kb], acc[jc8], 0, 0, 0);
        }
        __builtin_amdgcn_s_setprio(0);
    }

    if (node < N_NODES) {
#pragma unroll
        for (int jc8 = 0; jc8 < 4; ++jc8) {
            int j0 = (ch * 4 + jc8) * 16 + kg * 4;
            float4 v;
            v.x = fmaxf(acc[jc8][0], 0.f); v.y = fmaxf(acc[jc8][1], 0.f);
            v.z = fmaxf(acc[jc8][2], 0.f); v.w = fmaxf(acc[jc8][3], 0.f);
            *(float4*)(y + (size_t)node * C_DIM + j0) = v;
        }
    }
}

// ---------------- fused query MLP (2-term bf16 MFMA, 32qx64c waves, coop h-stage) ----------------
// 64 q/block, 512 thr, 8 waves: wave = qs*4+cg, qs in {0,1} (32-q half), cg in {0..3}
// (64-col quarter). Weights hi+lo planes (strips), activations bf16 hi only.
// LDS 80KB -> 2 blocks/CU: [0,48K) 3x16KB strips; [48K,80K) l1b (h then h1).
__global__ __launch_bounds__(512, 4) void k_mlp(const float* __restrict__ y,
                                             const int* __restrict__ e1,
                                             const int* __restrict__ e2,
                                             const unsigned short* __restrict__ W0p,
                                             const unsigned short* __restrict__ W1p,
                                             const float* __restrict__ shift0,
                                             const float* __restrict__ shift1,
                                             const float* __restrict__ w2,
                                             const float* __restrict__ b2,
                                             float* __restrict__ out) {
    __shared__ __align__(16) char smem[81920];
    unsigned short* l1b = (unsigned short*)(smem + 49152);   // 64 x 256 shorts
    float* red = (float*)smem;                               // 2KB, epilogue only

    const int t = threadIdx.x;
    const int lane = t & 63;
    const int wave = t >> 6;
    const int qs = wave >> 2, cg = wave & 3;
    const int l16 = lane & 15, kg = lane >> 4;
    const int qb = blockIdx.x * 64;

    auto STG = [&](const unsigned short* W, int sidx, int b) {
        const char* g = (const char*)W + ((size_t)sidx << 14) + wave * 2048 + lane * 16;
        char* d = smem + b * 16384 + wave * 2048;
        __builtin_amdgcn_global_load_lds((const __attribute__((address_space(1))) void*)g,
                                         (__attribute__((address_space(3))) void*)d, 16, 0, 0);
        __builtin_amdgcn_global_load_lds((const __attribute__((address_space(1))) void*)(g + 1024),
                                         (__attribute__((address_space(3))) void*)(d + 1024), 16, 0, 0);
    };

    STG(W0p, 0, 0); STG(W0p, 1, 1);   // overlap with phase 0

    // ---- phase 0: cooperative h staging (each query row gathered ONCE/block) ----
    {
        int k2 = lane * 2;
        int G = lane >> 2;            // k-granule 0..15
        int off = k2 & 7;
#pragma unroll
        for (int qi = 0; qi < 8; ++qi) {
            int qrow = wave * 8 + qi;
            int q = qb + qrow; if (q >= Q_PAIRS) q = Q_PAIRS - 1;
            const float* ya = y + (size_t)e1[q] * C_DIM;
            const float* yb = y + (size_t)e2[q] * C_DIM;
            float2 a = *(const float2*)(ya + k2);
            float2 b = *(const float2*)(yb + k2);
            int idx = qrow * 256 + ((G ^ (qrow & 7)) << 3) + off;
            l1b[idx] = f2bf(a.x * b.x);
            l1b[idx + 1] = f2bf(a.y * b.y);
        }
    }
    __syncthreads();   // h visible

    // ---- pickup h fragments into regs (proven bh2-path layout) ----
    bf16x8 bh[2][4];
#pragma unroll
    for (int qq = 0; qq < 2; ++qq) {
        int qrow = qs * 32 + qq * 16 + l16;
#pragma unroll
        for (int kb = 0; kb < 4; ++kb) {
            int gidx = qrow * 256 + (((kb * 4 + kg) ^ (qrow & 7)) * 8);
            bh[qq][kb] = *(const bf16x8*)&l1b[gidx];
        }
    }

    f32x4 acc[2][4];
#pragma unroll
    for (int qq = 0; qq < 2; ++qq)
#pragma unroll
        for (int jc = 0; jc < 4; ++jc) acc[qq][jc] = 0.f;

    // ---- layer 1: 8 strips (4 kb x {hi,lo}), 2-term: (Whi+Wlo) x bh ----
#pragma unroll
    for (int s = 0; s < 8; ++s) {
        if (s < 7) { VMCNT2; } else { VMCNT0; }
        SBAR;
        if (s + 2 < 8) STG(W0p, s + 2, (s + 2) % 3);
        const unsigned short* strip = (const unsigned short*)(smem + (s % 3) * 16384);
        const int kb = s >> 1;
        __builtin_amdgcn_s_setprio(1);
#pragma unroll
        for (int jc = 0; jc < 4; ++jc) {
            int col = cg * 64 + jc * 16 + l16;
            bf16x8 a = *(const bf16x8*)&strip[kg * 2048 + col * 8];
            acc[0][jc] = __builtin_amdgcn_mfma_f32_16x16x32_bf16(a, bh[0][kb], acc[0][jc], 0, 0, 0);
            acc[1][jc] = __builtin_amdgcn_mfma_f32_16x16x32_bf16(a, bh[1][kb], acc[1][jc], 0, 0, 0);
        }
        __builtin_amdgcn_s_setprio(0);
    }

    // ---- epilogue 1: BN-shift + relu -> l1b (bf16 hi only, swizzled granules) ----
    // all pickups happened pre-loop; loop barriers guarantee no l1b readers remain
#pragma unroll
    for (int qq = 0; qq < 2; ++qq) {
        int qrow = qs * 32 + qq * 16 + l16;
#pragma unroll
        for (int jc = 0; jc < 4; ++jc) {
            int jg = cg * 4 + jc;
            int j0 = jg * 16 + kg * 4;
            f32x4 sh = *(const f32x4*)(shift0 + j0);
            s16x4 th;
#pragma unroll
            for (int r = 0; r < 4; ++r)
                th[r] = (short)f2bf(fmaxf(acc[qq][jc][r] + sh[r], 0.f));
            int G = jg * 2 + (kg >> 1);
            int idx = qrow * 256 + ((G ^ (qrow & 7)) * 8) + (kg & 1) * 4;
            *(s16x4*)&l1b[idx] = th;
        }
    }
    __syncthreads();   // h1 visible; all strip reads of layer 1 complete

    // ---- layer 2: 16 strips (8 kb x {hi,lo}), 2-term ----
    f32x4 acc2[2][4];
#pragma unroll
    for (int qq = 0; qq < 2; ++qq)
#pragma unroll
        for (int jc = 0; jc < 4; ++jc) acc2[qq][jc] = 0.f;
    STG(W1p, 0, 0); STG(W1p, 1, 1);
    bf16x8 bh2[2];
#pragma unroll
    for (int s = 0; s < 16; ++s) {
        if (s < 15) { VMCNT2; } else { VMCNT0; }
        SBAR;
        if (s + 2 < 16) STG(W1p, s + 2, (s + 2) % 3);
        const unsigned short* strip = (const unsigned short*)(smem + (s % 3) * 16384);
        const int kb = s >> 1;
        if ((s & 1) == 0) {   // read B-frags once per kb, reuse on lo strip
#pragma unroll
            for (int qq = 0; qq < 2; ++qq) {
                int qrow = qs * 32 + qq * 16 + l16;
                int gidx = qrow * 256 + (((kb * 4 + kg) ^ (qrow & 7)) * 8);
                bh2[qq] = *(const bf16x8*)&l1b[gidx];
            }
        }
        __builtin_amdgcn_s_setprio(1);
#pragma unroll
        for (int jc = 0; jc < 4; ++jc) {
            int col = cg * 64 + jc * 16 + l16;
            bf16x8 a = *(const bf16x8*)&strip[kg * 2048 + col * 8];
            acc2[0][jc] = __builtin_amdgcn_mfma_f32_16x16x32_bf16(a, bh2[0], acc2[0][jc], 0, 0, 0);
            acc2[1][jc] = __builtin_amdgcn_mfma_f32_16x16x32_bf16(a, bh2[1], acc2[1][jc], 0, 0, 0);
        }
        __builtin_amdgcn_s_setprio(0);
    }

    // ---- layer 3: BN-shift + relu + 256->2 partials ----
    float p[2][2] = {};   // [qq][cls]
#pragma unroll
    for (int qq = 0; qq < 2; ++qq)
#pragma unroll
        for (int jc = 0; jc < 4; ++jc) {
            int j0 = (cg * 4 + jc) * 16 + kg * 4;
            f32x4 sh = *(const f32x4*)(shift1 + j0);
            f32x4 wa = *(const f32x4*)(w2 + j0);
            f32x4 wb = *(const f32x4*)(w2 + H_DIM + j0);
#pragma unroll
            for (int r = 0; r < 4; ++r) {
                float v = fmaxf(acc2[qq][jc][r] + sh[r], 0.f);
                p[qq][0] += v * wa[r];
                p[qq][1] += v * wb[r];
            }
        }
    // reduce over kg groups (lanes l16, l16+16, l16+32, l16+48)
#pragma unroll
    for (int qq = 0; qq < 2; ++qq) {
        p[qq][0] += __shfl_xor(p[qq][0], 16, 64); p[qq][0] += __shfl_xor(p[qq][0], 32, 64);
        p[qq][1] += __shfl_xor(p[qq][1], 16, 64); p[qq][1] += __shfl_xor(p[qq][1], 32, 64);
    }
    __syncthreads();   // all strip reads done; strip region reusable as red
    if (kg == 0) {
#pragma unroll
        for (int qq = 0; qq < 2; ++qq) {
            int base = ((qs * 2 + qq) * 16 + l16) * 2;
            red[(base + 0) * 4 + cg] = p[qq][0];
            red[(base + 1) * 4 + cg] = p[qq][1];
        }
    }
    __syncthreads();
    if (t < 64) {
        int q = qb + t;
        if (q < Q_PAIRS) {
            int base = t * 2;
            float l0 = red[base * 4 + 0] + red[base * 4 + 1] + red[base * 4 + 2] + red[base * 4 + 3] + b2[0];
            float l1v = red[(base + 1) * 4 + 0] + red[(base + 1) * 4 + 1]
                      + red[(base + 1) * 4 + 2] + red[(base + 1) * 4 + 3] + b2[1];
            float mx = fmaxf(l0, l1v);
            float lse = mx + logf(expf(l0 - mx) + expf(l1v - mx));
            float2 o; o.x = l0 - lse; o.y = l1v - lse;
            *(float2*)(out + (size_t)q * N_CLS) = o;
        }
    }
}

// ---------------- launch ----------------
extern "C" void kernel_launch(void* const* d_in, const int* in_sizes, int n_in,
                              void* d_out, int out_size, void* d_ws, size_t ws_size,
                              hipStream_t stream) {
    const float* X  = (const float*)d_in[0];
    const int*   ei = (const int*)d_in[1];
    const float* ew = (const float*)d_in[2];
    const int*   e1 = (const int*)d_in[3];
    const int*   e2 = (const int*)d_in[4];
    const float* w_init[2] = {(const float*)d_in[5],  (const float*)d_in[10]};
    const float* w_ih[2]   = {(const float*)d_in[6],  (const float*)d_in[11]};
    const float* w_hh[2]   = {(const float*)d_in[7],  (const float*)d_in[12]};
    const float* b_ih[2]   = {(const float*)d_in[8],  (const float*)d_in[13]};
    const float* b_hh[2]   = {(const float*)d_in[9],  (const float*)d_in[14]};
    const float* lw0 = (const float*)d_in[15]; const float* lb0 = (const float*)d_in[16];
    const float* lw1 = (const float*)d_in[17]; const float* lb1 = (const float*)d_in[18];
    const float* lw2 = (const float*)d_in[19]; const float* lb2 = (const float*)d_in[20];
    const float* bg0 = (const float*)d_in[21]; const float* bb0 = (const float*)d_in[22];
    const float* bm0 = (const float*)d_in[23]; const float* bv0 = (const float*)d_in[24];
    const float* bg1 = (const float*)d_in[25]; const float* bb1 = (const float*)d_in[26];
    const float* bm1 = (const float*)d_in[27]; const float* bv1 = (const float*)d_in[28];
    const int* src = ei;
    const int* dst = ei + E_EDGES;

    char* ws = (char*)d_ws;
    size_t o = 0;
    auto alloc = [&](size_t bytes) { char* p = ws + o; o += (bytes + 63) & ~(size_t)63; return p; };
    float* bufA   = (float*)alloc((size_t)N_NODES * C_DIM * 4);   // agg
    float* bufB   = (float*)alloc((size_t)N_NODES * C_DIM * 4);   // y
    float* dinv   = (float*)alloc(N_NODES * 4);
    float* we0    = (float*)alloc(C_DIM * C_DIM * 4);
    float* we1    = (float*)alloc(C_DIM * C_DIM * 4);
    float* shift0 = (float*)alloc(H_DIM * 4);
    float* shift1 = (float*)alloc(H_DIM * 4);
    int*   cnt    = (int*)alloc(N_NODES * 4);
    int*   pos    = (int*)alloc(N_NODES * 4);
    int*   off    = (int*)alloc((N_NODES + 1) * 4);
    int*   bsum   = (int*)alloc(64 * 4);
    int*   boff   = (int*)alloc(64 * 4);
    int2*  csr    = (int2*)alloc((size_t)E_EDGES * 8);
    unsigned short* W0p = (unsigned short*)alloc(65536 * 2);    // 128KB
    unsigned short* W1p = (unsigned short*)alloc(131072 * 2);   // 256KB
    unsigned short* Wc0 = (unsigned short*)alloc(32768 * 2);    // 64KB
    unsigned short* Wc1 = (unsigned short*)alloc(32768 * 2);    // 64KB
    if (o > ws_size) return;

    dim3 b256(256);
    const int gN = (N_NODES + 255) / 256;
    const int gE = (E_EDGES + 255) / 256;

    // degrees + CSR
    k_init<<<gN, b256, 0, stream>>>(dinv, cnt);
    k_deg_hist<<<gE, b256, 0, stream>>>(dst, ew, dinv, cnt);
    k_deg_fin<<<gN, b256, 0, stream>>>(dinv);
    k_scan1<<<49, dim3(1024), 0, stream>>>(cnt, pos, bsum);
    k_scan2<<<1, dim3(64), 0, stream>>>(bsum, boff);
    k_scan3<<<49, dim3(1024), 0, stream>>>(cnt, pos, boff, off);
    k_fill<<<gE, b256, 0, stream>>>(src, dst, ew, dinv, pos, csr);

    // GRU (both layers) + weight preps
    k_gru2<<<256, dim3(128), 0, stream>>>(w_init[0], w_ih[0], w_hh[0], b_ih[0], b_hh[0], we0,
                                          w_init[1], w_ih[1], w_hh[1], b_ih[1], b_hh[1], we1);
    k_prep_conv<<<256, b256, 0, stream>>>(we0, we1, Wc0, Wc1);
    k_prep_w<<<256, b256, 0, stream>>>(lw0, bg0, bv0, C_DIM, 65536, W0p);
    k_prep_w<<<512, b256, 0, stream>>>(lw1, bg1, bv1, H_DIM, 131072, W1p);
    k_prep_shift<<<1, dim3(512), 0, stream>>>(lb0, bg0, bb0, bm0, bv0, lb1, bg1, bb1, bm1, bv1, shift0, shift1);

    const int ga = (N_NODES * 32) / 256;          // 6250
    const int gg = (N_NODES + 63) / 64;           // 782
    // layer 0: aggregate-then-multiply (A(XW) == (AX)W)
    k_agg<<<ga, b256, 0, stream>>>(X, dinv, off, csr, bufA);
    k_gemm<<<gg, dim3(512), 0, stream>>>(bufA, Wc0, bufB);
    // layer 1
    k_agg<<<ga, b256, 0, stream>>>(bufB, dinv, off, csr, bufA);
    k_gemm<<<gg, dim3(512), 0, stream>>>(bufA, Wc1, bufB);
    // fused MFMA MLP
    k_mlp<<<(Q_PAIRS + 63) / 64, dim3(512), 0, stream>>>(bufB, e1, e2, W0p, W1p, shift0, shift1,
                                                         lw2, lb2, (float*)d_out);
}

// Round 9
// 711.221 us; speedup vs baseline: 11.8196x; 1.0490x over previous
//
#include <hip/hip_runtime.h>
#include <math.h>

#define N_NODES 50000
#define C_DIM   128
#define E_EDGES 1600000
#define Q_PAIRS 500000
#define H_DIM   256
#define N_CLS   2
#define BN_EPS  1e-5f

typedef __attribute__((ext_vector_type(8))) short bf16x8;
typedef __attribute__((ext_vector_type(4))) short s16x4;
typedef __attribute__((ext_vector_type(4))) unsigned short u16x4;
typedef __attribute__((ext_vector_type(4))) float f32x4;

#define VMCNT0 asm volatile("s_waitcnt vmcnt(0)" ::: "memory")
#define VMCNT1 asm volatile("s_waitcnt vmcnt(1)" ::: "memory")
#define VMCNT2 asm volatile("s_waitcnt vmcnt(2)" ::: "memory")
#define SBAR do { __builtin_amdgcn_s_barrier(); \
                  __builtin_amdgcn_sched_barrier(0); } while (0)

__device__ __forceinline__ unsigned short f2bf(float x) {   // RNE f32->bf16 bits
    unsigned u = __float_as_uint(x);
    u += 0x7fffu + ((u >> 16) & 1u);
    return (unsigned short)(u >> 16);
}
__device__ __forceinline__ float bf2f(unsigned short h) {
    return __uint_as_float(((unsigned)h) << 16);
}

// ---------------- init + degree/hist ----------------
__global__ __launch_bounds__(256) void k_init(float* deg, int* cnt, int* qcnt) {
    int i = blockIdx.x * 256 + threadIdx.x;
    if (i < N_NODES) { deg[i] = 1.0f; cnt[i] = 0; qcnt[i] = 0; }
}
__global__ __launch_bounds__(256) void k_deg_hist(const int* __restrict__ dst,
                                                  const float* __restrict__ ew,
                                                  float* deg, int* cnt) {
    int e = blockIdx.x * 256 + threadIdx.x;
    if (e < E_EDGES) {
        int d = dst[e];
        unsafeAtomicAdd(&deg[d], ew[e]);
        atomicAdd(&cnt[d], 1);
    }
}
__global__ __launch_bounds__(256) void k_deg_fin(float* deg) {
    int i = blockIdx.x * 256 + threadIdx.x;
    if (i < N_NODES) deg[i] = rsqrtf(deg[i]);
}
__global__ __launch_bounds__(256) void k_qhist(const int* __restrict__ e1, int* qcnt) {
    int q = blockIdx.x * 256 + threadIdx.x;
    if (q < Q_PAIRS) atomicAdd(&qcnt[e1[q]], 1);
}

// ---------------- multi-block scan (3 kernels, bins = N_NODES) ----------------
__global__ __launch_bounds__(1024) void k_scan1(const int* __restrict__ cnt,
                                                int* __restrict__ locincl,
                                                int* __restrict__ bsum) {
    __shared__ int pa[1024], pb[1024];
    int t = threadIdx.x;
    int x = blockIdx.x * 1024 + t;
    int v = (x < N_NODES) ? cnt[x] : 0;
    pa[t] = v;
    __syncthreads();
    int* sp = pa; int* dp = pb;
    for (int o = 1; o < 1024; o <<= 1) {
        int u = sp[t] + ((t >= o) ? sp[t - o] : 0);
        dp[t] = u;
        __syncthreads();
        int* tmp = sp; sp = dp; dp = tmp;
    }
    if (x < N_NODES) locincl[x] = sp[t];
    if (t == 1023) bsum[blockIdx.x] = sp[1023];
}
__global__ __launch_bounds__(64) void k_scan2(const int* __restrict__ bsum,
                                              int* __restrict__ boff) {
    int t = threadIdx.x;
    int v = (t < 49) ? bsum[t] : 0;
    int own = v;
    for (int o = 1; o < 64; o <<= 1) {
        int u = __shfl_up(v, o, 64);
        if (t >= o) v += u;
    }
    if (t < 49) boff[t] = v - own;   // exclusive
}
__global__ __launch_bounds__(1024) void k_scan3(const int* __restrict__ cnt,
                                                int* __restrict__ pos,
                                                const int* __restrict__ boff,
                                                int* __restrict__ off) {
    int x = blockIdx.x * 1024 + threadIdx.x;
    if (x >= N_NODES) return;
    int incl = pos[x];
    int c = cnt[x];
    int o = boff[blockIdx.x] + incl - c;
    off[x] = o;
    pos[x] = o;
    if (x == N_NODES - 1) off[N_NODES] = o + c;
}

// packed CSR entry: .x = src node, .y = float weight bits
__global__ __launch_bounds__(256) void k_fill(const int* __restrict__ src,
                                              const int* __restrict__ dst,
                                              const float* __restrict__ ew,
                                              const float* __restrict__ dinv,
                                              int* pos,
                                              int2* __restrict__ csr) {
    int e = blockIdx.x * 256 + threadIdx.x;
    if (e >= E_EDGES) return;
    int s = src[e], d = dst[e];
    int slot = atomicAdd(&pos[d], 1);
    int2 p;
    p.x = s;
    p.y = __float_as_int(dinv[s] * ew[e] * dinv[d]);
    csr[slot] = p;
}
// query sort fill: qpair[slot] = (e1,e2), qidx[slot] = original q
__global__ __launch_bounds__(256) void k_qfill(const int* __restrict__ e1,
                                               const int* __restrict__ e2,
                                               int* qpos,
                                               int2* __restrict__ qpair,
                                               int* __restrict__ qidx) {
    int q = blockIdx.x * 256 + threadIdx.x;
    if (q >= Q_PAIRS) return;
    int a = e1[q];
    int slot = atomicAdd(&qpos[a], 1);
    int2 p; p.x = a; p.y = e2[q];
    qpair[slot] = p;
    qidx[slot] = q;
}

// ---------------- GRU weight evolution (both layers in one launch) ----------------
__global__ __launch_bounds__(128) void k_gru2(
    const float* __restrict__ wi0, const float* __restrict__ wih0, const float* __restrict__ whh0,
    const float* __restrict__ bih0, const float* __restrict__ bhh0, float* __restrict__ we0,
    const float* __restrict__ wi1, const float* __restrict__ wih1, const float* __restrict__ whh1,
    const float* __restrict__ bih1, const float* __restrict__ bhh1, float* __restrict__ we1) {
    __shared__ float xrow[C_DIM];
    int layer = blockIdx.x >> 7;
    int i = blockIdx.x & 127, j = threadIdx.x;
    const float* w_init = layer ? wi1 : wi0;
    const float* wih = layer ? wih1 : wih0;
    const float* whh = layer ? whh1 : whh0;
    const float* bih = layer ? bih1 : bih0;
    const float* bhh = layer ? bhh1 : bhh0;
    float* w_out = layer ? we1 : we0;
    xrow[j] = w_init[i * C_DIM + j];
    __syncthreads();
    float gi[3], gh[3];
#pragma unroll
    for (int g = 0; g < 3; ++g) {
        const float* wi = wih + (size_t)(g * C_DIM + j) * C_DIM;
        const float* wh = whh + (size_t)(g * C_DIM + j) * C_DIM;
        float ai = 0.f, ah = 0.f;
        for (int k = 0; k < C_DIM; ++k) { ai += xrow[k] * wi[k]; ah += xrow[k] * wh[k]; }
        gi[g] = ai + bih[g * C_DIM + j];
        gh[g] = ah + bhh[g * C_DIM + j];
    }
    float r = 1.f / (1.f + expf(-(gi[0] + gh[0])));
    float z = 1.f / (1.f + expf(-(gi[1] + gh[1])));
    float n = tanhf(gi[2] + r * gh[2]);
    w_out[i * C_DIM + j] = (1.f - z) * n + z * xrow[j];
}

// ---------------- X -> bf16 ----------------
__global__ __launch_bounds__(256) void k_xbf(const float* __restrict__ x,
                                             unsigned short* __restrict__ xb) {
    int i = (blockIdx.x * 256 + threadIdx.x) * 8;
    f32x4 a = *(const f32x4*)(x + i);
    f32x4 b = *(const f32x4*)(x + i + 4);
    bf16x8 o;
#pragma unroll
    for (int e = 0; e < 4; ++e) { o[e] = (short)f2bf(a[e]); o[e + 4] = (short)f2bf(b[e]); }
    *(bf16x8*)(xb + i) = o;
}

// ---------------- CSR aggregation from bf16 rows: agg = dinv^2 x + sum w_e x[src] ----------------
__global__ __launch_bounds__(256) void k_agg(const unsigned short* __restrict__ xb,
                                             const float* __restrict__ dinv,
                                             const int* __restrict__ off,
                                             const int2* __restrict__ csr,
                                             float* __restrict__ agg) {
    int tid = blockIdx.x * 256 + threadIdx.x;
    int n = tid >> 5;
    int c = (tid & 31) << 2;
    float dv = dinv[n];
    float d2 = dv * dv;
    u16x4 xs = *(const u16x4*)(xb + (size_t)n * C_DIM + c);
    float4 acc;
    acc.x = d2 * bf2f(xs[0]); acc.y = d2 * bf2f(xs[1]);
    acc.z = d2 * bf2f(xs[2]); acc.w = d2 * bf2f(xs[3]);
    int i = off[n], e = off[n + 1];
    for (; i + 8 <= e; i += 8) {
        int2 q0 = csr[i], q1 = csr[i + 1], q2 = csr[i + 2], q3 = csr[i + 3];
        int2 q4 = csr[i + 4], q5 = csr[i + 5], q6 = csr[i + 6], q7 = csr[i + 7];
        u16x4 v0 = *(const u16x4*)(xb + (size_t)q0.x * C_DIM + c);
        u16x4 v1 = *(const u16x4*)(xb + (size_t)q1.x * C_DIM + c);
        u16x4 v2 = *(const u16x4*)(xb + (size_t)q2.x * C_DIM + c);
        u16x4 v3 = *(const u16x4*)(xb + (size_t)q3.x * C_DIM + c);
        u16x4 v4 = *(const u16x4*)(xb + (size_t)q4.x * C_DIM + c);
        u16x4 v5 = *(const u16x4*)(xb + (size_t)q5.x * C_DIM + c);
        u16x4 v6 = *(const u16x4*)(xb + (size_t)q6.x * C_DIM + c);
        u16x4 v7 = *(const u16x4*)(xb + (size_t)q7.x * C_DIM + c);
        float w0 = __int_as_float(q0.y), w1 = __int_as_float(q1.y);
        float w2 = __int_as_float(q2.y), w3 = __int_as_float(q3.y);
        float w4 = __int_as_float(q4.y), w5 = __int_as_float(q5.y);
        float w6 = __int_as_float(q6.y), w7 = __int_as_float(q7.y);
        acc.x += w0 * bf2f(v0[0]) + w1 * bf2f(v1[0]) + w2 * bf2f(v2[0]) + w3 * bf2f(v3[0])
               + w4 * bf2f(v4[0]) + w5 * bf2f(v5[0]) + w6 * bf2f(v6[0]) + w7 * bf2f(v7[0]);
        acc.y += w0 * bf2f(v0[1]) + w1 * bf2f(v1[1]) + w2 * bf2f(v2[1]) + w3 * bf2f(v3[1])
               + w4 * bf2f(v4[1]) + w5 * bf2f(v5[1]) + w6 * bf2f(v6[1]) + w7 * bf2f(v7[1]);
        acc.z += w0 * bf2f(v0[2]) + w1 * bf2f(v1[2]) + w2 * bf2f(v2[2]) + w3 * bf2f(v3[2])
               + w4 * bf2f(v4[2]) + w5 * bf2f(v5[2]) + w6 * bf2f(v6[2]) + w7 * bf2f(v7[2]);
        acc.w += w0 * bf2f(v0[3]) + w1 * bf2f(v1[3]) + w2 * bf2f(v2[3]) + w3 * bf2f(v3[3])
               + w4 * bf2f(v4[3]) + w5 * bf2f(v5[3]) + w6 * bf2f(v6[3]) + w7 * bf2f(v7[3]);
    }
    for (; i < e; ++i) {
        int2 pe = csr[i];
        float w = __int_as_float(pe.y);
        u16x4 v = *(const u16x4*)(xb + (size_t)pe.x * C_DIM + c);
        acc.x += w * bf2f(v[0]); acc.y += w * bf2f(v[1]);
        acc.z += w * bf2f(v[2]); acc.w += w * bf2f(v[3]);
    }
    *(float4*)(agg + (size_t)n * C_DIM + c) = acc;
}

// ---------------- weight prep ----------------
// MLP weights: [kb][plane][kg(4)][col(256)][e(8)]
__global__ __launch_bounds__(256) void k_prep_w(const float* __restrict__ w,
                                                const float* __restrict__ g,
                                                const float* __restrict__ v,
                                                int kdim, int total,
                                                unsigned short* __restrict__ outp) {
    int idx = blockIdx.x * 256 + threadIdx.x;
    if (idx >= total) return;
    int e = idx & 7, col = (idx >> 3) & 255, kg = (idx >> 11) & 3;
    int plane = (idx >> 13) & 1, kb = idx >> 14;
    int k = kb * 32 + kg * 8 + e;
    float sc = g[col] * rsqrtf(v[col] + BN_EPS);
    float x = w[(size_t)col * kdim + k] * sc;
    unsigned short hi = f2bf(x);
    outp[idx] = plane ? f2bf(x - bf2f(hi)) : hi;
}
// conv weights (both layers): [layer][kb(4)][plane][kg(4)][col(128)][e(8)]
__global__ __launch_bounds__(256) void k_prep_conv(const float* __restrict__ we0,
                                                   const float* __restrict__ we1,
                                                   unsigned short* __restrict__ Wc0,
                                                   unsigned short* __restrict__ Wc1) {
    int idx = blockIdx.x * 256 + threadIdx.x;   // 65536 total
    int e = idx & 7, col = (idx >> 3) & 127, kg = (idx >> 10) & 3;
    int plane = (idx >> 12) & 1, kb = (idx >> 13) & 3, layer = idx >> 15;
    int k = kb * 32 + kg * 8 + e;
    const float* we = layer ? we1 : we0;
    float x = we[(size_t)k * C_DIM + col];
    unsigned short hi = f2bf(x);
    unsigned short o = plane ? f2bf(x - bf2f(hi)) : hi;
    (layer ? Wc1 : Wc0)[idx & 32767] = o;
}

__global__ __launch_bounds__(512) void k_prep_shift(
    const float* __restrict__ lb0, const float* __restrict__ bg0, const float* __restrict__ bb0,
    const float* __restrict__ bm0, const float* __restrict__ bv0,
    const float* __restrict__ lb1, const float* __restrict__ bg1, const float* __restrict__ bb1,
    const float* __restrict__ bm1, const float* __restrict__ bv1,
    float* __restrict__ shift0, float* __restrict__ shift1) {
    int j = threadIdx.x;
    if (j < 256) {
        float sc = bg0[j] * rsqrtf(bv0[j] + BN_EPS);
        shift0[j] = (lb0[j] - bm0[j]) * sc + bb0[j];
    } else {
        int i = j - 256;
        float sc = bg1[i] * rsqrtf(bv1[i] + BN_EPS);
        shift1[i] = (lb1[i] - bm1[i]) * sc + bb1[i];
    }
}

// ---------------- conv GEMM: y = relu(agg @ W); OUT_BF: write bf16 rows ----------------
template <int OUT_BF>
__global__ __launch_bounds__(512) void k_gemm(const float* __restrict__ agg,
                                              const unsigned short* __restrict__ Wc,
                                              float* __restrict__ y,
                                              unsigned short* __restrict__ yb) {
    __shared__ __align__(16) char smem[3 * 8192];
    const int t = threadIdx.x, lane = t & 63, wave = t >> 6;
    const int qg = wave >> 1, ch = wave & 1;
    const int l16 = lane & 15, kg = lane >> 4;
    const int qrow = qg * 16 + l16;
    const int node = blockIdx.x * 64 + qrow;
    const int nodec = node < N_NODES ? node : N_NODES - 1;

    auto STG = [&](int sidx, int b) {
        const char* g = (const char*)Wc + sidx * 8192 + wave * 1024 + lane * 16;
        char* d = smem + b * 8192 + wave * 1024;
        __builtin_amdgcn_global_load_lds((const __attribute__((address_space(1))) void*)g,
                                         (__attribute__((address_space(3))) void*)d, 16, 0, 0);
    };
    STG(0, 0); STG(1, 1);

    bf16x8 bh[4], bl[4];
    const float* ar = agg + (size_t)nodec * C_DIM;
#pragma unroll
    for (int kb = 0; kb < 4; ++kb) {
        int k0 = kb * 32 + kg * 8;
        f32x4 a0 = *(const f32x4*)(ar + k0);
        f32x4 a1 = *(const f32x4*)(ar + k0 + 4);
#pragma unroll
        for (int e = 0; e < 4; ++e) {
            unsigned short h0 = f2bf(a0[e]);
            bh[kb][e] = (short)h0; bl[kb][e] = (short)f2bf(a0[e] - bf2f(h0));
            unsigned short h1 = f2bf(a1[e]);
            bh[kb][e + 4] = (short)h1; bl[kb][e + 4] = (short)f2bf(a1[e] - bf2f(h1));
        }
    }
    f32x4 acc[4];
#pragma unroll
    for (int i = 0; i < 4; ++i) acc[i] = 0.f;

#pragma unroll
    for (int s = 0; s < 8; ++s) {
        if (s < 7) { VMCNT1; } else { VMCNT0; }
        SBAR;
        if (s + 2 < 8) STG(s + 2, (s + 2) % 3);
        const unsigned short* strip = (const unsigned short*)(smem + (s % 3) * 8192);
        const int kb = s >> 1;
        __builtin_amdgcn_s_setprio(1);
#pragma unroll
        for (int jc8 = 0; jc8 < 4; ++jc8) {
            int col = (ch * 4 + jc8) * 16 + l16;
            bf16x8 a = *(const bf16x8*)&strip[kg * 1024 + col * 8];
            acc[jc8] = __builtin_amdgcn_mfma_f32_16x16x32_bf16(a, bh[kb], acc[jc8], 0, 0, 0);
            if ((s & 1) == 0)
                acc[jc8] = __builtin_amdgcn_mfma_f32_16x16x32_bf16(a, bl[kb], acc[jc8], 0, 0, 0);
        }
        __builtin_amdgcn_s_setprio(0);
    }

    if (node < N_NODES) {
#pragma unroll
        for (int jc8 = 0; jc8 < 4; ++jc8) {
            int j0 = (ch * 4 + jc8) * 16 + kg * 4;
            if (OUT_BF) {
                u16x4 v;
#pragma unroll
                for (int r = 0; r < 4; ++r) v[r] = f2bf(fmaxf(acc[jc8][r], 0.f));
                *(u16x4*)(yb + (size_t)node * C_DIM + j0) = v;
            } else {
                float4 v;
                v.x = fmaxf(acc[jc8][0], 0.f); v.y = fmaxf(acc[jc8][1], 0.f);
                v.z = fmaxf(acc[jc8][2], 0.f); v.w = fmaxf(acc[jc8][3], 0.f);
                *(float4*)(y + (size_t)node * C_DIM + j0) = v;
            }
        }
    }
}

// ---------------- fused query MLP (2-term bf16 MFMA, e1-sorted queries) ----------------
__global__ __launch_bounds__(512, 4) void k_mlp(const float* __restrict__ y,
                                             const int2* __restrict__ qpair,
                                             const int* __restrict__ qidx,
                                             const unsigned short* __restrict__ W0p,
                                             const unsigned short* __restrict__ W1p,
                                             const float* __restrict__ shift0,
                                             const float* __restrict__ shift1,
                                             const float* __restrict__ w2,
                                             const float* __restrict__ b2,
                                             float* __restrict__ out) {
    __shared__ __align__(16) char smem[81920];
    unsigned short* l1b = (unsigned short*)(smem + 49152);   // 64 x 256 shorts
    float* red = (float*)smem;                               // 2KB, epilogue only

    const int t = threadIdx.x;
    const int lane = t & 63;
    const int wave = t >> 6;
    const int qs = wave >> 2, cg = wave & 3;
    const int l16 = lane & 15, kg = lane >> 4;
    const int qb = blockIdx.x * 64;

    auto STG = [&](const unsigned short* W, int sidx, int b) {
        const char* g = (const char*)W + ((size_t)sidx << 14) + wave * 2048 + lane * 16;
        char* d = smem + b * 16384 + wave * 2048;
        __builtin_amdgcn_global_load_lds((const __attribute__((address_space(1))) void*)g,
                                         (__attribute__((address_space(3))) void*)d, 16, 0, 0);
        __builtin_amdgcn_global_load_lds((const __attribute__((address_space(1))) void*)(g + 1024),
                                         (__attribute__((address_space(3))) void*)(d + 1024), 16, 0, 0);
    };

    STG(W0p, 0, 0); STG(W0p, 1, 1);   // overlap with phase 0

    // ---- phase 0: cooperative h staging (sorted queries: e1 rows L1/L2-local) ----
    {
        int k2 = lane * 2;
        int G = lane >> 2;            // k-granule 0..15
        int off = k2 & 7;
#pragma unroll
        for (int qi = 0; qi < 8; ++qi) {
            int qrow = wave * 8 + qi;
            int q = qb + qrow; if (q >= Q_PAIRS) q = Q_PAIRS - 1;
            int2 pr = qpair[q];
            const float* ya = y + (size_t)pr.x * C_DIM;
            const float* yb = y + (size_t)pr.y * C_DIM;
            float2 a = *(const float2*)(ya + k2);
            float2 b = *(const float2*)(yb + k2);
            int idx = qrow * 256 + ((G ^ (qrow & 7)) << 3) + off;
            l1b[idx] = f2bf(a.x * b.x);
            l1b[idx + 1] = f2bf(a.y * b.y);
        }
    }
    __syncthreads();   // h visible

    // ---- pickup h fragments into regs ----
    bf16x8 bh[2][4];
#pragma unroll
    for (int qq = 0; qq < 2; ++qq) {
        int qrow = qs * 32 + qq * 16 + l16;
#pragma unroll
        for (int kb = 0; kb < 4; ++kb) {
            int gidx = qrow * 256 + (((kb * 4 + kg) ^ (qrow & 7)) * 8);
            bh[qq][kb] = *(const bf16x8*)&l1b[gidx];
        }
    }

    f32x4 acc[2][4];
#pragma unroll
    for (int qq = 0; qq < 2; ++qq)
#pragma unroll
        for (int jc = 0; jc < 4; ++jc) acc[qq][jc] = 0.f;

    // ---- layer 1: 8 strips (4 kb x {hi,lo}), 2-term ----
#pragma unroll
    for (int s = 0; s < 8; ++s) {
        if (s < 7) { VMCNT2; } else { VMCNT0; }
        SBAR;
        if (s + 2 < 8) STG(W0p, s + 2, (s + 2) % 3);
        const unsigned short* strip = (const unsigned short*)(smem + (s % 3) * 16384);
        const int kb = s >> 1;
        __builtin_amdgcn_s_setprio(1);
#pragma unroll
        for (int jc = 0; jc < 4; ++jc) {
            int col = cg * 64 + jc * 16 + l16;
            bf16x8 a = *(const bf16x8*)&strip[kg * 2048 + col * 8];
            acc[0][jc] = __builtin_amdgcn_mfma_f32_16x16x32_bf16(a, bh[0][kb], acc[0][jc], 0, 0, 0);
            acc[1][jc] = __builtin_amdgcn_mfma_f32_16x16x32_bf16(a, bh[1][kb], acc[1][jc], 0, 0, 0);
        }
        __builtin_amdgcn_s_setprio(0);
    }

    // ---- epilogue 1: BN-shift + relu -> l1b (bf16 hi only) ----
#pragma unroll
    for (int qq = 0; qq < 2; ++qq) {
        int qrow = qs * 32 + qq * 16 + l16;
#pragma unroll
        for (int jc = 0; jc < 4; ++jc) {
            int jg = cg * 4 + jc;
            int j0 = jg * 16 + kg * 4;
            f32x4 sh = *(const f32x4*)(shift0 + j0);
            s16x4 th;
#pragma unroll
            for (int r = 0; r < 4; ++r)
                th[r] = (short)f2bf(fmaxf(acc[qq][jc][r] + sh[r], 0.f));
            int G = jg * 2 + (kg >> 1);
            int idx = qrow * 256 + ((G ^ (qrow & 7)) * 8) + (kg & 1) * 4;
            *(s16x4*)&l1b[idx] = th;
        }
    }
    __syncthreads();   // h1 visible; all strip reads of layer 1 complete

    // ---- layer 2: 16 strips (8 kb x {hi,lo}), 2-term ----
    f32x4 acc2[2][4];
#pragma unroll
    for (int qq = 0; qq < 2; ++qq)
#pragma unroll
        for (int jc = 0; jc < 4; ++jc) acc2[qq][jc] = 0.f;
    STG(W1p, 0, 0); STG(W1p, 1, 1);
    bf16x8 bh2[2];
#pragma unroll
    for (int s = 0; s < 16; ++s) {
        if (s < 15) { VMCNT2; } else { VMCNT0; }
        SBAR;
        if (s + 2 < 16) STG(W1p, s + 2, (s + 2) % 3);
        const unsigned short* strip = (const unsigned short*)(smem + (s % 3) * 16384);
        const int kb = s >> 1;
        if ((s & 1) == 0) {
#pragma unroll
            for (int qq = 0; qq < 2; ++qq) {
                int qrow = qs * 32 + qq * 16 + l16;
                int gidx = qrow * 256 + (((kb * 4 + kg) ^ (qrow & 7)) * 8);
                bh2[qq] = *(const bf16x8*)&l1b[gidx];
            }
        }
        __builtin_amdgcn_s_setprio(1);
#pragma unroll
        for (int jc = 0; jc < 4; ++jc) {
            int col = cg * 64 + jc * 16 + l16;
            bf16x8 a = *(const bf16x8*)&strip[kg * 2048 + col * 8];
            acc2[0][jc] = __builtin_amdgcn_mfma_f32_16x16x32_bf16(a, bh2[0], acc2[0][jc], 0, 0, 0);
            acc2[1][jc] = __builtin_amdgcn_mfma_f32_16x16x32_bf16(a, bh2[1], acc2[1][jc], 0, 0, 0);
        }
        __builtin_amdgcn_s_setprio(0);
    }

    // ---- layer 3: BN-shift + relu + 256->2 partials ----
    float p[2][2] = {};
#pragma unroll
    for (int qq = 0; qq < 2; ++qq)
#pragma unroll
        for (int jc = 0; jc < 4; ++jc) {
            int j0 = (cg * 4 + jc) * 16 + kg * 4;
            f32x4 sh = *(const f32x4*)(shift1 + j0);
            f32x4 wa = *(const f32x4*)(w2 + j0);
            f32x4 wb = *(const f32x4*)(w2 + H_DIM + j0);
#pragma unroll
            for (int r = 0; r < 4; ++r) {
                float v = fmaxf(acc2[qq][jc][r] + sh[r], 0.f);
                p[qq][0] += v * wa[r];
                p[qq][1] += v * wb[r];
            }
        }
#pragma unroll
    for (int qq = 0; qq < 2; ++qq) {
        p[qq][0] += __shfl_xor(p[qq][0], 16, 64); p[qq][0] += __shfl_xor(p[qq][0], 32, 64);
        p[qq][1] += __shfl_xor(p[qq][1], 16, 64); p[qq][1] += __shfl_xor(p[qq][1], 32, 64);
    }
    __syncthreads();   // strip region reusable as red
    if (kg == 0) {
#pragma unroll
        for (int qq = 0; qq < 2; ++qq) {
            int base = ((qs * 2 + qq) * 16 + l16) * 2;
            red[(base + 0) * 4 + cg] = p[qq][0];
            red[(base + 1) * 4 + cg] = p[qq][1];
        }
    }
    __syncthreads();
    if (t < 64) {
        int q = qb + t;
        if (q < Q_PAIRS) {
            int base = t * 2;
            float l0 = red[base * 4 + 0] + red[base * 4 + 1] + red[base * 4 + 2] + red[base * 4 + 3] + b2[0];
            float l1v = red[(base + 1) * 4 + 0] + red[(base + 1) * 4 + 1]
                      + red[(base + 1) * 4 + 2] + red[(base + 1) * 4 + 3] + b2[1];
            float mx = fmaxf(l0, l1v);
            float lse = mx + logf(expf(l0 - mx) + expf(l1v - mx));
            float2 o; o.x = l0 - lse; o.y = l1v - lse;
            *(float2*)(out + (size_t)qidx[q] * N_CLS) = o;
        }
    }
}

// ---------------- launch ----------------
extern "C" void kernel_launch(void* const* d_in, const int* in_sizes, int n_in,
                              void* d_out, int out_size, void* d_ws, size_t ws_size,
                              hipStream_t stream) {
    const float* X  = (const float*)d_in[0];
    const int*   ei = (const int*)d_in[1];
    const float* ew = (const float*)d_in[2];
    const int*   e1 = (const int*)d_in[3];
    const int*   e2 = (const int*)d_in[4];
    const float* w_init[2] = {(const float*)d_in[5],  (const float*)d_in[10]};
    const float* w_ih[2]   = {(const float*)d_in[6],  (const float*)d_in[11]};
    const float* w_hh[2]   = {(const float*)d_in[7],  (const float*)d_in[12]};
    const float* b_ih[2]   = {(const float*)d_in[8],  (const float*)d_in[13]};
    const float* b_hh[2]   = {(const float*)d_in[9],  (const float*)d_in[14]};
    const float* lw0 = (const float*)d_in[15]; const float* lb0 = (const float*)d_in[16];
    const float* lw1 = (const float*)d_in[17]; const float* lb1 = (const float*)d_in[18];
    const float* lw2 = (const float*)d_in[19]; const float* lb2 = (const float*)d_in[20];
    const float* bg0 = (const float*)d_in[21]; const float* bb0 = (const float*)d_in[22];
    const float* bm0 = (const float*)d_in[23]; const float* bv0 = (const float*)d_in[24];
    const float* bg1 = (const float*)d_in[25]; const float* bb1 = (const float*)d_in[26];
    const float* bm1 = (const float*)d_in[27]; const float* bv1 = (const float*)d_in[28];
    const int* src = ei;
    const int* dst = ei + E_EDGES;

    char* ws = (char*)d_ws;
    size_t o = 0;
    auto alloc = [&](size_t bytes) { char* p = ws + o; o += (bytes + 63) & ~(size_t)63; return p; };
    float* bufA   = (float*)alloc((size_t)N_NODES * C_DIM * 4);   // agg (f32)
    float* bufB   = (float*)alloc((size_t)N_NODES * C_DIM * 4);   // y2 (f32)
    unsigned short* xbf = (unsigned short*)alloc((size_t)N_NODES * C_DIM * 2);  // X bf16
    unsigned short* ybf = (unsigned short*)alloc((size_t)N_NODES * C_DIM * 2);  // y1 bf16
    float* dinv   = (float*)alloc(N_NODES * 4);
    float* we0    = (float*)alloc(C_DIM * C_DIM * 4);
    float* we1    = (float*)alloc(C_DIM * C_DIM * 4);
    float* shift0 = (float*)alloc(H_DIM * 4);
    float* shift1 = (float*)alloc(H_DIM * 4);
    int*   cnt    = (int*)alloc(N_NODES * 4);
    int*   pos    = (int*)alloc(N_NODES * 4);
    int*   off    = (int*)alloc((N_NODES + 1) * 4);
    int*   bsum   = (int*)alloc(64 * 4);
    int*   boff   = (int*)alloc(64 * 4);
    int*   qcnt   = (int*)alloc(N_NODES * 4);
    int*   qpos   = (int*)alloc(N_NODES * 4);
    int*   qoff   = (int*)alloc((N_NODES + 1) * 4);
    int*   qbsum  = (int*)alloc(64 * 4);
    int*   qboff  = (int*)alloc(64 * 4);
    int2*  csr    = (int2*)alloc((size_t)E_EDGES * 8);
    int2*  qpair  = (int2*)alloc((size_t)Q_PAIRS * 8);
    int*   qidx   = (int*)alloc((size_t)Q_PAIRS * 4);
    unsigned short* W0p = (unsigned short*)alloc(65536 * 2);    // 128KB
    unsigned short* W1p = (unsigned short*)alloc(131072 * 2);   // 256KB
    unsigned short* Wc0 = (unsigned short*)alloc(32768 * 2);    // 64KB
    unsigned short* Wc1 = (unsigned short*)alloc(32768 * 2);    // 64KB
    if (o > ws_size) return;

    dim3 b256(256);
    const int gN = (N_NODES + 255) / 256;
    const int gE = (E_EDGES + 255) / 256;
    const int gQ = (Q_PAIRS + 255) / 256;

    // degrees + CSR + query sort histograms
    k_init<<<gN, b256, 0, stream>>>(dinv, cnt, qcnt);
    k_deg_hist<<<gE, b256, 0, stream>>>(dst, ew, dinv, cnt);
    k_qhist<<<gQ, b256, 0, stream>>>(e1, qcnt);
    k_deg_fin<<<gN, b256, 0, stream>>>(dinv);
    k_scan1<<<49, dim3(1024), 0, stream>>>(cnt, pos, bsum);
    k_scan2<<<1, dim3(64), 0, stream>>>(bsum, boff);
    k_scan3<<<49, dim3(1024), 0, stream>>>(cnt, pos, boff, off);
    k_fill<<<gE, b256, 0, stream>>>(src, dst, ew, dinv, pos, csr);
    k_scan1<<<49, dim3(1024), 0, stream>>>(qcnt, qpos, qbsum);
    k_scan2<<<1, dim3(64), 0, stream>>>(qbsum, qboff);
    k_scan3<<<49, dim3(1024), 0, stream>>>(qcnt, qpos, qboff, qoff);
    k_qfill<<<gQ, b256, 0, stream>>>(e1, e2, qpos, qpair, qidx);

    // GRU (both layers) + weight preps + X->bf16
    k_gru2<<<256, dim3(128), 0, stream>>>(w_init[0], w_ih[0], w_hh[0], b_ih[0], b_hh[0], we0,
                                          w_init[1], w_ih[1], w_hh[1], b_ih[1], b_hh[1], we1);
    k_prep_conv<<<256, b256, 0, stream>>>(we0, we1, Wc0, Wc1);
    k_prep_w<<<256, b256, 0, stream>>>(lw0, bg0, bv0, C_DIM, 65536, W0p);
    k_prep_w<<<512, b256, 0, stream>>>(lw1, bg1, bv1, H_DIM, 131072, W1p);
    k_prep_shift<<<1, dim3(512), 0, stream>>>(lb0, bg0, bb0, bm0, bv0, lb1, bg1, bb1, bm1, bv1, shift0, shift1);
    k_xbf<<<(N_NODES * C_DIM) / 2048, b256, 0, stream>>>(X, xbf);

    const int ga = (N_NODES * 32) / 256;          // 6250
    const int gg = (N_NODES + 63) / 64;           // 782
    // layer 0: aggregate (bf16 in) -> GEMM (bf16 out)
    k_agg<<<ga, b256, 0, stream>>>(xbf, dinv, off, csr, bufA);
    k_gemm<1><<<gg, dim3(512), 0, stream>>>(bufA, Wc0, bufB, ybf);
    // layer 1: aggregate (bf16 in) -> GEMM (f32 out for MLP)
    k_agg<<<ga, b256, 0, stream>>>(ybf, dinv, off, csr, bufA);
    k_gemm<0><<<gg, dim3(512), 0, stream>>>(bufA, Wc1, bufB, ybf);
    // fused MFMA MLP over e1-sorted queries
    k_mlp<<<(Q_PAIRS + 63) / 64, dim3(512), 0, stream>>>(bufB, qpair, qidx, W0p, W1p,
                                                         shift0, shift1, lw2, lb2, (float*)d_out);
}

// Round 10
// 651.520 us; speedup vs baseline: 12.9027x; 1.0916x over previous
//
#include <hip/hip_runtime.h>
#include <math.h>

#define N_NODES 50000
#define C_DIM   128
#define E_EDGES 1600000
#define Q_PAIRS 500000
#define H_DIM   256
#define N_CLS   2
#define BN_EPS  1e-5f

typedef __attribute__((ext_vector_type(8))) short bf16x8;
typedef __attribute__((ext_vector_type(4))) short s16x4;
typedef __attribute__((ext_vector_type(4))) unsigned short u16x4;
typedef __attribute__((ext_vector_type(4))) float f32x4;

#define VMCNT0 asm volatile("s_waitcnt vmcnt(0)" ::: "memory")
#define VMCNT1 asm volatile("s_waitcnt vmcnt(1)" ::: "memory")
#define SBAR do { __builtin_amdgcn_s_barrier(); \
                  __builtin_amdgcn_sched_barrier(0); } while (0)

#define DEG_SCALE 2097152.0f   // 2^21 fixed point for packed degree

__device__ __forceinline__ unsigned short f2bf(float x) {   // RNE f32->bf16 bits
    unsigned u = __float_as_uint(x);
    u += 0x7fffu + ((u >> 16) & 1u);
    return (unsigned short)(u >> 16);
}
__device__ __forceinline__ float bf2f(unsigned short h) {
    return __uint_as_float(((unsigned)h) << 16);
}

// ---------------- init + packed degree/hist ----------------
__global__ __launch_bounds__(256) void k_init(unsigned long long* dpack, int* qcnt) {
    int i = blockIdx.x * 256 + threadIdx.x;
    if (i < N_NODES) { dpack[i] = 0ULL; qcnt[i] = 0; }
}
// one u64 atomic per edge: hi32 = count, lo32 = ew in 2^21 fixed point
__global__ __launch_bounds__(256) void k_deg_hist(const int* __restrict__ dst,
                                                  const float* __restrict__ ew,
                                                  unsigned long long* dpack) {
    int e = blockIdx.x * 256 + threadIdx.x;
    if (e < E_EDGES) {
        unsigned pv = __float2uint_rn(ew[e] * DEG_SCALE);
        atomicAdd(&dpack[dst[e]], (1ULL << 32) | (unsigned long long)pv);
    }
}
__global__ __launch_bounds__(256) void k_qhist(const int* __restrict__ e1, int* qcnt) {
    int q = blockIdx.x * 256 + threadIdx.x;
    if (q < Q_PAIRS) atomicAdd(&qcnt[e1[q]], 1);
}

// ---------------- multi-block scan (3 kernels; cnt read with runtime stride) ----------------
__global__ __launch_bounds__(1024) void k_scan1(const int* __restrict__ cnt, int stride,
                                                int* __restrict__ locincl,
                                                int* __restrict__ bsum) {
    __shared__ int pa[1024], pb[1024];
    int t = threadIdx.x;
    int x = blockIdx.x * 1024 + t;
    int v = (x < N_NODES) ? cnt[(size_t)x * stride] : 0;
    pa[t] = v;
    __syncthreads();
    int* sp = pa; int* dp = pb;
    for (int o = 1; o < 1024; o <<= 1) {
        int u = sp[t] + ((t >= o) ? sp[t - o] : 0);
        dp[t] = u;
        __syncthreads();
        int* tmp = sp; sp = dp; dp = tmp;
    }
    if (x < N_NODES) locincl[x] = sp[t];
    if (t == 1023) bsum[blockIdx.x] = sp[1023];
}
__global__ __launch_bounds__(64) void k_scan2(const int* __restrict__ bsum,
                                              int* __restrict__ boff) {
    int t = threadIdx.x;
    int v = (t < 49) ? bsum[t] : 0;
    int own = v;
    for (int o = 1; o < 64; o <<= 1) {
        int u = __shfl_up(v, o, 64);
        if (t >= o) v += u;
    }
    if (t < 49) boff[t] = v - own;   // exclusive
}
// also finalizes dinv from packed degree when dpack != nullptr
__global__ __launch_bounds__(1024) void k_scan3(const int* __restrict__ cnt, int stride,
                                                int* __restrict__ pos,
                                                const int* __restrict__ boff,
                                                int* __restrict__ off,
                                                const unsigned long long* __restrict__ dpack,
                                                float* __restrict__ dinv) {
    int x = blockIdx.x * 1024 + threadIdx.x;
    if (x >= N_NODES) return;
    int incl = pos[x];
    int c = cnt[(size_t)x * stride];
    int o = boff[blockIdx.x] + incl - c;
    off[x] = o;
    pos[x] = o;
    if (x == N_NODES - 1) off[N_NODES] = o + c;
    if (dpack) {
        unsigned lo = (unsigned)(dpack[x] & 0xffffffffULL);
        dinv[x] = rsqrtf(1.0f + (float)lo * (1.0f / DEG_SCALE));
    }
}

// packed CSR entry: .x = src node, .y = float weight bits
__global__ __launch_bounds__(256) void k_fill(const int* __restrict__ src,
                                              const int* __restrict__ dst,
                                              const float* __restrict__ ew,
                                              const float* __restrict__ dinv,
                                              int* pos,
                                              int2* __restrict__ csr) {
    int e = blockIdx.x * 256 + threadIdx.x;
    if (e >= E_EDGES) return;
    int s = src[e], d = dst[e];
    int slot = atomicAdd(&pos[d], 1);
    int2 p;
    p.x = s;
    p.y = __float_as_int(dinv[s] * ew[e] * dinv[d]);
    csr[slot] = p;
}
// query sort fill: qpair[slot] = (e1,e2), qidx[slot] = original q
__global__ __launch_bounds__(256) void k_qfill(const int* __restrict__ e1,
                                               const int* __restrict__ e2,
                                               int* qpos,
                                               int2* __restrict__ qpair,
                                               int* __restrict__ qidx) {
    int q = blockIdx.x * 256 + threadIdx.x;
    if (q >= Q_PAIRS) return;
    int a = e1[q];
    int slot = atomicAdd(&qpos[a], 1);
    int2 p; p.x = a; p.y = e2[q];
    qpair[slot] = p;
    qidx[slot] = q;
}

// ---------------- GRU weight evolution (both layers in one launch) ----------------
__global__ __launch_bounds__(128) void k_gru2(
    const float* __restrict__ wi0, const float* __restrict__ wih0, const float* __restrict__ whh0,
    const float* __restrict__ bih0, const float* __restrict__ bhh0, float* __restrict__ we0,
    const float* __restrict__ wi1, const float* __restrict__ wih1, const float* __restrict__ whh1,
    const float* __restrict__ bih1, const float* __restrict__ bhh1, float* __restrict__ we1) {
    __shared__ float xrow[C_DIM];
    int layer = blockIdx.x >> 7;
    int i = blockIdx.x & 127, j = threadIdx.x;
    const float* w_init = layer ? wi1 : wi0;
    const float* wih = layer ? wih1 : wih0;
    const float* whh = layer ? whh1 : whh0;
    const float* bih = layer ? bih1 : bih0;
    const float* bhh = layer ? bhh1 : bhh0;
    float* w_out = layer ? we1 : we0;
    xrow[j] = w_init[i * C_DIM + j];
    __syncthreads();
    float gi[3], gh[3];
#pragma unroll
    for (int g = 0; g < 3; ++g) {
        const float* wi = wih + (size_t)(g * C_DIM + j) * C_DIM;
        const float* wh = whh + (size_t)(g * C_DIM + j) * C_DIM;
        float ai = 0.f, ah = 0.f;
        for (int k = 0; k < C_DIM; ++k) { ai += xrow[k] * wi[k]; ah += xrow[k] * wh[k]; }
        gi[g] = ai + bih[g * C_DIM + j];
        gh[g] = ah + bhh[g * C_DIM + j];
    }
    float r = 1.f / (1.f + expf(-(gi[0] + gh[0])));
    float z = 1.f / (1.f + expf(-(gi[1] + gh[1])));
    float n = tanhf(gi[2] + r * gh[2]);
    w_out[i * C_DIM + j] = (1.f - z) * n + z * xrow[j];
}

// ---------------- X -> bf16 ----------------
__global__ __launch_bounds__(256) void k_xbf(const float* __restrict__ x,
                                             unsigned short* __restrict__ xb) {
    int i = (blockIdx.x * 256 + threadIdx.x) * 8;
    f32x4 a = *(const f32x4*)(x + i);
    f32x4 b = *(const f32x4*)(x + i + 4);
    bf16x8 o;
#pragma unroll
    for (int e = 0; e < 4; ++e) { o[e] = (short)f2bf(a[e]); o[e + 4] = (short)f2bf(b[e]); }
    *(bf16x8*)(xb + i) = o;
}

// ---------------- CSR aggregation from bf16 rows ----------------
__global__ __launch_bounds__(256) void k_agg(const unsigned short* __restrict__ xb,
                                             const float* __restrict__ dinv,
                                             const int* __restrict__ off,
                                             const int2* __restrict__ csr,
                                             float* __restrict__ agg) {
    int tid = blockIdx.x * 256 + threadIdx.x;
    int n = tid >> 5;
    int c = (tid & 31) << 2;
    float dv = dinv[n];
    float d2 = dv * dv;
    u16x4 xs = *(const u16x4*)(xb + (size_t)n * C_DIM + c);
    float4 acc;
    acc.x = d2 * bf2f(xs[0]); acc.y = d2 * bf2f(xs[1]);
    acc.z = d2 * bf2f(xs[2]); acc.w = d2 * bf2f(xs[3]);
    int i = off[n], e = off[n + 1];
    for (; i + 8 <= e; i += 8) {
        int2 q0 = csr[i], q1 = csr[i + 1], q2 = csr[i + 2], q3 = csr[i + 3];
        int2 q4 = csr[i + 4], q5 = csr[i + 5], q6 = csr[i + 6], q7 = csr[i + 7];
        u16x4 v0 = *(const u16x4*)(xb + (size_t)q0.x * C_DIM + c);
        u16x4 v1 = *(const u16x4*)(xb + (size_t)q1.x * C_DIM + c);
        u16x4 v2 = *(const u16x4*)(xb + (size_t)q2.x * C_DIM + c);
        u16x4 v3 = *(const u16x4*)(xb + (size_t)q3.x * C_DIM + c);
        u16x4 v4 = *(const u16x4*)(xb + (size_t)q4.x * C_DIM + c);
        u16x4 v5 = *(const u16x4*)(xb + (size_t)q5.x * C_DIM + c);
        u16x4 v6 = *(const u16x4*)(xb + (size_t)q6.x * C_DIM + c);
        u16x4 v7 = *(const u16x4*)(xb + (size_t)q7.x * C_DIM + c);
        float w0 = __int_as_float(q0.y), w1 = __int_as_float(q1.y);
        float w2 = __int_as_float(q2.y), w3 = __int_as_float(q3.y);
        float w4 = __int_as_float(q4.y), w5 = __int_as_float(q5.y);
        float w6 = __int_as_float(q6.y), w7 = __int_as_float(q7.y);
        acc.x += w0 * bf2f(v0[0]) + w1 * bf2f(v1[0]) + w2 * bf2f(v2[0]) + w3 * bf2f(v3[0])
               + w4 * bf2f(v4[0]) + w5 * bf2f(v5[0]) + w6 * bf2f(v6[0]) + w7 * bf2f(v7[0]);
        acc.y += w0 * bf2f(v0[1]) + w1 * bf2f(v1[1]) + w2 * bf2f(v2[1]) + w3 * bf2f(v3[1])
               + w4 * bf2f(v4[1]) + w5 * bf2f(v5[1]) + w6 * bf2f(v6[1]) + w7 * bf2f(v7[1]);
        acc.z += w0 * bf2f(v0[2]) + w1 * bf2f(v1[2]) + w2 * bf2f(v2[2]) + w3 * bf2f(v3[2])
               + w4 * bf2f(v4[2]) + w5 * bf2f(v5[2]) + w6 * bf2f(v6[2]) + w7 * bf2f(v7[2]);
        acc.w += w0 * bf2f(v0[3]) + w1 * bf2f(v1[3]) + w2 * bf2f(v2[3]) + w3 * bf2f(v3[3])
               + w4 * bf2f(v4[3]) + w5 * bf2f(v5[3]) + w6 * bf2f(v6[3]) + w7 * bf2f(v7[3]);
    }
    for (; i < e; ++i) {
        int2 pe = csr[i];
        float w = __int_as_float(pe.y);
        u16x4 v = *(const u16x4*)(xb + (size_t)pe.x * C_DIM + c);
        acc.x += w * bf2f(v[0]); acc.y += w * bf2f(v[1]);
        acc.z += w * bf2f(v[2]); acc.w += w * bf2f(v[3]);
    }
    *(float4*)(agg + (size_t)n * C_DIM + c) = acc;
}

// ---------------- weight prep ----------------
// MLP weights: [kb][plane][kg(4)][col(256)][e(8)]
__global__ __launch_bounds__(256) void k_prep_w(const float* __restrict__ w,
                                                const float* __restrict__ g,
                                                const float* __restrict__ v,
                                                int kdim, int total,
                                                unsigned short* __restrict__ outp) {
    int idx = blockIdx.x * 256 + threadIdx.x;
    if (idx >= total) return;
    int e = idx & 7, col = (idx >> 3) & 255, kg = (idx >> 11) & 3;
    int plane = (idx >> 13) & 1, kb = idx >> 14;
    int k = kb * 32 + kg * 8 + e;
    float sc = g[col] * rsqrtf(v[col] + BN_EPS);
    float x = w[(size_t)col * kdim + k] * sc;
    unsigned short hi = f2bf(x);
    outp[idx] = plane ? f2bf(x - bf2f(hi)) : hi;
}
// conv weights (both layers): [layer][kb(4)][plane][kg(4)][col(128)][e(8)]
__global__ __launch_bounds__(256) void k_prep_conv(const float* __restrict__ we0,
                                                   const float* __restrict__ we1,
                                                   unsigned short* __restrict__ Wc0,
                                                   unsigned short* __restrict__ Wc1) {
    int idx = blockIdx.x * 256 + threadIdx.x;   // 65536 total
    int e = idx & 7, col = (idx >> 3) & 127, kg = (idx >> 10) & 3;
    int plane = (idx >> 12) & 1, kb = (idx >> 13) & 3, layer = idx >> 15;
    int k = kb * 32 + kg * 8 + e;
    const float* we = layer ? we1 : we0;
    float x = we[(size_t)k * C_DIM + col];
    unsigned short hi = f2bf(x);
    unsigned short o = plane ? f2bf(x - bf2f(hi)) : hi;
    (layer ? Wc1 : Wc0)[idx & 32767] = o;
}

__global__ __launch_bounds__(512) void k_prep_shift(
    const float* __restrict__ lb0, const float* __restrict__ bg0, const float* __restrict__ bb0,
    const float* __restrict__ bm0, const float* __restrict__ bv0,
    const float* __restrict__ lb1, const float* __restrict__ bg1, const float* __restrict__ bb1,
    const float* __restrict__ bm1, const float* __restrict__ bv1,
    float* __restrict__ shift0, float* __restrict__ shift1) {
    int j = threadIdx.x;
    if (j < 256) {
        float sc = bg0[j] * rsqrtf(bv0[j] + BN_EPS);
        shift0[j] = (lb0[j] - bm0[j]) * sc + bb0[j];
    } else {
        int i = j - 256;
        float sc = bg1[i] * rsqrtf(bv1[i] + BN_EPS);
        shift1[i] = (lb1[i] - bm1[i]) * sc + bb1[i];
    }
}

// ---------------- conv GEMM: y = relu(agg @ W); OUT_BF: write bf16 rows ----------------
template <int OUT_BF>
__global__ __launch_bounds__(512) void k_gemm(const float* __restrict__ agg,
                                              const unsigned short* __restrict__ Wc,
                                              float* __restrict__ y,
                                              unsigned short* __restrict__ yb) {
    __shared__ __align__(16) char smem[3 * 8192];
    const int t = threadIdx.x, lane = t & 63, wave = t >> 6;
    const int qg = wave >> 1, ch = wave & 1;
    const int l16 = lane & 15, kg = lane >> 4;
    const int qrow = qg * 16 + l16;
    const int node = blockIdx.x * 64 + qrow;
    const int nodec = node < N_NODES ? node : N_NODES - 1;

    auto STG = [&](int sidx, int b) {
        const char* g = (const char*)Wc + sidx * 8192 + wave * 1024 + lane * 16;
        char* d = smem + b * 8192 + wave * 1024;
        __builtin_amdgcn_global_load_lds((const __attribute__((address_space(1))) void*)g,
                                         (__attribute__((address_space(3))) void*)d, 16, 0, 0);
    };
    STG(0, 0); STG(1, 1);

    bf16x8 bh[4], bl[4];
    const float* ar = agg + (size_t)nodec * C_DIM;
#pragma unroll
    for (int kb = 0; kb < 4; ++kb) {
        int k0 = kb * 32 + kg * 8;
        f32x4 a0 = *(const f32x4*)(ar + k0);
        f32x4 a1 = *(const f32x4*)(ar + k0 + 4);
#pragma unroll
        for (int e = 0; e < 4; ++e) {
            unsigned short h0 = f2bf(a0[e]);
            bh[kb][e] = (short)h0; bl[kb][e] = (short)f2bf(a0[e] - bf2f(h0));
            unsigned short h1 = f2bf(a1[e]);
            bh[kb][e + 4] = (short)h1; bl[kb][e + 4] = (short)f2bf(a1[e] - bf2f(h1));
        }
    }
    f32x4 acc[4];
#pragma unroll
    for (int i = 0; i < 4; ++i) acc[i] = 0.f;

#pragma unroll
    for (int s = 0; s < 8; ++s) {
        if (s < 7) { VMCNT1; } else { VMCNT0; }
        SBAR;
        if (s + 2 < 8) STG(s + 2, (s + 2) % 3);
        const unsigned short* strip = (const unsigned short*)(smem + (s % 3) * 8192);
        const int kb = s >> 1;
        __builtin_amdgcn_s_setprio(1);
#pragma unroll
        for (int jc8 = 0; jc8 < 4; ++jc8) {
            int col = (ch * 4 + jc8) * 16 + l16;
            bf16x8 a = *(const bf16x8*)&strip[kg * 1024 + col * 8];
            acc[jc8] = __builtin_amdgcn_mfma_f32_16x16x32_bf16(a, bh[kb], acc[jc8], 0, 0, 0);
            if ((s & 1) == 0)
                acc[jc8] = __builtin_amdgcn_mfma_f32_16x16x32_bf16(a, bl[kb], acc[jc8], 0, 0, 0);
        }
        __builtin_amdgcn_s_setprio(0);
    }

    if (node < N_NODES) {
#pragma unroll
        for (int jc8 = 0; jc8 < 4; ++jc8) {
            int j0 = (ch * 4 + jc8) * 16 + kg * 4;
            if (OUT_BF) {
                u16x4 v;
#pragma unroll
                for (int r = 0; r < 4; ++r) v[r] = f2bf(fmaxf(acc[jc8][r], 0.f));
                *(u16x4*)(yb + (size_t)node * C_DIM + j0) = v;
            } else {
                float4 v;
                v.x = fmaxf(acc[jc8][0], 0.f); v.y = fmaxf(acc[jc8][1], 0.f);
                v.z = fmaxf(acc[jc8][2], 0.f); v.w = fmaxf(acc[jc8][3], 0.f);
                *(float4*)(y + (size_t)node * C_DIM + j0) = v;
            }
        }
    }
}

// ---------------- fused query MLP (2-term bf16 MFMA, 128 q/block, 16 waves) ----------------
// wave = qs*4+cg, qs in 0..3 (32-q group), cg in 0..3 (64-col quarter).
// LDS 112KB -> 1 block/CU, 16 waves: [0,48K) 3x16KB strips; [48K,112K) l1b 128x256.
__global__ __launch_bounds__(1024, 4) void k_mlp(const float* __restrict__ y,
                                             const int2* __restrict__ qpair,
                                             const int* __restrict__ qidx,
                                             const unsigned short* __restrict__ W0p,
                                             const unsigned short* __restrict__ W1p,
                                             const float* __restrict__ shift0,
                                             const float* __restrict__ shift1,
                                             const float* __restrict__ w2,
                                             const float* __restrict__ b2,
                                             float* __restrict__ out) {
    __shared__ __align__(16) char smem[114688];
    unsigned short* l1b = (unsigned short*)(smem + 49152);   // 128 x 256 shorts
    float* red = (float*)smem;                               // 4KB, epilogue only

    const int t = threadIdx.x;
    const int lane = t & 63;
    const int wave = t >> 6;                 // 0..15
    const int qs = wave >> 2, cg = wave & 3;
    const int l16 = lane & 15, kg = lane >> 4;
    const int qb = blockIdx.x * 128;

    auto STG = [&](const unsigned short* W, int sidx, int b) {
        const char* g = (const char*)W + ((size_t)sidx << 14) + wave * 1024 + lane * 16;
        char* d = smem + b * 16384 + wave * 1024;
        __builtin_amdgcn_global_load_lds((const __attribute__((address_space(1))) void*)g,
                                         (__attribute__((address_space(3))) void*)d, 16, 0, 0);
    };

    STG(W0p, 0, 0); STG(W0p, 1, 1);   // overlap with phase 0

    // ---- phase 0: cooperative h staging (16 waves x 8 rows = 128 rows, once each) ----
    {
        int k2 = lane * 2;
        int G = lane >> 2;            // k-granule 0..15
        int off = k2 & 7;
#pragma unroll
        for (int qi = 0; qi < 8; ++qi) {
            int qrow = wave * 8 + qi;
            int q = qb + qrow; if (q >= Q_PAIRS) q = Q_PAIRS - 1;
            int2 pr = qpair[q];
            const float* ya = y + (size_t)pr.x * C_DIM;
            const float* yb = y + (size_t)pr.y * C_DIM;
            float2 a = *(const float2*)(ya + k2);
            float2 b = *(const float2*)(yb + k2);
            int idx = qrow * 256 + ((G ^ (qrow & 7)) << 3) + off;
            l1b[idx] = f2bf(a.x * b.x);
            l1b[idx + 1] = f2bf(a.y * b.y);
        }
    }
    __syncthreads();   // h visible

    // ---- pickup h fragments into regs ----
    bf16x8 bh[2][4];
#pragma unroll
    for (int qq = 0; qq < 2; ++qq) {
        int qrow = qs * 32 + qq * 16 + l16;
#pragma unroll
        for (int kb = 0; kb < 4; ++kb) {
            int gidx = qrow * 256 + (((kb * 4 + kg) ^ (qrow & 7)) * 8);
            bh[qq][kb] = *(const bf16x8*)&l1b[gidx];
        }
    }

    f32x4 acc[2][4];
#pragma unroll
    for (int qq = 0; qq < 2; ++qq)
#pragma unroll
        for (int jc = 0; jc < 4; ++jc) acc[qq][jc] = 0.f;

    // ---- layer 1: 8 strips (4 kb x {hi,lo}), 2-term, depth-2 pipeline ----
#pragma unroll
    for (int s = 0; s < 8; ++s) {
        if (s < 7) { VMCNT1; } else { VMCNT0; }
        SBAR;
        if (s + 2 < 8) STG(W0p, s + 2, (s + 2) % 3);
        const unsigned short* strip = (const unsigned short*)(smem + (s % 3) * 16384);
        const int kb = s >> 1;
        __builtin_amdgcn_s_setprio(1);
#pragma unroll
        for (int jc = 0; jc < 4; ++jc) {
            int col = cg * 64 + jc * 16 + l16;
            bf16x8 a = *(const bf16x8*)&strip[kg * 2048 + col * 8];
            acc[0][jc] = __builtin_amdgcn_mfma_f32_16x16x32_bf16(a, bh[0][kb], acc[0][jc], 0, 0, 0);
            acc[1][jc] = __builtin_amdgcn_mfma_f32_16x16x32_bf16(a, bh[1][kb], acc[1][jc], 0, 0, 0);
        }
        __builtin_amdgcn_s_setprio(0);
    }

    // ---- epilogue 1: BN-shift + relu -> l1b (bf16 hi only) ----
#pragma unroll
    for (int qq = 0; qq < 2; ++qq) {
        int qrow = qs * 32 + qq * 16 + l16;
#pragma unroll
        for (int jc = 0; jc < 4; ++jc) {
            int jg = cg * 4 + jc;
            int j0 = jg * 16 + kg * 4;
            f32x4 sh = *(const f32x4*)(shift0 + j0);
            s16x4 th;
#pragma unroll
            for (int r = 0; r < 4; ++r)
                th[r] = (short)f2bf(fmaxf(acc[qq][jc][r] + sh[r], 0.f));
            int G = jg * 2 + (kg >> 1);
            int idx = qrow * 256 + ((G ^ (qrow & 7)) * 8) + (kg & 1) * 4;
            *(s16x4*)&l1b[idx] = th;
        }
    }
    __syncthreads();   // h1 visible; all strip reads of layer 1 complete

    // ---- layer 2: 16 strips (8 kb x {hi,lo}), 2-term ----
    f32x4 acc2[2][4];
#pragma unroll
    for (int qq = 0; qq < 2; ++qq)
#pragma unroll
        for (int jc = 0; jc < 4; ++jc) acc2[qq][jc] = 0.f;
    STG(W1p, 0, 0); STG(W1p, 1, 1);
    bf16x8 bh2[2];
#pragma unroll
    for (int s = 0; s < 16; ++s) {
        if (s < 15) { VMCNT1; } else { VMCNT0; }
        SBAR;
        if (s + 2 < 16) STG(W1p, s + 2, (s + 2) % 3);
        const unsigned short* strip = (const unsigned short*)(smem + (s % 3) * 16384);
        const int kb = s >> 1;
        if ((s & 1) == 0) {
#pragma unroll
            for (int qq = 0; qq < 2; ++qq) {
                int qrow = qs * 32 + qq * 16 + l16;
                int gidx = qrow * 256 + (((kb * 4 + kg) ^ (qrow & 7)) * 8);
                bh2[qq] = *(const bf16x8*)&l1b[gidx];
            }
        }
        __builtin_amdgcn_s_setprio(1);
#pragma unroll
        for (int jc = 0; jc < 4; ++jc) {
            int col = cg * 64 + jc * 16 + l16;
            bf16x8 a = *(const bf16x8*)&strip[kg * 2048 + col * 8];
            acc2[0][jc] = __builtin_amdgcn_mfma_f32_16x16x32_bf16(a, bh2[0], acc2[0][jc], 0, 0, 0);
            acc2[1][jc] = __builtin_amdgcn_mfma_f32_16x16x32_bf16(a, bh2[1], acc2[1][jc], 0, 0, 0);
        }
        __builtin_amdgcn_s_setprio(0);
    }

    // ---- layer 3: BN-shift + relu + 256->2 partials ----
    float p[2][2] = {};
#pragma unroll
    for (int qq = 0; qq < 2; ++qq)
#pragma unroll
        for (int jc = 0; jc < 4; ++jc) {
            int j0 = (cg * 4 + jc) * 16 + kg * 4;
            f32x4 sh = *(const f32x4*)(shift1 + j0);
            f32x4 wa = *(const f32x4*)(w2 + j0);
            f32x4 wb = *(const f32x4*)(w2 + H_DIM + j0);
#pragma unroll
            for (int r = 0; r < 4; ++r) {
                float v = fmaxf(acc2[qq][jc][r] + sh[r], 0.f);
                p[qq][0] += v * wa[r];
                p[qq][1] += v * wb[r];
            }
        }
#pragma unroll
    for (int qq = 0; qq < 2; ++qq) {
        p[qq][0] += __shfl_xor(p[qq][0], 16, 64); p[qq][0] += __shfl_xor(p[qq][0], 32, 64);
        p[qq][1] += __shfl_xor(p[qq][1], 16, 64); p[qq][1] += __shfl_xor(p[qq][1], 32, 64);
    }
    __syncthreads();   // all strip reads done; strip region reusable as red
    if (kg == 0) {
#pragma unroll
        for (int qq = 0; qq < 2; ++qq) {
            int base = ((qs * 2 + qq) * 16 + l16) * 2;
            red[(base + 0) * 4 + cg] = p[qq][0];
            red[(base + 1) * 4 + cg] = p[qq][1];
        }
    }
    __syncthreads();
    if (t < 128) {
        int q = qb + t;
        if (q < Q_PAIRS) {
            int base = t * 2;
            float l0 = red[base * 4 + 0] + red[base * 4 + 1] + red[base * 4 + 2] + red[base * 4 + 3] + b2[0];
            float l1v = red[(base + 1) * 4 + 0] + red[(base + 1) * 4 + 1]
                      + red[(base + 1) * 4 + 2] + red[(base + 1) * 4 + 3] + b2[1];
            float mx = fmaxf(l0, l1v);
            float lse = mx + logf(expf(l0 - mx) + expf(l1v - mx));
            float2 o; o.x = l0 - lse; o.y = l1v - lse;
            *(float2*)(out + (size_t)qidx[q] * N_CLS) = o;
        }
    }
}

// ---------------- launch ----------------
extern "C" void kernel_launch(void* const* d_in, const int* in_sizes, int n_in,
                              void* d_out, int out_size, void* d_ws, size_t ws_size,
                              hipStream_t stream) {
    const float* X  = (const float*)d_in[0];
    const int*   ei = (const int*)d_in[1];
    const float* ew = (const float*)d_in[2];
    const int*   e1 = (const int*)d_in[3];
    const int*   e2 = (const int*)d_in[4];
    const float* w_init[2] = {(const float*)d_in[5],  (const float*)d_in[10]};
    const float* w_ih[2]   = {(const float*)d_in[6],  (const float*)d_in[11]};
    const float* w_hh[2]   = {(const float*)d_in[7],  (const float*)d_in[12]};
    const float* b_ih[2]   = {(const float*)d_in[8],  (const float*)d_in[13]};
    const float* b_hh[2]   = {(const float*)d_in[9],  (const float*)d_in[14]};
    const float* lw0 = (const float*)d_in[15]; const float* lb0 = (const float*)d_in[16];
    const float* lw1 = (const float*)d_in[17]; const float* lb1 = (const float*)d_in[18];
    const float* lw2 = (const float*)d_in[19]; const float* lb2 = (const float*)d_in[20];
    const float* bg0 = (const float*)d_in[21]; const float* bb0 = (const float*)d_in[22];
    const float* bm0 = (const float*)d_in[23]; const float* bv0 = (const float*)d_in[24];
    const float* bg1 = (const float*)d_in[25]; const float* bb1 = (const float*)d_in[26];
    const float* bm1 = (const float*)d_in[27]; const float* bv1 = (const float*)d_in[28];
    const int* src = ei;
    const int* dst = ei + E_EDGES;

    char* ws = (char*)d_ws;
    size_t o = 0;
    auto alloc = [&](size_t bytes) { char* p = ws + o; o += (bytes + 63) & ~(size_t)63; return p; };
    float* bufA   = (float*)alloc((size_t)N_NODES * C_DIM * 4);   // agg (f32)
    float* bufB   = (float*)alloc((size_t)N_NODES * C_DIM * 4);   // y2 (f32)
    unsigned short* xbf = (unsigned short*)alloc((size_t)N_NODES * C_DIM * 2);  // X bf16
    unsigned short* ybf = (unsigned short*)alloc((size_t)N_NODES * C_DIM * 2);  // y1 bf16
    float* dinv   = (float*)alloc(N_NODES * 4);
    float* we0    = (float*)alloc(C_DIM * C_DIM * 4);
    float* we1    = (float*)alloc(C_DIM * C_DIM * 4);
    float* shift0 = (float*)alloc(H_DIM * 4);
    float* shift1 = (float*)alloc(H_DIM * 4);
    unsigned long long* dpack = (unsigned long long*)alloc((size_t)N_NODES * 8);
    int*   pos    = (int*)alloc(N_NODES * 4);
    int*   off    = (int*)alloc((N_NODES + 1) * 4);
    int*   bsum   = (int*)alloc(64 * 4);
    int*   boff   = (int*)alloc(64 * 4);
    int*   qcnt   = (int*)alloc(N_NODES * 4);
    int*   qpos   = (int*)alloc(N_NODES * 4);
    int*   qoff   = (int*)alloc((N_NODES + 1) * 4);
    int*   qbsum  = (int*)alloc(64 * 4);
    int*   qboff  = (int*)alloc(64 * 4);
    int2*  csr    = (int2*)alloc((size_t)E_EDGES * 8);
    int2*  qpair  = (int2*)alloc((size_t)Q_PAIRS * 8);
    int*   qidx   = (int*)alloc((size_t)Q_PAIRS * 4);
    unsigned short* W0p = (unsigned short*)alloc(65536 * 2);    // 128KB
    unsigned short* W1p = (unsigned short*)alloc(131072 * 2);   // 256KB
    unsigned short* Wc0 = (unsigned short*)alloc(32768 * 2);    // 64KB
    unsigned short* Wc1 = (unsigned short*)alloc(32768 * 2);    // 64KB
    if (o > ws_size) return;

    dim3 b256(256);
    const int gN = (N_NODES + 255) / 256;
    const int gE = (E_EDGES + 255) / 256;
    const int gQ = (Q_PAIRS + 255) / 256;

    // degrees (packed) + CSR + query-sort histograms
    k_init<<<gN, b256, 0, stream>>>(dpack, qcnt);
    k_deg_hist<<<gE, b256, 0, stream>>>(dst, ew, dpack);
    k_qhist<<<gQ, b256, 0, stream>>>(e1, qcnt);
    k_scan1<<<49, dim3(1024), 0, stream>>>((const int*)dpack + 1, 2, pos, bsum);
    k_scan2<<<1, dim3(64), 0, stream>>>(bsum, boff);
    k_scan3<<<49, dim3(1024), 0, stream>>>((const int*)dpack + 1, 2, pos, boff, off, dpack, dinv);
    k_fill<<<gE, b256, 0, stream>>>(src, dst, ew, dinv, pos, csr);
    k_scan1<<<49, dim3(1024), 0, stream>>>(qcnt, 1, qpos, qbsum);
    k_scan2<<<1, dim3(64), 0, stream>>>(qbsum, qboff);
    k_scan3<<<49, dim3(1024), 0, stream>>>(qcnt, 1, qpos, qboff, qoff, nullptr, nullptr);
    k_qfill<<<gQ, b256, 0, stream>>>(e1, e2, qpos, qpair, qidx);

    // GRU (both layers) + weight preps + X->bf16
    k_gru2<<<256, dim3(128), 0, stream>>>(w_init[0], w_ih[0], w_hh[0], b_ih[0], b_hh[0], we0,
                                          w_init[1], w_ih[1], w_hh[1], b_ih[1], b_hh[1], we1);
    k_prep_conv<<<256, b256, 0, stream>>>(we0, we1, Wc0, Wc1);
    k_prep_w<<<256, b256, 0, stream>>>(lw0, bg0, bv0, C_DIM, 65536, W0p);
    k_prep_w<<<512, b256, 0, stream>>>(lw1, bg1, bv1, H_DIM, 131072, W1p);
    k_prep_shift<<<1, dim3(512), 0, stream>>>(lb0, bg0, bb0, bm0, bv0, lb1, bg1, bb1, bm1, bv1, shift0, shift1);
    k_xbf<<<(N_NODES * C_DIM) / 2048, b256, 0, stream>>>(X, xbf);

    const int ga = (N_NODES * 32) / 256;          // 6250
    const int gg = (N_NODES + 63) / 64;           // 782
    // layer 0: aggregate (bf16 in) -> GEMM (bf16 out)
    k_agg<<<ga, b256, 0, stream>>>(xbf, dinv, off, csr, bufA);
    k_gemm<1><<<gg, dim3(512), 0, stream>>>(bufA, Wc0, bufB, ybf);
    // layer 1: aggregate (bf16 in) -> GEMM (f32 out for MLP)
    k_agg<<<ga, b256, 0, stream>>>(ybf, dinv, off, csr, bufA);
    k_gemm<0><<<gg, dim3(512), 0, stream>>>(bufA, Wc1, bufB, ybf);
    // fused MFMA MLP over e1-sorted queries (128 q/block, 16 waves)
    k_mlp<<<(Q_PAIRS + 127) / 128, dim3(1024), 0, stream>>>(bufB, qpair, qidx, W0p, W1p,
                                                            shift0, shift1, lw2, lb2, (float*)d_out);
}

// Round 11
// 572.913 us; speedup vs baseline: 14.6730x; 1.1372x over previous
//
#include <hip/hip_runtime.h>
#include <math.h>

#define N_NODES 50000
#define C_DIM   128
#define E_EDGES 1600000
#define Q_PAIRS 500000
#define H_DIM   256
#define N_CLS   2
#define BN_EPS  1e-5f

typedef __attribute__((ext_vector_type(8))) short bf16x8;
typedef __attribute__((ext_vector_type(4))) short s16x4;
typedef __attribute__((ext_vector_type(4))) unsigned short u16x4;
typedef __attribute__((ext_vector_type(4))) float f32x4;

#define VMCNT0 asm volatile("s_waitcnt vmcnt(0)" ::: "memory")
#define VMCNT1 asm volatile("s_waitcnt vmcnt(1)" ::: "memory")
#define VMCNT2 asm volatile("s_waitcnt vmcnt(2)" ::: "memory")
#define SBAR do { __builtin_amdgcn_s_barrier(); \
                  __builtin_amdgcn_sched_barrier(0); } while (0)

#define DEG_SCALE 2097152.0f   // 2^21 fixed point for packed degree

__device__ __forceinline__ unsigned short f2bf(float x) {   // RNE f32->bf16 bits
    unsigned u = __float_as_uint(x);
    u += 0x7fffu + ((u >> 16) & 1u);
    return (unsigned short)(u >> 16);
}
__device__ __forceinline__ float bf2f(unsigned short h) {
    return __uint_as_float(((unsigned)h) << 16);
}

// ---------------- init + packed degree/hist ----------------
__global__ __launch_bounds__(256) void k_init(unsigned long long* dpack, int* qcnt) {
    int i = blockIdx.x * 256 + threadIdx.x;
    if (i < N_NODES) { dpack[i] = 0ULL; qcnt[i] = 0; }
}
// one u64 atomic per edge: hi32 = count, lo32 = ew in 2^21 fixed point
__global__ __launch_bounds__(256) void k_deg_hist(const int* __restrict__ dst,
                                                  const float* __restrict__ ew,
                                                  unsigned long long* dpack) {
    int e = blockIdx.x * 256 + threadIdx.x;
    if (e < E_EDGES) {
        unsigned pv = __float2uint_rn(ew[e] * DEG_SCALE);
        atomicAdd(&dpack[dst[e]], (1ULL << 32) | (unsigned long long)pv);
    }
}
__global__ __launch_bounds__(256) void k_qhist(const int* __restrict__ e1, int* qcnt) {
    int q = blockIdx.x * 256 + threadIdx.x;
    if (q < Q_PAIRS) atomicAdd(&qcnt[e1[q]], 1);
}

// ---------------- multi-block scan (3 kernels; cnt read with runtime stride) ----------------
__global__ __launch_bounds__(1024) void k_scan1(const int* __restrict__ cnt, int stride,
                                                int* __restrict__ locincl,
                                                int* __restrict__ bsum) {
    __shared__ int pa[1024], pb[1024];
    int t = threadIdx.x;
    int x = blockIdx.x * 1024 + t;
    int v = (x < N_NODES) ? cnt[(size_t)x * stride] : 0;
    pa[t] = v;
    __syncthreads();
    int* sp = pa; int* dp = pb;
    for (int o = 1; o < 1024; o <<= 1) {
        int u = sp[t] + ((t >= o) ? sp[t - o] : 0);
        dp[t] = u;
        __syncthreads();
        int* tmp = sp; sp = dp; dp = tmp;
    }
    if (x < N_NODES) locincl[x] = sp[t];
    if (t == 1023) bsum[blockIdx.x] = sp[1023];
}
__global__ __launch_bounds__(64) void k_scan2(const int* __restrict__ bsum,
                                              int* __restrict__ boff) {
    int t = threadIdx.x;
    int v = (t < 49) ? bsum[t] : 0;
    int own = v;
    for (int o = 1; o < 64; o <<= 1) {
        int u = __shfl_up(v, o, 64);
        if (t >= o) v += u;
    }
    if (t < 49) boff[t] = v - own;   // exclusive
}
// also finalizes dinv from packed degree when dpack != nullptr
__global__ __launch_bounds__(1024) void k_scan3(const int* __restrict__ cnt, int stride,
                                                int* __restrict__ pos,
                                                const int* __restrict__ boff,
                                                int* __restrict__ off,
                                                const unsigned long long* __restrict__ dpack,
                                                float* __restrict__ dinv) {
    int x = blockIdx.x * 1024 + threadIdx.x;
    if (x >= N_NODES) return;
    int incl = pos[x];
    int c = cnt[(size_t)x * stride];
    int o = boff[blockIdx.x] + incl - c;
    off[x] = o;
    pos[x] = o;
    if (x == N_NODES - 1) off[N_NODES] = o + c;
    if (dpack) {
        unsigned lo = (unsigned)(dpack[x] & 0xffffffffULL);
        dinv[x] = rsqrtf(1.0f + (float)lo * (1.0f / DEG_SCALE));
    }
}

// packed CSR entry: .x = src node, .y = float weight bits
__global__ __launch_bounds__(256) void k_fill(const int* __restrict__ src,
                                              const int* __restrict__ dst,
                                              const float* __restrict__ ew,
                                              const float* __restrict__ dinv,
                                              int* pos,
                                              int2* __restrict__ csr) {
    int e = blockIdx.x * 256 + threadIdx.x;
    if (e >= E_EDGES) return;
    int s = src[e], d = dst[e];
    int slot = atomicAdd(&pos[d], 1);
    int2 p;
    p.x = s;
    p.y = __float_as_int(dinv[s] * ew[e] * dinv[d]);
    csr[slot] = p;
}
// query sort fill: qpair[slot] = (e1,e2), qidx[slot] = original q
__global__ __launch_bounds__(256) void k_qfill(const int* __restrict__ e1,
                                               const int* __restrict__ e2,
                                               int* qpos,
                                               int2* __restrict__ qpair,
                                               int* __restrict__ qidx) {
    int q = blockIdx.x * 256 + threadIdx.x;
    if (q >= Q_PAIRS) return;
    int a = e1[q];
    int slot = atomicAdd(&qpos[a], 1);
    int2 p; p.x = a; p.y = e2[q];
    qpair[slot] = p;
    qidx[slot] = q;
}

// ---------------- GRU weight evolution (both layers in one launch) ----------------
__global__ __launch_bounds__(128) void k_gru2(
    const float* __restrict__ wi0, const float* __restrict__ wih0, const float* __restrict__ whh0,
    const float* __restrict__ bih0, const float* __restrict__ bhh0, float* __restrict__ we0,
    const float* __restrict__ wi1, const float* __restrict__ wih1, const float* __restrict__ whh1,
    const float* __restrict__ bih1, const float* __restrict__ bhh1, float* __restrict__ we1) {
    __shared__ float xrow[C_DIM];
    int layer = blockIdx.x >> 7;
    int i = blockIdx.x & 127, j = threadIdx.x;
    const float* w_init = layer ? wi1 : wi0;
    const float* wih = layer ? wih1 : wih0;
    const float* whh = layer ? whh1 : whh0;
    const float* bih = layer ? bih1 : bih0;
    const float* bhh = layer ? bhh1 : bhh0;
    float* w_out = layer ? we1 : we0;
    xrow[j] = w_init[i * C_DIM + j];
    __syncthreads();
    float gi[3], gh[3];
#pragma unroll
    for (int g = 0; g < 3; ++g) {
        const float* wi = wih + (size_t)(g * C_DIM + j) * C_DIM;
        const float* wh = whh + (size_t)(g * C_DIM + j) * C_DIM;
        float ai = 0.f, ah = 0.f;
        for (int k = 0; k < C_DIM; ++k) { ai += xrow[k] * wi[k]; ah += xrow[k] * wh[k]; }
        gi[g] = ai + bih[g * C_DIM + j];
        gh[g] = ah + bhh[g * C_DIM + j];
    }
    float r = 1.f / (1.f + expf(-(gi[0] + gh[0])));
    float z = 1.f / (1.f + expf(-(gi[1] + gh[1])));
    float n = tanhf(gi[2] + r * gh[2]);
    w_out[i * C_DIM + j] = (1.f - z) * n + z * xrow[j];
}

// ---------------- X -> bf16 ----------------
__global__ __launch_bounds__(256) void k_xbf(const float* __restrict__ x,
                                             unsigned short* __restrict__ xb) {
    int i = (blockIdx.x * 256 + threadIdx.x) * 8;
    f32x4 a = *(const f32x4*)(x + i);
    f32x4 b = *(const f32x4*)(x + i + 4);
    bf16x8 o;
#pragma unroll
    for (int e = 0; e < 4; ++e) { o[e] = (short)f2bf(a[e]); o[e + 4] = (short)f2bf(b[e]); }
    *(bf16x8*)(xb + i) = o;
}

// ---------------- CSR aggregation from bf16 rows ----------------
__global__ __launch_bounds__(256) void k_agg(const unsigned short* __restrict__ xb,
                                             const float* __restrict__ dinv,
                                             const int* __restrict__ off,
                                             const int2* __restrict__ csr,
                                             float* __restrict__ agg) {
    int tid = blockIdx.x * 256 + threadIdx.x;
    int n = tid >> 5;
    int c = (tid & 31) << 2;
    float dv = dinv[n];
    float d2 = dv * dv;
    u16x4 xs = *(const u16x4*)(xb + (size_t)n * C_DIM + c);
    float4 acc;
    acc.x = d2 * bf2f(xs[0]); acc.y = d2 * bf2f(xs[1]);
    acc.z = d2 * bf2f(xs[2]); acc.w = d2 * bf2f(xs[3]);
    int i = off[n], e = off[n + 1];
    for (; i + 8 <= e; i += 8) {
        int2 q0 = csr[i], q1 = csr[i + 1], q2 = csr[i + 2], q3 = csr[i + 3];
        int2 q4 = csr[i + 4], q5 = csr[i + 5], q6 = csr[i + 6], q7 = csr[i + 7];
        u16x4 v0 = *(const u16x4*)(xb + (size_t)q0.x * C_DIM + c);
        u16x4 v1 = *(const u16x4*)(xb + (size_t)q1.x * C_DIM + c);
        u16x4 v2 = *(const u16x4*)(xb + (size_t)q2.x * C_DIM + c);
        u16x4 v3 = *(const u16x4*)(xb + (size_t)q3.x * C_DIM + c);
        u16x4 v4 = *(const u16x4*)(xb + (size_t)q4.x * C_DIM + c);
        u16x4 v5 = *(const u16x4*)(xb + (size_t)q5.x * C_DIM + c);
        u16x4 v6 = *(const u16x4*)(xb + (size_t)q6.x * C_DIM + c);
        u16x4 v7 = *(const u16x4*)(xb + (size_t)q7.x * C_DIM + c);
        float w0 = __int_as_float(q0.y), w1 = __int_as_float(q1.y);
        float w2 = __int_as_float(q2.y), w3 = __int_as_float(q3.y);
        float w4 = __int_as_float(q4.y), w5 = __int_as_float(q5.y);
        float w6 = __int_as_float(q6.y), w7 = __int_as_float(q7.y);
        acc.x += w0 * bf2f(v0[0]) + w1 * bf2f(v1[0]) + w2 * bf2f(v2[0]) + w3 * bf2f(v3[0])
               + w4 * bf2f(v4[0]) + w5 * bf2f(v5[0]) + w6 * bf2f(v6[0]) + w7 * bf2f(v7[0]);
        acc.y += w0 * bf2f(v0[1]) + w1 * bf2f(v1[1]) + w2 * bf2f(v2[1]) + w3 * bf2f(v3[1])
               + w4 * bf2f(v4[1]) + w5 * bf2f(v5[1]) + w6 * bf2f(v6[1]) + w7 * bf2f(v7[1]);
        acc.z += w0 * bf2f(v0[2]) + w1 * bf2f(v1[2]) + w2 * bf2f(v2[2]) + w3 * bf2f(v3[2])
               + w4 * bf2f(v4[2]) + w5 * bf2f(v5[2]) + w6 * bf2f(v6[2]) + w7 * bf2f(v7[2]);
        acc.w += w0 * bf2f(v0[3]) + w1 * bf2f(v1[3]) + w2 * bf2f(v2[3]) + w3 * bf2f(v3[3])
               + w4 * bf2f(v4[3]) + w5 * bf2f(v5[3]) + w6 * bf2f(v6[3]) + w7 * bf2f(v7[3]);
    }
    for (; i < e; ++i) {
        int2 pe = csr[i];
        float w = __int_as_float(pe.y);
        u16x4 v = *(const u16x4*)(xb + (size_t)pe.x * C_DIM + c);
        acc.x += w * bf2f(v[0]); acc.y += w * bf2f(v[1]);
        acc.z += w * bf2f(v[2]); acc.w += w * bf2f(v[3]);
    }
    *(float4*)(agg + (size_t)n * C_DIM + c) = acc;
}

// ---------------- weight prep ----------------
// MLP weights hi-plane only: [kb][kg(4)][col(256)][e(8)], 16KB per kb strip
__global__ __launch_bounds__(256) void k_prep_w(const float* __restrict__ w,
                                                const float* __restrict__ g,
                                                const float* __restrict__ v,
                                                int kdim, int total,
                                                unsigned short* __restrict__ outp) {
    int idx = blockIdx.x * 256 + threadIdx.x;
    if (idx >= total) return;
    int e = idx & 7, col = (idx >> 3) & 255, kg = (idx >> 11) & 3;
    int kb = idx >> 13;
    int k = kb * 32 + kg * 8 + e;
    float sc = g[col] * rsqrtf(v[col] + BN_EPS);
    outp[idx] = f2bf(w[(size_t)col * kdim + k] * sc);
}
// conv weights (both layers): [layer][kb(4)][plane][kg(4)][col(128)][e(8)]
__global__ __launch_bounds__(256) void k_prep_conv(const float* __restrict__ we0,
                                                   const float* __restrict__ we1,
                                                   unsigned short* __restrict__ Wc0,
                                                   unsigned short* __restrict__ Wc1) {
    int idx = blockIdx.x * 256 + threadIdx.x;   // 65536 total
    int e = idx & 7, col = (idx >> 3) & 127, kg = (idx >> 10) & 3;
    int plane = (idx >> 12) & 1, kb = (idx >> 13) & 3, layer = idx >> 15;
    int k = kb * 32 + kg * 8 + e;
    const float* we = layer ? we1 : we0;
    float x = we[(size_t)k * C_DIM + col];
    unsigned short hi = f2bf(x);
    unsigned short o = plane ? f2bf(x - bf2f(hi)) : hi;
    (layer ? Wc1 : Wc0)[idx & 32767] = o;
}

__global__ __launch_bounds__(512) void k_prep_shift(
    const float* __restrict__ lb0, const float* __restrict__ bg0, const float* __restrict__ bb0,
    const float* __restrict__ bm0, const float* __restrict__ bv0,
    const float* __restrict__ lb1, const float* __restrict__ bg1, const float* __restrict__ bb1,
    const float* __restrict__ bm1, const float* __restrict__ bv1,
    float* __restrict__ shift0, float* __restrict__ shift1) {
    int j = threadIdx.x;
    if (j < 256) {
        float sc = bg0[j] * rsqrtf(bv0[j] + BN_EPS);
        shift0[j] = (lb0[j] - bm0[j]) * sc + bb0[j];
    } else {
        int i = j - 256;
        float sc = bg1[i] * rsqrtf(bv1[i] + BN_EPS);
        shift1[i] = (lb1[i] - bm1[i]) * sc + bb1[i];
    }
}

// ---------------- conv GEMM: y = relu(agg @ W); OUT_BF: write bf16 rows ----------------
template <int OUT_BF>
__global__ __launch_bounds__(512) void k_gemm(const float* __restrict__ agg,
                                              const unsigned short* __restrict__ Wc,
                                              float* __restrict__ y,
                                              unsigned short* __restrict__ yb) {
    __shared__ __align__(16) char smem[3 * 8192];
    const int t = threadIdx.x, lane = t & 63, wave = t >> 6;
    const int qg = wave >> 1, ch = wave & 1;
    const int l16 = lane & 15, kg = lane >> 4;
    const int qrow = qg * 16 + l16;
    const int node = blockIdx.x * 64 + qrow;
    const int nodec = node < N_NODES ? node : N_NODES - 1;

    auto STG = [&](int sidx, int b) {
        const char* g = (const char*)Wc + sidx * 8192 + wave * 1024 + lane * 16;
        char* d = smem + b * 8192 + wave * 1024;
        __builtin_amdgcn_global_load_lds((const __attribute__((address_space(1))) void*)g,
                                         (__attribute__((address_space(3))) void*)d, 16, 0, 0);
    };
    STG(0, 0); STG(1, 1);

    bf16x8 bh[4], bl[4];
    const float* ar = agg + (size_t)nodec * C_DIM;
#pragma unroll
    for (int kb = 0; kb < 4; ++kb) {
        int k0 = kb * 32 + kg * 8;
        f32x4 a0 = *(const f32x4*)(ar + k0);
        f32x4 a1 = *(const f32x4*)(ar + k0 + 4);
#pragma unroll
        for (int e = 0; e < 4; ++e) {
            unsigned short h0 = f2bf(a0[e]);
            bh[kb][e] = (short)h0; bl[kb][e] = (short)f2bf(a0[e] - bf2f(h0));
            unsigned short h1 = f2bf(a1[e]);
            bh[kb][e + 4] = (short)h1; bl[kb][e + 4] = (short)f2bf(a1[e] - bf2f(h1));
        }
    }
    f32x4 acc[4];
#pragma unroll
    for (int i = 0; i < 4; ++i) acc[i] = 0.f;

#pragma unroll
    for (int s = 0; s < 8; ++s) {
        if (s < 7) { VMCNT1; } else { VMCNT0; }
        SBAR;
        if (s + 2 < 8) STG(s + 2, (s + 2) % 3);
        const unsigned short* strip = (const unsigned short*)(smem + (s % 3) * 8192);
        const int kb = s >> 1;
        __builtin_amdgcn_s_setprio(1);
#pragma unroll
        for (int jc8 = 0; jc8 < 4; ++jc8) {
            int col = (ch * 4 + jc8) * 16 + l16;
            bf16x8 a = *(const bf16x8*)&strip[kg * 1024 + col * 8];
            acc[jc8] = __builtin_amdgcn_mfma_f32_16x16x32_bf16(a, bh[kb], acc[jc8], 0, 0, 0);
            if ((s & 1) == 0)
                acc[jc8] = __builtin_amdgcn_mfma_f32_16x16x32_bf16(a, bl[kb], acc[jc8], 0, 0, 0);
        }
        __builtin_amdgcn_s_setprio(0);
    }

    if (node < N_NODES) {
#pragma unroll
        for (int jc8 = 0; jc8 < 4; ++jc8) {
            int j0 = (ch * 4 + jc8) * 16 + kg * 4;
            if (OUT_BF) {
                u16x4 v;
#pragma unroll
                for (int r = 0; r < 4; ++r) v[r] = f2bf(fmaxf(acc[jc8][r], 0.f));
                *(u16x4*)(yb + (size_t)node * C_DIM + j0) = v;
            } else {
                float4 v;
                v.x = fmaxf(acc[jc8][0], 0.f); v.y = fmaxf(acc[jc8][1], 0.f);
                v.z = fmaxf(acc[jc8][2], 0.f); v.w = fmaxf(acc[jc8][3], 0.f);
                *(float4*)(y + (size_t)node * C_DIM + j0) = v;
            }
        }
    }
}

// ---------------- fused query MLP (1-term bf16 MFMA, hi-only weights, 12 phases) ----------------
// 64 q/block, 512 thr, 8 waves: wave = qs*4+cg, qs in {0,1}, cg in {0..3}.
// LDS 80KB -> 2 blocks/CU (16 waves/CU): [0,48K) 3x16KB strips; [48K,80K) l1b 64x256.
__global__ __launch_bounds__(512, 4) void k_mlp(const float* __restrict__ y,
                                             const int2* __restrict__ qpair,
                                             const int* __restrict__ qidx,
                                             const unsigned short* __restrict__ W0p,
                                             const unsigned short* __restrict__ W1p,
                                             const float* __restrict__ shift0,
                                             const float* __restrict__ shift1,
                                             const float* __restrict__ w2,
                                             const float* __restrict__ b2,
                                             float* __restrict__ out) {
    __shared__ __align__(16) char smem[81920];
    unsigned short* l1b = (unsigned short*)(smem + 49152);   // 64 x 256 shorts
    float* red = (float*)smem;                               // 2KB, epilogue only

    const int t = threadIdx.x;
    const int lane = t & 63;
    const int wave = t >> 6;
    const int qs = wave >> 2, cg = wave & 3;
    const int l16 = lane & 15, kg = lane >> 4;
    const int qb = blockIdx.x * 64;

    auto STG = [&](const unsigned short* W, int sidx, int b) {
        const char* g = (const char*)W + ((size_t)sidx << 14) + wave * 2048 + lane * 16;
        char* d = smem + b * 16384 + wave * 2048;
        __builtin_amdgcn_global_load_lds((const __attribute__((address_space(1))) void*)g,
                                         (__attribute__((address_space(3))) void*)d, 16, 0, 0);
        __builtin_amdgcn_global_load_lds((const __attribute__((address_space(1))) void*)(g + 1024),
                                         (__attribute__((address_space(3))) void*)(d + 1024), 16, 0, 0);
    };

    STG(W0p, 0, 0); STG(W0p, 1, 1);   // overlap with phase 0

    // ---- phase 0: cooperative h staging (each query row gathered ONCE/block) ----
    {
        int k2 = lane * 2;
        int G = lane >> 2;            // k-granule 0..15
        int off = k2 & 7;
#pragma unroll
        for (int qi = 0; qi < 8; ++qi) {
            int qrow = wave * 8 + qi;
            int q = qb + qrow; if (q >= Q_PAIRS) q = Q_PAIRS - 1;
            int2 pr = qpair[q];
            const float* ya = y + (size_t)pr.x * C_DIM;
            const float* yb = y + (size_t)pr.y * C_DIM;
            float2 a = *(const float2*)(ya + k2);
            float2 b = *(const float2*)(yb + k2);
            int idx = qrow * 256 + ((G ^ (qrow & 7)) << 3) + off;
            l1b[idx] = f2bf(a.x * b.x);
            l1b[idx + 1] = f2bf(a.y * b.y);
        }
    }
    __syncthreads();   // h visible

    // ---- pickup h fragments into regs ----
    bf16x8 bh[2][4];
#pragma unroll
    for (int qq = 0; qq < 2; ++qq) {
        int qrow = qs * 32 + qq * 16 + l16;
#pragma unroll
        for (int kb = 0; kb < 4; ++kb) {
            int gidx = qrow * 256 + (((kb * 4 + kg) ^ (qrow & 7)) * 8);
            bh[qq][kb] = *(const bf16x8*)&l1b[gidx];
        }
    }

    f32x4 acc[2][4];
#pragma unroll
    for (int qq = 0; qq < 2; ++qq)
#pragma unroll
        for (int jc = 0; jc < 4; ++jc) acc[qq][jc] = 0.f;

    // ---- layer 1: 4 strips (hi only), depth-2 pipeline ----
#pragma unroll
    for (int s = 0; s < 4; ++s) {
        if (s < 3) { VMCNT2; } else { VMCNT0; }
        SBAR;
        if (s + 2 < 4) STG(W0p, s + 2, (s + 2) % 3);
        const unsigned short* strip = (const unsigned short*)(smem + (s % 3) * 16384);
        __builtin_amdgcn_s_setprio(1);
#pragma unroll
        for (int jc = 0; jc < 4; ++jc) {
            int col = cg * 64 + jc * 16 + l16;
            bf16x8 a = *(const bf16x8*)&strip[kg * 2048 + col * 8];
            acc[0][jc] = __builtin_amdgcn_mfma_f32_16x16x32_bf16(a, bh[0][s], acc[0][jc], 0, 0, 0);
            acc[1][jc] = __builtin_amdgcn_mfma_f32_16x16x32_bf16(a, bh[1][s], acc[1][jc], 0, 0, 0);
        }
        __builtin_amdgcn_s_setprio(0);
    }

    // ---- epilogue 1: BN-shift + relu -> l1b (bf16 hi only) ----
#pragma unroll
    for (int qq = 0; qq < 2; ++qq) {
        int qrow = qs * 32 + qq * 16 + l16;
#pragma unroll
        for (int jc = 0; jc < 4; ++jc) {
            int jg = cg * 4 + jc;
            int j0 = jg * 16 + kg * 4;
            f32x4 sh = *(const f32x4*)(shift0 + j0);
            s16x4 th;
#pragma unroll
            for (int r = 0; r < 4; ++r)
                th[r] = (short)f2bf(fmaxf(acc[qq][jc][r] + sh[r], 0.f));
            int G = jg * 2 + (kg >> 1);
            int idx = qrow * 256 + ((G ^ (qrow & 7)) * 8) + (kg & 1) * 4;
            *(s16x4*)&l1b[idx] = th;
        }
    }
    __syncthreads();   // h1 visible; all strip reads of layer 1 complete

    // ---- layer 2: 8 strips (hi only), depth-2 pipeline; bh2 pickup each phase ----
    f32x4 acc2[2][4];
#pragma unroll
    for (int qq = 0; qq < 2; ++qq)
#pragma unroll
        for (int jc = 0; jc < 4; ++jc) acc2[qq][jc] = 0.f;
    STG(W1p, 0, 0); STG(W1p, 1, 1);
    bf16x8 bh2[2];
#pragma unroll
    for (int s = 0; s < 8; ++s) {
        if (s < 7) { VMCNT2; } else { VMCNT0; }
        SBAR;
        if (s + 2 < 8) STG(W1p, s + 2, (s + 2) % 3);
        const unsigned short* strip = (const unsigned short*)(smem + (s % 3) * 16384);
#pragma unroll
        for (int qq = 0; qq < 2; ++qq) {
            int qrow = qs * 32 + qq * 16 + l16;
            int gidx = qrow * 256 + (((s * 4 + kg) ^ (qrow & 7)) * 8);
            bh2[qq] = *(const bf16x8*)&l1b[gidx];
        }
        __builtin_amdgcn_s_setprio(1);
#pragma unroll
        for (int jc = 0; jc < 4; ++jc) {
            int col = cg * 64 + jc * 16 + l16;
            bf16x8 a = *(const bf16x8*)&strip[kg * 2048 + col * 8];
            acc2[0][jc] = __builtin_amdgcn_mfma_f32_16x16x32_bf16(a, bh2[0], acc2[0][jc], 0, 0, 0);
            acc2[1][jc] = __builtin_amdgcn_mfma_f32_16x16x32_bf16(a, bh2[1], acc2[1][jc], 0, 0, 0);
        }
        __builtin_amdgcn_s_setprio(0);
    }

    // ---- layer 3: BN-shift + relu + 256->2 partials ----
    float p[2][2] = {};
#pragma unroll
    for (int qq = 0; qq < 2; ++qq)
#pragma unroll
        for (int jc = 0; jc < 4; ++jc) {
            int j0 = (cg * 4 + jc) * 16 + kg * 4;
            f32x4 sh = *(const f32x4*)(shift1 + j0);
            f32x4 wa = *(const f32x4*)(w2 + j0);
            f32x4 wb = *(const f32x4*)(w2 + H_DIM + j0);
#pragma unroll
            for (int r = 0; r < 4; ++r) {
                float v = fmaxf(acc2[qq][jc][r] + sh[r], 0.f);
                p[qq][0] += v * wa[r];
                p[qq][1] += v * wb[r];
            }
        }
#pragma unroll
    for (int qq = 0; qq < 2; ++qq) {
        p[qq][0] += __shfl_xor(p[qq][0], 16, 64); p[qq][0] += __shfl_xor(p[qq][0], 32, 64);
        p[qq][1] += __shfl_xor(p[qq][1], 16, 64); p[qq][1] += __shfl_xor(p[qq][1], 32, 64);
    }
    __syncthreads();   // all strip reads done; strip region reusable as red
    if (kg == 0) {
#pragma unroll
        for (int qq = 0; qq < 2; ++qq) {
            int base = ((qs * 2 + qq) * 16 + l16) * 2;
            red[(base + 0) * 4 + cg] = p[qq][0];
            red[(base + 1) * 4 + cg] = p[qq][1];
        }
    }
    __syncthreads();
    if (t < 64) {
        int q = qb + t;
        if (q < Q_PAIRS) {
            int base = t * 2;
            float l0 = red[base * 4 + 0] + red[base * 4 + 1] + red[base * 4 + 2] + red[base * 4 + 3] + b2[0];
            float l1v = red[(base + 1) * 4 + 0] + red[(base + 1) * 4 + 1]
                      + red[(base + 1) * 4 + 2] + red[(base + 1) * 4 + 3] + b2[1];
            float mx = fmaxf(l0, l1v);
            float lse = mx + logf(expf(l0 - mx) + expf(l1v - mx));
            float2 o; o.x = l0 - lse; o.y = l1v - lse;
            *(float2*)(out + (size_t)qidx[q] * N_CLS) = o;
        }
    }
}

// ---------------- launch ----------------
extern "C" void kernel_launch(void* const* d_in, const int* in_sizes, int n_in,
                              void* d_out, int out_size, void* d_ws, size_t ws_size,
                              hipStream_t stream) {
    const float* X  = (const float*)d_in[0];
    const int*   ei = (const int*)d_in[1];
    const float* ew = (const float*)d_in[2];
    const int*   e1 = (const int*)d_in[3];
    const int*   e2 = (const int*)d_in[4];
    const float* w_init[2] = {(const float*)d_in[5],  (const float*)d_in[10]};
    const float* w_ih[2]   = {(const float*)d_in[6],  (const float*)d_in[11]};
    const float* w_hh[2]   = {(const float*)d_in[7],  (const float*)d_in[12]};
    const float* b_ih[2]   = {(const float*)d_in[8],  (const float*)d_in[13]};
    const float* b_hh[2]   = {(const float*)d_in[9],  (const float*)d_in[14]};
    const float* lw0 = (const float*)d_in[15]; const float* lb0 = (const float*)d_in[16];
    const float* lw1 = (const float*)d_in[17]; const float* lb1 = (const float*)d_in[18];
    const float* lw2 = (const float*)d_in[19]; const float* lb2 = (const float*)d_in[20];
    const float* bg0 = (const float*)d_in[21]; const float* bb0 = (const float*)d_in[22];
    const float* bm0 = (const float*)d_in[23]; const float* bv0 = (const float*)d_in[24];
    const float* bg1 = (const float*)d_in[25]; const float* bb1 = (const float*)d_in[26];
    const float* bm1 = (const float*)d_in[27]; const float* bv1 = (const float*)d_in[28];
    const int* src = ei;
    const int* dst = ei + E_EDGES;

    char* ws = (char*)d_ws;
    size_t o = 0;
    auto alloc = [&](size_t bytes) { char* p = ws + o; o += (bytes + 63) & ~(size_t)63; return p; };
    float* bufA   = (float*)alloc((size_t)N_NODES * C_DIM * 4);   // agg (f32)
    float* bufB   = (float*)alloc((size_t)N_NODES * C_DIM * 4);   // y2 (f32)
    unsigned short* xbf = (unsigned short*)alloc((size_t)N_NODES * C_DIM * 2);  // X bf16
    unsigned short* ybf = (unsigned short*)alloc((size_t)N_NODES * C_DIM * 2);  // y1 bf16
    float* dinv   = (float*)alloc(N_NODES * 4);
    float* we0    = (float*)alloc(C_DIM * C_DIM * 4);
    float* we1    = (float*)alloc(C_DIM * C_DIM * 4);
    float* shift0 = (float*)alloc(H_DIM * 4);
    float* shift1 = (float*)alloc(H_DIM * 4);
    unsigned long long* dpack = (unsigned long long*)alloc((size_t)N_NODES * 8);
    int*   pos    = (int*)alloc(N_NODES * 4);
    int*   off    = (int*)alloc((N_NODES + 1) * 4);
    int*   bsum   = (int*)alloc(64 * 4);
    int*   boff   = (int*)alloc(64 * 4);
    int*   qcnt   = (int*)alloc(N_NODES * 4);
    int*   qpos   = (int*)alloc(N_NODES * 4);
    int*   qoff   = (int*)alloc((N_NODES + 1) * 4);
    int*   qbsum  = (int*)alloc(64 * 4);
    int*   qboff  = (int*)alloc(64 * 4);
    int2*  csr    = (int2*)alloc((size_t)E_EDGES * 8);
    int2*  qpair  = (int2*)alloc((size_t)Q_PAIRS * 8);
    int*   qidx   = (int*)alloc((size_t)Q_PAIRS * 4);
    unsigned short* W0p = (unsigned short*)alloc(32768 * 2);    // 64KB  (hi only)
    unsigned short* W1p = (unsigned short*)alloc(65536 * 2);    // 128KB (hi only)
    unsigned short* Wc0 = (unsigned short*)alloc(32768 * 2);    // 64KB
    unsigned short* Wc1 = (unsigned short*)alloc(32768 * 2);    // 64KB
    if (o > ws_size) return;

    dim3 b256(256);
    const int gN = (N_NODES + 255) / 256;
    const int gE = (E_EDGES + 255) / 256;
    const int gQ = (Q_PAIRS + 255) / 256;

    // degrees (packed) + CSR + query-sort histograms
    k_init<<<gN, b256, 0, stream>>>(dpack, qcnt);
    k_deg_hist<<<gE, b256, 0, stream>>>(dst, ew, dpack);
    k_qhist<<<gQ, b256, 0, stream>>>(e1, qcnt);
    k_scan1<<<49, dim3(1024), 0, stream>>>((const int*)dpack + 1, 2, pos, bsum);
    k_scan2<<<1, dim3(64), 0, stream>>>(bsum, boff);
    k_scan3<<<49, dim3(1024), 0, stream>>>((const int*)dpack + 1, 2, pos, boff, off, dpack, dinv);
    k_fill<<<gE, b256, 0, stream>>>(src, dst, ew, dinv, pos, csr);
    k_scan1<<<49, dim3(1024), 0, stream>>>(qcnt, 1, qpos, qbsum);
    k_scan2<<<1, dim3(64), 0, stream>>>(qbsum, qboff);
    k_scan3<<<49, dim3(1024), 0, stream>>>(qcnt, 1, qpos, qboff, qoff, nullptr, nullptr);
    k_qfill<<<gQ, b256, 0, stream>>>(e1, e2, qpos, qpair, qidx);

    // GRU (both layers) + weight preps + X->bf16
    k_gru2<<<256, dim3(128), 0, stream>>>(w_init[0], w_ih[0], w_hh[0], b_ih[0], b_hh[0], we0,
                                          w_init[1], w_ih[1], w_hh[1], b_ih[1], b_hh[1], we1);
    k_prep_conv<<<256, b256, 0, stream>>>(we0, we1, Wc0, Wc1);
    k_prep_w<<<128, b256, 0, stream>>>(lw0, bg0, bv0, C_DIM, 32768, W0p);
    k_prep_w<<<256, b256, 0, stream>>>(lw1, bg1, bv1, H_DIM, 65536, W1p);
    k_prep_shift<<<1, dim3(512), 0, stream>>>(lb0, bg0, bb0, bm0, bv0, lb1, bg1, bb1, bm1, bv1, shift0, shift1);
    k_xbf<<<(N_NODES * C_DIM) / 2048, b256, 0, stream>>>(X, xbf);

    const int ga = (N_NODES * 32) / 256;          // 6250
    const int gg = (N_NODES + 63) / 64;           // 782
    // layer 0: aggregate (bf16 in) -> GEMM (bf16 out)
    k_agg<<<ga, b256, 0, stream>>>(xbf, dinv, off, csr, bufA);
    k_gemm<1><<<gg, dim3(512), 0, stream>>>(bufA, Wc0, bufB, ybf);
    // layer 1: aggregate (bf16 in) -> GEMM (f32 out for MLP)
    k_agg<<<ga, b256, 0, stream>>>(ybf, dinv, off, csr, bufA);
    k_gemm<0><<<gg, dim3(512), 0, stream>>>(bufA, Wc1, bufB, ybf);
    // fused MFMA MLP over e1-sorted queries (hi-only weights, 12 phases)
    k_mlp<<<(Q_PAIRS + 63) / 64, dim3(512), 0, stream>>>(bufB, qpair, qidx, W0p, W1p,
                                                         shift0, shift1, lw2, lb2, (float*)d_out);
}